// Round 1
// baseline (853.646 us; speedup 1.0000x reference)
//
#include <hip/hip_runtime.h>
#include <hip/hip_bf16.h>

// Problem constants
#define B_ 128
#define S_ 128
#define H_ 512
#define R_ 16
#define IN_ 2
#define OPS_ 5
#define NPAD_ 16
#define L_ 18          // IN_ + NPAD_
#define NEGV (-1000000000000.0f)

__device__ __forceinline__ float fast_tanh(float x) {
    // tanh(x) = 2*sigmoid(2x)-1 ; safe at +/-inf (no NaN form)
    return 2.0f / (1.0f + __expf(-2.0f * x)) - 1.0f;
}
__device__ __forceinline__ float fast_sigmoid(float x) {
    return 1.0f / (1.0f + __expf(-x));
}

// ---------------------------------------------------------------------------
// Generic fp32 tiled GEMM: C[M,N] = A[M,K] @ W[K,N]   (no bias; bias fused in
// consumers). 64x64 block tile, 256 threads, 4x4 per thread, BK=16.
// N must be a multiple of 64, K a multiple of 16. M arbitrary (guarded).
// ---------------------------------------------------------------------------
#define BM 64
#define BN 64
#define BK 16

__global__ __launch_bounds__(256) void gemm_f32(const float* __restrict__ A,
                                                const float* __restrict__ W,
                                                float* __restrict__ C,
                                                int M, int N, int K) {
    __shared__ float As[BK][BM + 4];  // stored transposed: As[k][m]; +4 keeps 16B align
    __shared__ float Bs[BK][BN];

    const int bm = blockIdx.y * BM;
    const int bn = blockIdx.x * BN;
    const int tid = threadIdx.x;

    const int tcol = (tid & 15) * 4;   // 16 thr * 4 = 64 cols
    const int trow = (tid >> 4) * 4;   // 16 grp * 4 = 64 rows

    const int a_row  = tid >> 2;        // 64 rows
    const int a_col4 = (tid & 3) * 4;   // k offset within BK
    const int b_row  = tid >> 4;        // 16 k rows
    const int b_col4 = (tid & 15) * 4;

    float acc[4][4] = {};

    for (int k0 = 0; k0 < K; k0 += BK) {
        float4 av = make_float4(0.f, 0.f, 0.f, 0.f);
        const int am = bm + a_row;
        if (am < M) av = *(const float4*)(A + (size_t)am * K + k0 + a_col4);
        As[a_col4 + 0][a_row] = av.x;
        As[a_col4 + 1][a_row] = av.y;
        As[a_col4 + 2][a_row] = av.z;
        As[a_col4 + 3][a_row] = av.w;

        float4 bv = *(const float4*)(W + (size_t)(k0 + b_row) * N + bn + b_col4);
        *(float4*)&Bs[b_row][b_col4] = bv;
        __syncthreads();

        #pragma unroll
        for (int k = 0; k < BK; ++k) {
            float4 a4 = *(const float4*)&As[k][trow];
            float4 b4 = *(const float4*)&Bs[k][tcol];
            float a[4] = {a4.x, a4.y, a4.z, a4.w};
            float b[4] = {b4.x, b4.y, b4.z, b4.w};
            #pragma unroll
            for (int i = 0; i < 4; ++i)
                #pragma unroll
                for (int j = 0; j < 4; ++j)
                    acc[i][j] += a[i] * b[j];
        }
        __syncthreads();
    }

    #pragma unroll
    for (int i = 0; i < 4; ++i) {
        const int m = bm + trow + i;
        if (m < M) {
            float* crow = C + (size_t)m * N + bn + tcol;
            crow[0] = acc[i][0]; crow[1] = acc[i][1];
            crow[2] = acc[i][2]; crow[3] = acc[i][3];
        }
    }
}

// ---------------------------------------------------------------------------
// c = stack_empty ? padding_hidden : current_emb ; acat = [left_childs | c]
// ---------------------------------------------------------------------------
__global__ void k_prep(const float* __restrict__ cur, const float* __restrict__ padh,
                       const float* __restrict__ left, const int* __restrict__ se,
                       float* __restrict__ c, float* __restrict__ acat) {
    int i = blockIdx.x * blockDim.x + threadIdx.x;   // B*H
    int b = i >> 9, j = i & 511;
    float cv = se[b] ? padh[j] : cur[i];
    c[i] = cv;
    acat[b * 1024 + j] = left[i];
    acat[b * 1024 + 512 + j] = cv;
}

// ew output: broadcast embedding_weight (l<2) then num_pades
__global__ void k_ew(const float* __restrict__ embw, const float* __restrict__ npade,
                     float* __restrict__ ew) {
    int i = blockIdx.x * blockDim.x + threadIdx.x;   // B*L*H
    int j = i & 511;
    int bl = i >> 9;
    int l = bl % L_;
    int b = bl / L_;
    float v = (l < IN_) ? embw[l * H_ + j] : npade[((size_t)b * NPAD_ + (l - IN_)) * H_ + j];
    ew[i] = v;
}

// q = has_left ? node_r : node_l  (gated tanh units); also current_node out + leaf[:, :H]
__global__ void k_node(const float* __restrict__ gl, const float* __restrict__ glg,
                       const float* __restrict__ gr, const float* __restrict__ grg,
                       const float* __restrict__ bl, const float* __restrict__ blg,
                       const float* __restrict__ br, const float* __restrict__ brg,
                       const int* __restrict__ hl,
                       float* __restrict__ q, float* __restrict__ node_out,
                       float* __restrict__ leaf) {
    int i = blockIdx.x * blockDim.x + threadIdx.x;   // B*H
    int b = i >> 9, j = i & 511;
    float nl = fast_tanh(gl[i] + bl[j]) * fast_sigmoid(glg[i] + blg[j]);
    float nr = fast_tanh(gr[i] + br[j]) * fast_sigmoid(grg[i] + brg[j]);
    float v = hl[b] ? nr : nl;
    q[i] = v;
    node_out[i] = v;
    leaf[b * 1024 + j] = v;
}

// tree attention scores: ae[b][s] = sm ? NEG : tanh(qT[b]+EOt[s,b]+b_ta) . w_ts + b_ts
__global__ __launch_bounds__(256) void k_tree_score(const float* __restrict__ qT,
                                                    const float* __restrict__ EOt,
                                                    const float* __restrict__ b_ta,
                                                    const float* __restrict__ w_ts,
                                                    const float* __restrict__ b_ts,
                                                    const int* __restrict__ seq_mask,
                                                    float* __restrict__ ae) {
    int wid = threadIdx.x >> 6, lane = threadIdx.x & 63;
    int row = blockIdx.x * 4 + wid;      // row = s*B + b
    int s = row >> 7, b = row & 127;
    const float* eo = EOt + (size_t)row * H_;
    const float* qr = qT + b * H_;
    float acc = 0.f;
    #pragma unroll
    for (int it = 0; it < H_ / 64; ++it) {
        int j = lane + it * 64;
        acc += fast_tanh(qr[j] + eo[j] + b_ta[j]) * w_ts[j];
    }
    for (int o = 32; o > 0; o >>= 1) acc += __shfl_down(acc, o);
    if (lane == 0)
        ae[b * S_ + s] = seq_mask[b * S_ + s] ? NEGV : (acc + b_ts[0]);
}

// in-place softmax over rows of length 128 (tree attention)
__global__ __launch_bounds__(128) void k_softmax_tree(float* __restrict__ data) {
    __shared__ float red[2], red2[2];
    int t = threadIdx.x;
    float* row = data + (size_t)blockIdx.x * 128;
    float v = row[t];
    float m = v;
    for (int o = 32; o > 0; o >>= 1) m = fmaxf(m, __shfl_down(m, o));
    if ((t & 63) == 0) red[t >> 6] = m;
    __syncthreads();
    m = fmaxf(red[0], red[1]);
    float e = __expf(v - m);
    float ssum = e;
    for (int o = 32; o > 0; o >>= 1) ssum += __shfl_down(ssum, o);
    if ((t & 63) == 0) red2[t >> 6] = ssum;
    __syncthreads();
    row[t] = e / (red2[0] + red2[1]);
}

// rule scores: comb[b][r][s] = sm ? NEG : tanh(EOr[s,b]+RP[r]+b_ra) . w_rs + b_rs
__global__ __launch_bounds__(256) void k_rule_score(const float* __restrict__ EOr,
                                                    const float* __restrict__ RP,
                                                    const float* __restrict__ b_ra,
                                                    const float* __restrict__ w_rs,
                                                    const float* __restrict__ b_rs,
                                                    const int* __restrict__ seq_mask,
                                                    float* __restrict__ comb) {
    __shared__ float ed[H_];
    int row = blockIdx.x;                 // s*B + b
    int s = row >> 7, b = row & 127;
    for (int j = threadIdx.x; j < H_; j += 256)
        ed[j] = EOr[(size_t)row * H_ + j] + b_ra[j];
    __syncthreads();
    int wid = threadIdx.x >> 6, lane = threadIdx.x & 63;
    bool masked = seq_mask[b * S_ + s] != 0;
    #pragma unroll
    for (int rr = 0; rr < 4; ++rr) {
        int r = wid * 4 + rr;
        float acc = 0.f;
        #pragma unroll
        for (int it = 0; it < 8; ++it) {
            int j = lane + it * 64;
            acc += fast_tanh(ed[j] + RP[r * H_ + j]) * w_rs[j];
        }
        for (int o = 32; o > 0; o >>= 1) acc += __shfl_down(acc, o);
        if (lane == 0)
            comb[((size_t)b * R_ + r) * S_ + s] = masked ? NEGV : (acc + b_rs[0]);
    }
}

// softmax over s for each (b,r), then += 0.2 * attn[b][s]   (in-place)
__global__ __launch_bounds__(128) void k_softmax_rules(float* __restrict__ comb,
                                                       const float* __restrict__ attn) {
    __shared__ float red[2], red2[2];
    int br = blockIdx.x;
    int b = br >> 4;
    int t = threadIdx.x;
    float* row = comb + (size_t)br * 128;
    float v = row[t];
    float m = v;
    for (int o = 32; o > 0; o >>= 1) m = fmaxf(m, __shfl_down(m, o));
    if ((t & 63) == 0) red[t >> 6] = m;
    __syncthreads();
    m = fmaxf(red[0], red[1]);
    float e = __expf(v - m);
    float ssum = e;
    for (int o = 32; o > 0; o >>= 1) ssum += __shfl_down(ssum, o);
    if ((t & 63) == 0) red2[t >> 6] = ssum;
    __syncthreads();
    row[t] = e / (red2[0] + red2[1]) + 0.2f * attn[b * 128 + t];
}

// contexts: ctx[b][j] = sum_s attn*EO ; rctx[b][r][j] = sum_s comb*EO
__global__ __launch_bounds__(256) void k_context(const float* __restrict__ EO,
                                                 const float* __restrict__ attn,
                                                 const float* __restrict__ comb,
                                                 float* __restrict__ ctx_out,
                                                 float* __restrict__ leaf,
                                                 float* __restrict__ rctx) {
    __shared__ float at[S_];
    __shared__ float cb[R_ * S_];
    int b = blockIdx.x;
    int j = blockIdx.y * 256 + threadIdx.x;
    if (threadIdx.x < S_) at[threadIdx.x] = attn[b * S_ + threadIdx.x];
    for (int i = threadIdx.x; i < R_ * S_; i += 256) cb[i] = comb[(size_t)b * R_ * S_ + i];
    __syncthreads();
    float ctx = 0.f;
    float rc[R_] = {};
    for (int s = 0; s < S_; ++s) {
        float eo = EO[((size_t)s * B_ + b) * H_ + j];
        ctx += at[s] * eo;
        #pragma unroll
        for (int r = 0; r < R_; ++r) rc[r] += cb[r * S_ + s] * eo;
    }
    ctx_out[b * H_ + j] = ctx;
    leaf[b * 1024 + 512 + j] = ctx;
    #pragma unroll
    for (int r = 0; r < R_; ++r) rctx[((size_t)b * R_ + r) * H_ + j] = rc[r];
}

// rule_prob[b][:] = softmax_r( tanh(rclin[b,r]+b_rp1) . w_rp2 + b_rp2 )
__global__ __launch_bounds__(256) void k_rp(const float* __restrict__ rclin,
                                            const float* __restrict__ b_rp1,
                                            const float* __restrict__ w_rp2,
                                            const float* __restrict__ b_rp2,
                                            float* __restrict__ prob) {
    __shared__ float sc[R_];
    int b = blockIdx.x;
    int wid = threadIdx.x >> 6, lane = threadIdx.x & 63;
    #pragma unroll
    for (int rr = 0; rr < 4; ++rr) {
        int r = wid * 4 + rr;
        float acc = 0.f;
        #pragma unroll
        for (int it = 0; it < 8; ++it) {
            int j = lane + it * 64;
            acc += fast_tanh(rclin[((size_t)b * R_ + r) * H_ + j] + b_rp1[j]) * w_rp2[j];
        }
        for (int o = 32; o > 0; o >>= 1) acc += __shfl_down(acc, o);
        if (lane == 0) sc[r] = acc + b_rp2[0];
    }
    __syncthreads();
    if (threadIdx.x < R_) {
        float m = -1e30f;
        for (int r = 0; r < R_; ++r) m = fmaxf(m, sc[r]);
        float sum = 0.f;
        for (int r = 0; r < R_; ++r) sum += __expf(sc[r] - m);
        prob[b * R_ + threadIdx.x] = __expf(sc[threadIdx.x] - m) / sum;
    }
}

// num_score[b][l] = nm ? NEG : tanh(ls[b]+ewp[b,l]+b_sc) . w_scs
__global__ __launch_bounds__(256) void k_numscore(const float* __restrict__ ls,
                                                  const float* __restrict__ ewp,
                                                  const float* __restrict__ b_sc,
                                                  const float* __restrict__ w_scs,
                                                  const int* __restrict__ mask_nums,
                                                  float* __restrict__ out) {
    __shared__ float lsd[H_];
    int b = blockIdx.x;
    for (int j = threadIdx.x; j < H_; j += 256) lsd[j] = ls[b * H_ + j] + b_sc[j];
    __syncthreads();
    int wid = threadIdx.x >> 6, lane = threadIdx.x & 63;
    for (int l = wid; l < L_; l += 4) {
        float acc = 0.f;
        #pragma unroll
        for (int it = 0; it < 8; ++it) {
            int j = lane + it * 64;
            acc += fast_tanh(lsd[j] + ewp[((size_t)b * L_ + l) * H_ + j]) * w_scs[j];
        }
        for (int o = 32; o > 0; o >>= 1) acc += __shfl_down(acc, o);
        if (lane == 0) out[b * L_ + l] = mask_nums[b * L_ + l] ? NEGV : acc;
    }
}

// op[b][o] = leaf[b] . W_ops[:,o] + b_ops[o]   (5 waves per block, one per o)
__global__ __launch_bounds__(320) void k_op(const float* __restrict__ leaf,
                                            const float* __restrict__ Wops,
                                            const float* __restrict__ bops,
                                            float* __restrict__ out) {
    int b = blockIdx.x;
    int wid = threadIdx.x / 64, lane = threadIdx.x % 64;
    float acc = 0.f;
    #pragma unroll
    for (int it = 0; it < 16; ++it) {
        int k = lane + it * 64;
        acc += leaf[b * 1024 + k] * Wops[k * OPS_ + wid];
    }
    for (int o = 32; o > 0; o >>= 1) acc += __shfl_down(acc, o);
    if (lane == 0) out[b * OPS_ + wid] = acc + bops[wid];
}

// ---------------------------------------------------------------------------
static inline void gemm(const float* A, const float* W, float* C, int M, int N, int K,
                        hipStream_t s) {
    dim3 grid(N / BN, (M + BM - 1) / BM);
    gemm_f32<<<grid, 256, 0, s>>>(A, W, C, M, N, K);
}

extern "C" void kernel_launch(void* const* d_in, const int* in_sizes, int n_in,
                              void* d_out, int out_size, void* d_ws, size_t ws_size,
                              hipStream_t stream) {
    const float* EO   = (const float*)d_in[0];
    const float* cur  = (const float*)d_in[1];
    const float* left = (const float*)d_in[2];
    const float* padh = (const float*)d_in[3];
    const float* npad = (const float*)d_in[4];
    const float* rsc  = (const float*)d_in[5];
    const float* embw = (const float*)d_in[6];
    const float* Wl   = (const float*)d_in[7];  const float* bl   = (const float*)d_in[8];
    const float* Wlg  = (const float*)d_in[9];  const float* blg  = (const float*)d_in[10];
    const float* Wr   = (const float*)d_in[11]; const float* br   = (const float*)d_in[12];
    const float* Wrg  = (const float*)d_in[13]; const float* brg  = (const float*)d_in[14];
    const float* Wta  = (const float*)d_in[15]; const float* bta  = (const float*)d_in[16];
    const float* Wts  = (const float*)d_in[17]; const float* bts  = (const float*)d_in[18];
    const float* Wra  = (const float*)d_in[19]; const float* bra  = (const float*)d_in[20];
    const float* Wrs  = (const float*)d_in[21]; const float* brs  = (const float*)d_in[22];
    const float* Wrp1 = (const float*)d_in[23]; const float* brp1 = (const float*)d_in[24];
    const float* Wrp2 = (const float*)d_in[25]; const float* brp2 = (const float*)d_in[26];
    const float* Wsa  = (const float*)d_in[27]; const float* bsa  = (const float*)d_in[28];
    const float* Wss  = (const float*)d_in[29];
    const float* Wops = (const float*)d_in[30]; const float* bops = (const float*)d_in[31];
    const int* smk = (const int*)d_in[32];
    const int* nmk = (const int*)d_in[33];
    const int* hlk = (const int*)d_in[34];
    const int* sek = (const int*)d_in[35];

    float* out = (float*)d_out;
    float* ws  = (float*)d_ws;

    // output offsets (floats)
    const size_t O_NS    = 0;                           // B*L
    const size_t O_OP    = O_NS + (size_t)B_ * L_;      // B*OPS
    const size_t O_NODE  = O_OP + (size_t)B_ * OPS_;    // B*H
    const size_t O_CTX   = O_NODE + (size_t)B_ * H_;    // B*H
    const size_t O_EW    = O_CTX + (size_t)B_ * H_;     // B*L*H
    const size_t O_RPROB = O_EW + (size_t)B_ * L_ * H_; // B*R

    // workspace offsets (floats)
    float* c_     = ws;                       // 65536
    float* acat   = c_ + 65536;               // 131072
    float* gl     = acat + 131072;            // 65536
    float* glg    = gl + 65536;
    float* gr     = glg + 65536;
    float* grg    = gr + 65536;
    float* q      = grg + 65536;
    float* qT     = q + 65536;
    float* attn   = qT + 65536;               // 16384
    float* comb   = attn + 16384;             // 262144
    float* leaf   = comb + 262144;            // 131072
    float* rctx   = leaf + 131072;            // 1048576
    float* rclin  = rctx + 1048576;           // 1048576
    float* lsb    = rclin + 1048576;          // 65536
    float* ewp    = lsb + 65536;              // 1179648
    float* eobuf  = ewp + 1179648;            // 8388608 (reused: EOt then EOr)

    // 1. inputs-only prep
    k_prep<<<256, 256, 0, stream>>>(cur, padh, left, sek, c_, acat);
    k_ew<<<4608, 256, 0, stream>>>(embw, npad, out + O_EW);

    // 2. node GEMMs
    gemm(c_,   Wl,  gl,  B_, H_, H_, stream);
    gemm(c_,   Wlg, glg, B_, H_, H_, stream);
    gemm(acat, Wr,  gr,  B_, H_, 2 * H_, stream);
    gemm(acat, Wrg, grg, B_, H_, 2 * H_, stream);
    k_node<<<256, 256, 0, stream>>>(gl, glg, gr, grg, bl, blg, br, brg, hlk,
                                    q, out + O_NODE, leaf);

    // 3. tree attention
    gemm(q, Wta, qT, B_, H_, H_, stream);                       // q @ W_tree_attn[:h]
    gemm(EO, Wta + (size_t)H_ * H_, eobuf, S_ * B_, H_, H_, stream);  // EO @ W_tree_attn[h:]
    k_tree_score<<<S_ * B_ / 4, 256, 0, stream>>>(qT, eobuf, bta, Wts, bts, smk, attn);
    k_softmax_tree<<<B_, 128, 0, stream>>>(attn);

    // 4. rule attention (reuse eobuf)
    gemm(EO, Wra, eobuf, S_ * B_, H_, H_, stream);              // EO @ W_rule_attn[:h]
    gemm(rsc, Wra + (size_t)H_ * H_, qT, R_, H_, H_, stream);   // RP -> reuse qT buffer? NO
    // (qT no longer needed after k_tree_score; safe to reuse as RP buffer)
    k_rule_score<<<S_ * B_, 256, 0, stream>>>(eobuf, qT, bra, Wrs, brs, smk, comb);
    k_softmax_rules<<<B_ * R_, 128, 0, stream>>>(comb, attn);

    // 5. contexts (current + rules), leaf assembly
    k_context<<<dim3(B_, 2), 256, 0, stream>>>(EO, attn, comb, out + O_CTX, leaf, rctx);

    // 6. rule_prob
    gemm(rctx, Wrp1, rclin, B_ * R_, H_, H_, stream);
    k_rp<<<B_, 256, 0, stream>>>(rclin, brp1, Wrp2, brp2, out + O_RPROB);

    // 7. num_score + op
    gemm(leaf, Wsa, lsb, B_, H_, 2 * H_, stream);                     // leaf @ W_sc_attn[:2h]
    gemm(out + O_EW, Wsa + (size_t)2 * H_ * H_, ewp, B_ * L_, H_, H_, stream);
    k_numscore<<<B_, 256, 0, stream>>>(lsb, ewp, bsa, Wss, nmk, out + O_NS);
    k_op<<<B_, 320, 0, stream>>>(leaf, Wops, bops, out + O_OP);
}

// Round 2
// 487.588 us; speedup vs baseline: 1.7508x; 1.7508x over previous
//
#include <hip/hip_runtime.h>
#include <hip/hip_bf16.h>

// Problem constants
#define B_ 128
#define S_ 128
#define H_ 512
#define R_ 16
#define IN_ 2
#define OPS_ 5
#define NPAD_ 16
#define L_ 18          // IN_ + NPAD_
#define NEGV (-1000000000000.0f)

typedef __bf16 bf16_t;
typedef bf16_t bf16x8 __attribute__((ext_vector_type(8)));
typedef float floatx4 __attribute__((ext_vector_type(4)));

__device__ __forceinline__ float fast_tanh(float x) {
    return 2.0f / (1.0f + __expf(-2.0f * x)) - 1.0f;
}
__device__ __forceinline__ float fast_sigmoid(float x) {
    return 1.0f / (1.0f + __expf(-x));
}
__device__ __forceinline__ unsigned short f2bf(float f) {   // RNE
    unsigned int u = __builtin_bit_cast(unsigned int, f);
    u += 0x7fff + ((u >> 16) & 1);
    return (unsigned short)(u >> 16);
}
__device__ __forceinline__ float bf2f(unsigned short u) {
    return __builtin_bit_cast(float, (unsigned int)u << 16);
}

// ---------------------------------------------------------------------------
// fp32 tiled GEMM (kept for small M cases): C[M,N] = A[M,K] @ W[K,N]
// ---------------------------------------------------------------------------
#define BM 64
#define BN 64
#define BK 16

__device__ __forceinline__ void gemm_f32_body(const float* __restrict__ A,
                                              const float* __restrict__ W,
                                              float* __restrict__ C,
                                              int M, int N, int K,
                                              float (*As)[BM + 4], float (*Bs)[BN]) {
    const int bm = blockIdx.y * BM;
    const int bn = blockIdx.x * BN;
    const int tid = threadIdx.x;

    const int tcol = (tid & 15) * 4;
    const int trow = (tid >> 4) * 4;
    const int a_row  = tid >> 2;
    const int a_col4 = (tid & 3) * 4;
    const int b_row  = tid >> 4;
    const int b_col4 = (tid & 15) * 4;

    float acc[4][4] = {};

    for (int k0 = 0; k0 < K; k0 += BK) {
        float4 av = make_float4(0.f, 0.f, 0.f, 0.f);
        const int am = bm + a_row;
        if (am < M) av = *(const float4*)(A + (size_t)am * K + k0 + a_col4);
        float4 bv = *(const float4*)(W + (size_t)(k0 + b_row) * N + bn + b_col4);
        __syncthreads();
        As[a_col4 + 0][a_row] = av.x;
        As[a_col4 + 1][a_row] = av.y;
        As[a_col4 + 2][a_row] = av.z;
        As[a_col4 + 3][a_row] = av.w;
        *(float4*)&Bs[b_row][b_col4] = bv;
        __syncthreads();

        #pragma unroll
        for (int k = 0; k < BK; ++k) {
            float4 a4 = *(const float4*)&As[k][trow];
            float4 b4 = *(const float4*)&Bs[k][tcol];
            float a[4] = {a4.x, a4.y, a4.z, a4.w};
            float b[4] = {b4.x, b4.y, b4.z, b4.w};
            #pragma unroll
            for (int i = 0; i < 4; ++i)
                #pragma unroll
                for (int j = 0; j < 4; ++j)
                    acc[i][j] += a[i] * b[j];
        }
    }

    #pragma unroll
    for (int i = 0; i < 4; ++i) {
        const int m = bm + trow + i;
        if (m < M) {
            float* crow = C + (size_t)m * N + bn + tcol;
            crow[0] = acc[i][0]; crow[1] = acc[i][1];
            crow[2] = acc[i][2]; crow[3] = acc[i][3];
        }
    }
}

__global__ __launch_bounds__(256) void gemm_f32(const float* __restrict__ A,
                                                const float* __restrict__ W,
                                                float* __restrict__ C,
                                                int M, int N, int K) {
    __shared__ float As[BK][BM + 4];
    __shared__ float Bs[BK][BN];
    gemm_f32_body(A, W, C, M, N, K, As, Bs);
}

// z-batched variant: 5 independent small GEMMs in one dispatch (all N=512)
struct GB5 {
    const float* A[5]; const float* W[5]; float* C[5];
    int M[5]; int K[5];
};
__global__ __launch_bounds__(256) void gemm_f32_b5(GB5 g) {
    __shared__ float As[BK][BM + 4];
    __shared__ float Bs[BK][BN];
    int z = blockIdx.z;
    gemm_f32_body(g.A[z], g.W[z], g.C[z], g.M[z], 512, g.K[z], As, Bs);
}

// ---------------------------------------------------------------------------
// bf16 MFMA GEMM:  C[M,N] = A[M,K](bf16,row-major) . B  where Bt[N,K] = B^T
// 128x128 block tile, 4 waves (2x2 of 64x64 wave tiles), BK=32, 16x16x32 MFMA.
// Requires M%128==0, N%128==0, K%32==0.
// ---------------------------------------------------------------------------
#define LSTR 40   // padded LDS row stride in bf16 elements (32 + 8)

template <bool BF16_OUT>
__global__ __launch_bounds__(256) void gemm_bf16_bt(const unsigned short* __restrict__ A,
                                                    const unsigned short* __restrict__ Bt,
                                                    void* __restrict__ Cv,
                                                    int M, int N, int K) {
    __shared__ unsigned short As[128 * LSTR];
    __shared__ unsigned short Bs[128 * LSTR];

    const int tid  = threadIdx.x;
    const int wid  = tid >> 6, lane = tid & 63;
    const int quad = lane >> 4, mn = lane & 15;
    const int wm = (wid & 1) * 64, wn = (wid >> 1) * 64;
    const int m0 = blockIdx.y * 128, n0 = blockIdx.x * 128;

    // staging: 512 16B-chunks per operand tile; thread t does chunk t and t+256
    const int sr = tid >> 2;            // 0..63
    const int sc = (tid & 3) * 8;       // 0,8,16,24

    floatx4 acc[4][4] = {};

    for (int k0 = 0; k0 < K; k0 += 32) {
        uint4 a0 = *(const uint4*)(A  + (size_t)(m0 + sr)      * K + k0 + sc);
        uint4 a1 = *(const uint4*)(A  + (size_t)(m0 + sr + 64) * K + k0 + sc);
        uint4 b0 = *(const uint4*)(Bt + (size_t)(n0 + sr)      * K + k0 + sc);
        uint4 b1 = *(const uint4*)(Bt + (size_t)(n0 + sr + 64) * K + k0 + sc);
        __syncthreads();
        *(uint4*)&As[sr * LSTR + sc]        = a0;
        *(uint4*)&As[(sr + 64) * LSTR + sc] = a1;
        *(uint4*)&Bs[sr * LSTR + sc]        = b0;
        *(uint4*)&Bs[(sr + 64) * LSTR + sc] = b1;
        __syncthreads();

        bf16x8 af[4], bfr[4];
        #pragma unroll
        for (int i = 0; i < 4; ++i)
            af[i] = *(const bf16x8*)&As[(wm + i * 16 + mn) * LSTR + quad * 8];
        #pragma unroll
        for (int j = 0; j < 4; ++j)
            bfr[j] = *(const bf16x8*)&Bs[(wn + j * 16 + mn) * LSTR + quad * 8];

        #pragma unroll
        for (int i = 0; i < 4; ++i)
            #pragma unroll
            for (int j = 0; j < 4; ++j)
                acc[i][j] = __builtin_amdgcn_mfma_f32_16x16x32_bf16(af[i], bfr[j], acc[i][j], 0, 0, 0);
    }

    // C/D layout: col = lane&15, row = quad*4 + reg   [verified m89/m91]
    #pragma unroll
    for (int i = 0; i < 4; ++i) {
        #pragma unroll
        for (int j = 0; j < 4; ++j) {
            #pragma unroll
            for (int r = 0; r < 4; ++r) {
                int row = m0 + wm + i * 16 + quad * 4 + r;
                int col = n0 + wn + j * 16 + mn;
                if (BF16_OUT)
                    ((unsigned short*)Cv)[(size_t)row * N + col] = f2bf(acc[i][j][r]);
                else
                    ((float*)Cv)[(size_t)row * N + col] = acc[i][j][r];
            }
        }
    }
}

// ---------------------------------------------------------------------------
// conversion / prep kernels
// ---------------------------------------------------------------------------
__global__ void k_cast_eo(const float* __restrict__ src, unsigned short* __restrict__ dst) {
    int i = (blockIdx.x * 256 + threadIdx.x) * 4;   // S*B*H elements, /4
    float4 v = *(const float4*)(src + i);
    ushort4 o;
    o.x = f2bf(v.x); o.y = f2bf(v.y); o.z = f2bf(v.z); o.w = f2bf(v.w);
    *(ushort4*)(dst + i) = o;
}

// transpose+cast 512x512 fp32 (k-major) -> bf16 [n][k], z selects one of 4 jobs
__global__ __launch_bounds__(256) void k_wtrans(const float* s0, const float* s1,
                                                const float* s2, const float* s3,
                                                unsigned short* d0, unsigned short* d1,
                                                unsigned short* d2, unsigned short* d3) {
    const float* S[4] = {s0, s1, s2, s3};
    unsigned short* D[4] = {d0, d1, d2, d3};
    const float* src = S[blockIdx.z];
    unsigned short* dst = D[blockIdx.z];
    __shared__ float t[32][33];
    int bx = blockIdx.x * 32, by = blockIdx.y * 32;   // bx: n, by: k
    int tx = threadIdx.x & 31, ty = threadIdx.x >> 5; // ty 0..7
    #pragma unroll
    for (int i = 0; i < 32; i += 8)
        t[ty + i][tx] = src[(size_t)(by + ty + i) * 512 + bx + tx];
    __syncthreads();
    #pragma unroll
    for (int i = 0; i < 32; i += 8)
        dst[(size_t)(bx + ty + i) * 512 + by + tx] = f2bf(t[tx][ty + i]);
}

__global__ void k_prep(const float* __restrict__ cur, const float* __restrict__ padh,
                       const float* __restrict__ left, const int* __restrict__ se,
                       float* __restrict__ c, float* __restrict__ acat) {
    int i = blockIdx.x * blockDim.x + threadIdx.x;   // B*H
    int b = i >> 9, j = i & 511;
    float cv = se[b] ? padh[j] : cur[i];
    c[i] = cv;
    acat[b * 1024 + j] = left[i];
    acat[b * 1024 + 512 + j] = cv;
}

// ew output (fp32) + bf16 copy for MFMA GEMM
__global__ void k_ew(const float* __restrict__ embw, const float* __restrict__ npade,
                     float* __restrict__ ew, unsigned short* __restrict__ ewb) {
    int i = blockIdx.x * blockDim.x + threadIdx.x;   // B*L*H
    int j = i & 511;
    int bl = i >> 9;
    int l = bl % L_;
    int b = bl / L_;
    float v = (l < IN_) ? embw[l * H_ + j] : npade[((size_t)b * NPAD_ + (l - IN_)) * H_ + j];
    ew[i] = v;
    ewb[i] = f2bf(v);
}

__global__ void k_node(const float* __restrict__ gl, const float* __restrict__ glg,
                       const float* __restrict__ gr, const float* __restrict__ grg,
                       const float* __restrict__ bl, const float* __restrict__ blg,
                       const float* __restrict__ br, const float* __restrict__ brg,
                       const int* __restrict__ hl,
                       float* __restrict__ q, float* __restrict__ node_out,
                       float* __restrict__ leaf) {
    int i = blockIdx.x * blockDim.x + threadIdx.x;   // B*H
    int b = i >> 9, j = i & 511;
    float nl = fast_tanh(gl[i] + bl[j]) * fast_sigmoid(glg[i] + blg[j]);
    float nr = fast_tanh(gr[i] + br[j]) * fast_sigmoid(grg[i] + brg[j]);
    float v = hl[b] ? nr : nl;
    q[i] = v;
    node_out[i] = v;
    leaf[b * 1024 + j] = v;
}

// tree attention scores (EOt now bf16, stride 512)
__global__ __launch_bounds__(256) void k_tree_score(const float* __restrict__ qT,
                                                    const unsigned short* __restrict__ EOt,
                                                    const float* __restrict__ b_ta,
                                                    const float* __restrict__ w_ts,
                                                    const float* __restrict__ b_ts,
                                                    const int* __restrict__ seq_mask,
                                                    float* __restrict__ ae) {
    int wid = threadIdx.x >> 6, lane = threadIdx.x & 63;
    int row = blockIdx.x * 4 + wid;      // row = s*B + b
    int s = row >> 7, b = row & 127;
    const unsigned short* eo = EOt + (size_t)row * H_;
    const float* qr = qT + b * H_;
    float acc = 0.f;
    #pragma unroll
    for (int it = 0; it < H_ / 64; ++it) {
        int j = lane + it * 64;
        acc += fast_tanh(qr[j] + bf2f(eo[j]) + b_ta[j]) * w_ts[j];
    }
    for (int o = 32; o > 0; o >>= 1) acc += __shfl_down(acc, o);
    if (lane == 0)
        ae[b * S_ + s] = seq_mask[b * S_ + s] ? NEGV : (acc + b_ts[0]);
}

__global__ __launch_bounds__(128) void k_softmax_tree(float* __restrict__ data) {
    __shared__ float red[2], red2[2];
    int t = threadIdx.x;
    float* row = data + (size_t)blockIdx.x * 128;
    float v = row[t];
    float m = v;
    for (int o = 32; o > 0; o >>= 1) m = fmaxf(m, __shfl_down(m, o));
    if ((t & 63) == 0) red[t >> 6] = m;
    __syncthreads();
    m = fmaxf(red[0], red[1]);
    float e = __expf(v - m);
    float ssum = e;
    for (int o = 32; o > 0; o >>= 1) ssum += __shfl_down(ssum, o);
    if ((t & 63) == 0) red2[t >> 6] = ssum;
    __syncthreads();
    row[t] = e / (red2[0] + red2[1]);
}

// rule scores (EOr now bf16, stride 512)
__global__ __launch_bounds__(256) void k_rule_score(const unsigned short* __restrict__ EOr,
                                                    const float* __restrict__ RP,
                                                    const float* __restrict__ b_ra,
                                                    const float* __restrict__ w_rs,
                                                    const float* __restrict__ b_rs,
                                                    const int* __restrict__ seq_mask,
                                                    float* __restrict__ comb) {
    __shared__ float ed[H_];
    int row = blockIdx.x;                 // s*B + b
    int s = row >> 7, b = row & 127;
    for (int j = threadIdx.x; j < H_; j += 256)
        ed[j] = bf2f(EOr[(size_t)row * H_ + j]) + b_ra[j];
    __syncthreads();
    int wid = threadIdx.x >> 6, lane = threadIdx.x & 63;
    bool masked = seq_mask[b * S_ + s] != 0;
    #pragma unroll
    for (int rr = 0; rr < 4; ++rr) {
        int r = wid * 4 + rr;
        float acc = 0.f;
        #pragma unroll
        for (int it = 0; it < 8; ++it) {
            int j = lane + it * 64;
            acc += fast_tanh(ed[j] + RP[r * H_ + j]) * w_rs[j];
        }
        for (int o = 32; o > 0; o >>= 1) acc += __shfl_down(acc, o);
        if (lane == 0)
            comb[((size_t)b * R_ + r) * S_ + s] = masked ? NEGV : (acc + b_rs[0]);
    }
}

__global__ __launch_bounds__(128) void k_softmax_rules(float* __restrict__ comb,
                                                       const float* __restrict__ attn) {
    __shared__ float red[2], red2[2];
    int br = blockIdx.x;
    int b = br >> 4;
    int t = threadIdx.x;
    float* row = comb + (size_t)br * 128;
    float v = row[t];
    float m = v;
    for (int o = 32; o > 0; o >>= 1) m = fmaxf(m, __shfl_down(m, o));
    if ((t & 63) == 0) red[t >> 6] = m;
    __syncthreads();
    m = fmaxf(red[0], red[1]);
    float e = __expf(v - m);
    float ssum = e;
    for (int o = 32; o > 0; o >>= 1) ssum += __shfl_down(ssum, o);
    if ((t & 63) == 0) red2[t >> 6] = ssum;
    __syncthreads();
    row[t] = e / (red2[0] + red2[1]) + 0.2f * attn[b * 128 + t];
}

// contexts; rctx now written as bf16 for the MFMA GEMM
__global__ __launch_bounds__(256) void k_context(const float* __restrict__ EO,
                                                 const float* __restrict__ attn,
                                                 const float* __restrict__ comb,
                                                 float* __restrict__ ctx_out,
                                                 float* __restrict__ leaf,
                                                 unsigned short* __restrict__ rctx) {
    __shared__ float at[S_];
    __shared__ float cb[R_ * S_];
    int b = blockIdx.x;
    int j = blockIdx.y * 256 + threadIdx.x;
    if (threadIdx.x < S_) at[threadIdx.x] = attn[b * S_ + threadIdx.x];
    for (int i = threadIdx.x; i < R_ * S_; i += 256) cb[i] = comb[(size_t)b * R_ * S_ + i];
    __syncthreads();
    float ctx = 0.f;
    float rc[R_] = {};
    for (int s = 0; s < S_; ++s) {
        float eo = EO[((size_t)s * B_ + b) * H_ + j];
        ctx += at[s] * eo;
        #pragma unroll
        for (int r = 0; r < R_; ++r) rc[r] += cb[r * S_ + s] * eo;
    }
    ctx_out[b * H_ + j] = ctx;
    leaf[b * 1024 + 512 + j] = ctx;
    #pragma unroll
    for (int r = 0; r < R_; ++r) rctx[((size_t)b * R_ + r) * H_ + j] = f2bf(rc[r]);
}

__global__ __launch_bounds__(256) void k_rp(const float* __restrict__ rclin,
                                            const float* __restrict__ b_rp1,
                                            const float* __restrict__ w_rp2,
                                            const float* __restrict__ b_rp2,
                                            float* __restrict__ prob) {
    __shared__ float sc[R_];
    int b = blockIdx.x;
    int wid = threadIdx.x >> 6, lane = threadIdx.x & 63;
    #pragma unroll
    for (int rr = 0; rr < 4; ++rr) {
        int r = wid * 4 + rr;
        float acc = 0.f;
        #pragma unroll
        for (int it = 0; it < 8; ++it) {
            int j = lane + it * 64;
            acc += fast_tanh(rclin[((size_t)b * R_ + r) * H_ + j] + b_rp1[j]) * w_rp2[j];
        }
        for (int o = 32; o > 0; o >>= 1) acc += __shfl_down(acc, o);
        if (lane == 0) sc[r] = acc + b_rp2[0];
    }
    __syncthreads();
    if (threadIdx.x < R_) {
        float m = -1e30f;
        for (int r = 0; r < R_; ++r) m = fmaxf(m, sc[r]);
        float sum = 0.f;
        for (int r = 0; r < R_; ++r) sum += __expf(sc[r] - m);
        prob[b * R_ + threadIdx.x] = __expf(sc[threadIdx.x] - m) / sum;
    }
}

__global__ __launch_bounds__(256) void k_numscore(const float* __restrict__ ls,
                                                  const float* __restrict__ ewp,
                                                  const float* __restrict__ b_sc,
                                                  const float* __restrict__ w_scs,
                                                  const int* __restrict__ mask_nums,
                                                  float* __restrict__ out) {
    __shared__ float lsd[H_];
    int b = blockIdx.x;
    for (int j = threadIdx.x; j < H_; j += 256) lsd[j] = ls[b * H_ + j] + b_sc[j];
    __syncthreads();
    int wid = threadIdx.x >> 6, lane = threadIdx.x & 63;
    for (int l = wid; l < L_; l += 4) {
        float acc = 0.f;
        #pragma unroll
        for (int it = 0; it < 8; ++it) {
            int j = lane + it * 64;
            acc += fast_tanh(lsd[j] + ewp[((size_t)b * L_ + l) * H_ + j]) * w_scs[j];
        }
        for (int o = 32; o > 0; o >>= 1) acc += __shfl_down(acc, o);
        if (lane == 0) out[b * L_ + l] = mask_nums[b * L_ + l] ? NEGV : acc;
    }
}

__global__ __launch_bounds__(320) void k_op(const float* __restrict__ leaf,
                                            const float* __restrict__ Wops,
                                            const float* __restrict__ bops,
                                            float* __restrict__ out) {
    int b = blockIdx.x;
    int wid = threadIdx.x / 64, lane = threadIdx.x % 64;
    float acc = 0.f;
    #pragma unroll
    for (int it = 0; it < 16; ++it) {
        int k = lane + it * 64;
        acc += leaf[b * 1024 + k] * Wops[k * OPS_ + wid];
    }
    for (int o = 32; o > 0; o >>= 1) acc += __shfl_down(acc, o);
    if (lane == 0) out[b * OPS_ + wid] = acc + bops[wid];
}

// ---------------------------------------------------------------------------
static inline void gemm(const float* A, const float* W, float* C, int M, int N, int K,
                        hipStream_t s) {
    dim3 grid(N / BN, (M + BM - 1) / BM);
    gemm_f32<<<grid, 256, 0, s>>>(A, W, C, M, N, K);
}
template <bool BF16_OUT>
static inline void gemm_bf(const unsigned short* A, const unsigned short* Bt, void* C,
                           int M, int N, int K, hipStream_t s) {
    dim3 grid(N / 128, M / 128);
    gemm_bf16_bt<BF16_OUT><<<grid, 256, 0, s>>>(A, Bt, C, M, N, K);
}

extern "C" void kernel_launch(void* const* d_in, const int* in_sizes, int n_in,
                              void* d_out, int out_size, void* d_ws, size_t ws_size,
                              hipStream_t stream) {
    const float* EO   = (const float*)d_in[0];
    const float* cur  = (const float*)d_in[1];
    const float* left = (const float*)d_in[2];
    const float* padh = (const float*)d_in[3];
    const float* npad = (const float*)d_in[4];
    const float* rsc  = (const float*)d_in[5];
    const float* embw = (const float*)d_in[6];
    const float* Wl   = (const float*)d_in[7];  const float* bl   = (const float*)d_in[8];
    const float* Wlg  = (const float*)d_in[9];  const float* blg  = (const float*)d_in[10];
    const float* Wr   = (const float*)d_in[11]; const float* br   = (const float*)d_in[12];
    const float* Wrg  = (const float*)d_in[13]; const float* brg  = (const float*)d_in[14];
    const float* Wta  = (const float*)d_in[15]; const float* bta  = (const float*)d_in[16];
    const float* Wts  = (const float*)d_in[17]; const float* bts  = (const float*)d_in[18];
    const float* Wra  = (const float*)d_in[19]; const float* bra  = (const float*)d_in[20];
    const float* Wrs  = (const float*)d_in[21]; const float* brs  = (const float*)d_in[22];
    const float* Wrp1 = (const float*)d_in[23]; const float* brp1 = (const float*)d_in[24];
    const float* Wrp2 = (const float*)d_in[25]; const float* brp2 = (const float*)d_in[26];
    const float* Wsa  = (const float*)d_in[27]; const float* bsa  = (const float*)d_in[28];
    const float* Wss  = (const float*)d_in[29];
    const float* Wops = (const float*)d_in[30]; const float* bops = (const float*)d_in[31];
    const int* smk = (const int*)d_in[32];
    const int* nmk = (const int*)d_in[33];
    const int* hlk = (const int*)d_in[34];
    const int* sek = (const int*)d_in[35];

    float* out = (float*)d_out;
    float* ws  = (float*)d_ws;

    // output offsets (floats)
    const size_t O_NS    = 0;
    const size_t O_OP    = O_NS + (size_t)B_ * L_;
    const size_t O_NODE  = O_OP + (size_t)B_ * OPS_;
    const size_t O_CTX   = O_NODE + (size_t)B_ * H_;
    const size_t O_EW    = O_CTX + (size_t)B_ * H_;
    const size_t O_RPROB = O_EW + (size_t)B_ * L_ * H_;

    // ---- workspace layout (float units) ----
    float* c_     = ws;                        // 65536
    float* acat   = c_ + 65536;                // 131072
    float* gl     = acat + 131072;             // 65536
    float* glg    = gl + 65536;
    float* gr     = glg + 65536;
    float* grg    = gr + 65536;
    float* q      = grg + 65536;               // 65536
    float* qT     = q + 65536;                 // 65536
    float* rp_buf = qT + 65536;                // 8192  (R x H projection)
    float* attn   = rp_buf + 8192;             // 16384
    float* comb   = attn + 16384;              // 262144
    float* leaf   = comb + 262144;             // 131072
    float* lsb    = leaf + 131072;             // 65536
    unsigned short* EO_bf   = (unsigned short*)(lsb + 65536);     // 8388608 us = 4194304 f
    unsigned short* ew_bf   = (unsigned short*)(EO_bf + 8388608); // 2359296 us = 1179648 f
    unsigned short* Wt_tree = (unsigned short*)(ew_bf + 2359296); // 262144 us
    unsigned short* Wt_rule = Wt_tree + 262144;                   // 262144 us
    unsigned short* Wrp1t   = Wt_rule + 262144;                   // 262144 us
    unsigned short* Wsa2t   = Wrp1t + 262144;                     // 262144 us
    unsigned short* rctx_bf = Wsa2t + 262144;                     // 1048576 us = 524288 f
    float* bigreg = (float*)(rctx_bf + 1048576);  // 4194304 floats region:
    unsigned short* eobuf = (unsigned short*)bigreg;  // 8388608 us (steps tree/rule)
    float* rclin = bigreg;                            // 1048576 f (aliases eobuf, later)
    float* ewp   = bigreg + 1048576;                  // 1179648 f (aliases eobuf, later)
    // total: ~46.8 MB

    // 1. prep + casts (input-only)
    k_prep<<<256, 256, 0, stream>>>(cur, padh, left, sek, c_, acat);
    k_ew<<<4608, 256, 0, stream>>>(embw, npad, out + O_EW, ew_bf);
    k_cast_eo<<<8192, 256, 0, stream>>>(EO, EO_bf);
    k_wtrans<<<dim3(16, 16, 4), 256, 0, stream>>>(
        Wta + (size_t)H_ * H_, Wra, Wrp1, Wsa + (size_t)2 * H_ * H_,
        Wt_tree, Wt_rule, Wrp1t, Wsa2t);

    // 2. five independent small GEMMs, one dispatch
    GB5 g;
    g.A[0] = c_;   g.W[0] = Wl;                    g.C[0] = gl;     g.M[0] = B_;  g.K[0] = H_;
    g.A[1] = c_;   g.W[1] = Wlg;                   g.C[1] = glg;    g.M[1] = B_;  g.K[1] = H_;
    g.A[2] = acat; g.W[2] = Wr;                    g.C[2] = gr;     g.M[2] = B_;  g.K[2] = 2 * H_;
    g.A[3] = acat; g.W[3] = Wrg;                   g.C[3] = grg;    g.M[3] = B_;  g.K[3] = 2 * H_;
    g.A[4] = rsc;  g.W[4] = Wra + (size_t)H_ * H_; g.C[4] = rp_buf; g.M[4] = R_;  g.K[4] = H_;
    gemm_f32_b5<<<dim3(8, 2, 5), 256, 0, stream>>>(g);
    k_node<<<256, 256, 0, stream>>>(gl, glg, gr, grg, bl, blg, br, brg, hlk,
                                    q, out + O_NODE, leaf);

    // 3. tree attention
    gemm(q, Wta, qT, B_, H_, H_, stream);                            // q @ W_tree_attn[:h]
    gemm_bf<true>(EO_bf, Wt_tree, eobuf, S_ * B_, H_, H_, stream);   // EO @ W_tree_attn[h:]
    k_tree_score<<<S_ * B_ / 4, 256, 0, stream>>>(qT, eobuf, bta, Wts, bts, smk, attn);
    k_softmax_tree<<<B_, 128, 0, stream>>>(attn);

    // 4. rule attention (eobuf reused)
    gemm_bf<true>(EO_bf, Wt_rule, eobuf, S_ * B_, H_, H_, stream);   // EO @ W_rule_attn[:h]
    k_rule_score<<<S_ * B_, 256, 0, stream>>>(eobuf, rp_buf, bra, Wrs, brs, smk, comb);
    k_softmax_rules<<<B_ * R_, 128, 0, stream>>>(comb, attn);

    // 5. contexts
    k_context<<<dim3(B_, 2), 256, 0, stream>>>(EO, attn, comb, out + O_CTX, leaf, rctx_bf);

    // 6. rule_prob  (rclin aliases eobuf region — eobuf dead after k_rule_score)
    gemm_bf<false>(rctx_bf, Wrp1t, rclin, B_ * R_, H_, H_, stream);
    k_rp<<<B_, 256, 0, stream>>>(rclin, brp1, Wrp2, brp2, out + O_RPROB);

    // 7. num_score + op
    gemm(leaf, Wsa, lsb, B_, H_, 2 * H_, stream);                    // leaf @ W_sc_attn[:2h]
    gemm_bf<false>(ew_bf, Wsa2t, ewp, B_ * L_, H_, H_, stream);      // ew @ W_sc_attn[2h:]
    k_numscore<<<B_, 256, 0, stream>>>(lsb, ewp, bsa, Wss, nmk, out + O_NS);
    k_op<<<B_, 320, 0, stream>>>(leaf, Wops, bops, out + O_OP);
}

// Round 3
// 442.708 us; speedup vs baseline: 1.9282x; 1.1014x over previous
//
#include <hip/hip_runtime.h>
#include <hip/hip_bf16.h>

// Problem constants
#define B_ 128
#define S_ 128
#define H_ 512
#define R_ 16
#define IN_ 2
#define OPS_ 5
#define NPAD_ 16
#define L_ 18          // IN_ + NPAD_
#define NEGV (-1000000000000.0f)
#define C2_ (-2.885390081777927f)   // -2*log2(e):  tanh(x) = 2*rcp(1+exp2(C2*x)) - 1

typedef __bf16 bf16_t;
typedef bf16_t bf16x8 __attribute__((ext_vector_type(8)));
typedef float floatx4 __attribute__((ext_vector_type(4)));

__device__ __forceinline__ float rcp_f(float x) { return __builtin_amdgcn_rcpf(x); }
__device__ __forceinline__ float exp2_f(float x) { return __builtin_amdgcn_exp2f(x); }

__device__ __forceinline__ float fast_tanh(float x) {
    return 2.0f * rcp_f(1.0f + exp2_f(C2_ * x)) - 1.0f;
}
__device__ __forceinline__ float fast_sigmoid(float x) {
    return rcp_f(1.0f + exp2_f(-1.4426950408889634f * x));
}
__device__ __forceinline__ unsigned short f2bf(float f) {   // RNE
    unsigned int u = __builtin_bit_cast(unsigned int, f);
    u += 0x7fff + ((u >> 16) & 1);
    return (unsigned short)(u >> 16);
}
__device__ __forceinline__ float bf2f(unsigned short u) {
    return __builtin_bit_cast(float, (unsigned int)u << 16);
}

// ---------------------------------------------------------------------------
// fp32 tiled GEMM (small M cases): C[M,N] = A[M,K] @ W[K,N]
// ---------------------------------------------------------------------------
#define BM 64
#define BN 64
#define BK 16

__device__ __forceinline__ void gemm_f32_body(const float* __restrict__ A,
                                              const float* __restrict__ W,
                                              float* __restrict__ C,
                                              int M, int N, int K,
                                              float (*As)[BM + 4], float (*Bs)[BN]) {
    const int bm = blockIdx.y * BM;
    const int bn = blockIdx.x * BN;
    const int tid = threadIdx.x;

    const int tcol = (tid & 15) * 4;
    const int trow = (tid >> 4) * 4;
    const int a_row  = tid >> 2;
    const int a_col4 = (tid & 3) * 4;
    const int b_row  = tid >> 4;
    const int b_col4 = (tid & 15) * 4;

    float acc[4][4] = {};

    for (int k0 = 0; k0 < K; k0 += BK) {
        float4 av = make_float4(0.f, 0.f, 0.f, 0.f);
        const int am = bm + a_row;
        if (am < M) av = *(const float4*)(A + (size_t)am * K + k0 + a_col4);
        float4 bv = *(const float4*)(W + (size_t)(k0 + b_row) * N + bn + b_col4);
        __syncthreads();
        As[a_col4 + 0][a_row] = av.x;
        As[a_col4 + 1][a_row] = av.y;
        As[a_col4 + 2][a_row] = av.z;
        As[a_col4 + 3][a_row] = av.w;
        *(float4*)&Bs[b_row][b_col4] = bv;
        __syncthreads();

        #pragma unroll
        for (int k = 0; k < BK; ++k) {
            float4 a4 = *(const float4*)&As[k][trow];
            float4 b4 = *(const float4*)&Bs[k][tcol];
            float a[4] = {a4.x, a4.y, a4.z, a4.w};
            float b[4] = {b4.x, b4.y, b4.z, b4.w};
            #pragma unroll
            for (int i = 0; i < 4; ++i)
                #pragma unroll
                for (int j = 0; j < 4; ++j)
                    acc[i][j] += a[i] * b[j];
        }
    }

    #pragma unroll
    for (int i = 0; i < 4; ++i) {
        const int m = bm + trow + i;
        if (m < M) {
            float* crow = C + (size_t)m * N + bn + tcol;
            crow[0] = acc[i][0]; crow[1] = acc[i][1];
            crow[2] = acc[i][2]; crow[3] = acc[i][3];
        }
    }
}

__global__ __launch_bounds__(256) void gemm_f32(const float* __restrict__ A,
                                                const float* __restrict__ W,
                                                float* __restrict__ C,
                                                int M, int N, int K) {
    __shared__ float As[BK][BM + 4];
    __shared__ float Bs[BK][BN];
    gemm_f32_body(A, W, C, M, N, K, As, Bs);
}

struct GB5 {
    const float* A[5]; const float* W[5]; float* C[5];
    int M[5]; int K[5];
};
__global__ __launch_bounds__(256) void gemm_f32_b5(GB5 g) {
    __shared__ float As[BK][BM + 4];
    __shared__ float Bs[BK][BN];
    int z = blockIdx.z;
    gemm_f32_body(g.A[z], g.W[z], g.C[z], g.M[z], 512, g.K[z], As, Bs);
}

// ---------------------------------------------------------------------------
// bf16 MFMA GEMM:  C[M,N] = A[M,K](bf16,row-major) . B  where Bt[N,K] = B^T
// ---------------------------------------------------------------------------
#define LSTR 40

template <bool BF16_OUT>
__global__ __launch_bounds__(256) void gemm_bf16_bt(const unsigned short* __restrict__ A,
                                                    const unsigned short* __restrict__ Bt,
                                                    void* __restrict__ Cv,
                                                    int M, int N, int K) {
    __shared__ unsigned short As[128 * LSTR];
    __shared__ unsigned short Bs[128 * LSTR];

    const int tid  = threadIdx.x;
    const int wid  = tid >> 6, lane = tid & 63;
    const int quad = lane >> 4, mn = lane & 15;
    const int wm = (wid & 1) * 64, wn = (wid >> 1) * 64;
    const int m0 = blockIdx.y * 128, n0 = blockIdx.x * 128;

    const int sr = tid >> 2;
    const int sc = (tid & 3) * 8;

    floatx4 acc[4][4] = {};

    for (int k0 = 0; k0 < K; k0 += 32) {
        uint4 a0 = *(const uint4*)(A  + (size_t)(m0 + sr)      * K + k0 + sc);
        uint4 a1 = *(const uint4*)(A  + (size_t)(m0 + sr + 64) * K + k0 + sc);
        uint4 b0 = *(const uint4*)(Bt + (size_t)(n0 + sr)      * K + k0 + sc);
        uint4 b1 = *(const uint4*)(Bt + (size_t)(n0 + sr + 64) * K + k0 + sc);
        __syncthreads();
        *(uint4*)&As[sr * LSTR + sc]        = a0;
        *(uint4*)&As[(sr + 64) * LSTR + sc] = a1;
        *(uint4*)&Bs[sr * LSTR + sc]        = b0;
        *(uint4*)&Bs[(sr + 64) * LSTR + sc] = b1;
        __syncthreads();

        bf16x8 af[4], bfr[4];
        #pragma unroll
        for (int i = 0; i < 4; ++i)
            af[i] = *(const bf16x8*)&As[(wm + i * 16 + mn) * LSTR + quad * 8];
        #pragma unroll
        for (int j = 0; j < 4; ++j)
            bfr[j] = *(const bf16x8*)&Bs[(wn + j * 16 + mn) * LSTR + quad * 8];

        #pragma unroll
        for (int i = 0; i < 4; ++i)
            #pragma unroll
            for (int j = 0; j < 4; ++j)
                acc[i][j] = __builtin_amdgcn_mfma_f32_16x16x32_bf16(af[i], bfr[j], acc[i][j], 0, 0, 0);
    }

    #pragma unroll
    for (int i = 0; i < 4; ++i) {
        #pragma unroll
        for (int j = 0; j < 4; ++j) {
            #pragma unroll
            for (int r = 0; r < 4; ++r) {
                int row = m0 + wm + i * 16 + quad * 4 + r;
                int col = n0 + wn + j * 16 + mn;
                if (BF16_OUT)
                    ((unsigned short*)Cv)[(size_t)row * N + col] = f2bf(acc[i][j][r]);
                else
                    ((float*)Cv)[(size_t)row * N + col] = acc[i][j][r];
            }
        }
    }
}

// ---------------------------------------------------------------------------
// prep kernels
// ---------------------------------------------------------------------------
__global__ void k_cast_eo(const float* __restrict__ src, unsigned short* __restrict__ dst) {
    int i = (blockIdx.x * 256 + threadIdx.x) * 4;
    float4 v = *(const float4*)(src + i);
    ushort4 o;
    o.x = f2bf(v.x); o.y = f2bf(v.y); o.z = f2bf(v.z); o.w = f2bf(v.w);
    *(ushort4*)(dst + i) = o;
}

__global__ __launch_bounds__(256) void k_wtrans(const float* s0, const float* s1,
                                                const float* s2, const float* s3,
                                                unsigned short* d0, unsigned short* d1,
                                                unsigned short* d2, unsigned short* d3) {
    const float* S[4] = {s0, s1, s2, s3};
    unsigned short* D[4] = {d0, d1, d2, d3};
    const float* src = S[blockIdx.z];
    unsigned short* dst = D[blockIdx.z];
    __shared__ float t[32][33];
    int bx = blockIdx.x * 32, by = blockIdx.y * 32;
    int tx = threadIdx.x & 31, ty = threadIdx.x >> 5;
    #pragma unroll
    for (int i = 0; i < 32; i += 8)
        t[ty + i][tx] = src[(size_t)(by + ty + i) * 512 + bx + tx];
    __syncthreads();
    #pragma unroll
    for (int i = 0; i < 32; i += 8)
        dst[(size_t)(bx + ty + i) * 512 + by + tx] = f2bf(t[tx][ty + i]);
}

__global__ void k_prep(const float* __restrict__ cur, const float* __restrict__ padh,
                       const float* __restrict__ left, const int* __restrict__ se,
                       float* __restrict__ c, float* __restrict__ acat) {
    int i = blockIdx.x * blockDim.x + threadIdx.x;
    int b = i >> 9, j = i & 511;
    float cv = se[b] ? padh[j] : cur[i];
    c[i] = cv;
    acat[b * 1024 + j] = left[i];
    acat[b * 1024 + 512 + j] = cv;
}

__global__ void k_ew(const float* __restrict__ embw, const float* __restrict__ npade,
                     float* __restrict__ ew, unsigned short* __restrict__ ewb) {
    int i = blockIdx.x * blockDim.x + threadIdx.x;
    int j = i & 511;
    int bl = i >> 9;
    int l = bl % L_;
    int b = bl / L_;
    float v = (l < IN_) ? embw[l * H_ + j] : npade[((size_t)b * NPAD_ + (l - IN_)) * H_ + j];
    ew[i] = v;
    ewb[i] = f2bf(v);
}

__global__ void k_node(const float* __restrict__ gl, const float* __restrict__ glg,
                       const float* __restrict__ gr, const float* __restrict__ grg,
                       const float* __restrict__ bl, const float* __restrict__ blg,
                       const float* __restrict__ br, const float* __restrict__ brg,
                       const int* __restrict__ hl,
                       float* __restrict__ q, float* __restrict__ node_out,
                       float* __restrict__ leaf) {
    int i = blockIdx.x * blockDim.x + threadIdx.x;
    int b = i >> 9, j = i & 511;
    float nl = fast_tanh(gl[i] + bl[j]) * fast_sigmoid(glg[i] + blg[j]);
    float nr = fast_tanh(gr[i] + br[j]) * fast_sigmoid(grg[i] + brg[j]);
    float v = hl[b] ? nr : nl;
    q[i] = v;
    node_out[i] = v;
    leaf[b * 1024 + j] = v;
}

// ---------------------------------------------------------------------------
// score kernels: wave-per-row, register-resident, division-free, mask-skip
// score = sum_j w[j]*tanh(x_j) = sum_j (2w[j])*rcp(1+exp2(C2*x_j)) - sum_j w[j]
// ---------------------------------------------------------------------------

// tree: x = qT[b] + EOt[s,b] + b_ta ; out ae[b][s]
__global__ __launch_bounds__(256) void k_tree_score2(const float* __restrict__ qT,
                                                     const unsigned short* __restrict__ EOt,
                                                     const float* __restrict__ b_ta,
                                                     const float* __restrict__ w_ts,
                                                     const float* __restrict__ b_ts,
                                                     const int* __restrict__ sm,
                                                     float* __restrict__ ae) {
    int wid = threadIdx.x >> 6, lane = threadIdx.x & 63;
    int row = blockIdx.x * 4 + wid;   // s*B + b
    int s = row >> 7, b = row & 127;
    bool masked = sm[b * S_ + s] != 0;
    if (masked) {
        if (lane == 0) ae[b * S_ + s] = NEGV;
        return;
    }
    int j0 = lane * 8;
    uint4 ev = *(const uint4*)(EOt + (size_t)row * H_ + j0);
    const unsigned short* ep = (const unsigned short*)&ev;
    float4 q0 = *(const float4*)(qT + b * H_ + j0);
    float4 q1 = *(const float4*)(qT + b * H_ + j0 + 4);
    float4 t0 = *(const float4*)(b_ta + j0);
    float4 t1 = *(const float4*)(b_ta + j0 + 4);
    float4 w0 = *(const float4*)(w_ts + j0);
    float4 w1 = *(const float4*)(w_ts + j0 + 4);
    float qc[8] = {C2_*(q0.x+t0.x), C2_*(q0.y+t0.y), C2_*(q0.z+t0.z), C2_*(q0.w+t0.w),
                   C2_*(q1.x+t1.x), C2_*(q1.y+t1.y), C2_*(q1.z+t1.z), C2_*(q1.w+t1.w)};
    float w[8] = {w0.x, w0.y, w0.z, w0.w, w1.x, w1.y, w1.z, w1.w};
    float wsum = 0.f;
    #pragma unroll
    for (int k = 0; k < 8; ++k) wsum += w[k];
    float acc = -wsum;
    #pragma unroll
    for (int k = 0; k < 8; ++k) {
        float y = fmaf(C2_, bf2f(ep[k]), qc[k]);
        float rc = rcp_f(1.0f + exp2_f(y));
        acc = fmaf(2.0f * w[k], rc, acc);
    }
    #pragma unroll
    for (int o = 32; o > 0; o >>= 1) acc += __shfl_xor(acc, o);
    if (lane == 0) ae[b * S_ + s] = acc + b_ts[0];
}

// rule: x = EOr[s,b] + RP[r] + b_ra ; out comb[b][r][s]
__global__ __launch_bounds__(256) void k_rule_score2(const unsigned short* __restrict__ EOr,
                                                     const float* __restrict__ RP,
                                                     const float* __restrict__ b_ra,
                                                     const float* __restrict__ w_rs,
                                                     const float* __restrict__ b_rs,
                                                     const int* __restrict__ sm,
                                                     float* __restrict__ comb) {
    int wid = threadIdx.x >> 6, lane = threadIdx.x & 63;
    int row = blockIdx.x * 4 + wid;   // s*B + b
    int s = row >> 7, b = row & 127;
    bool masked = sm[b * S_ + s] != 0;
    if (masked) {
        if (lane < R_) comb[((size_t)b * R_ + lane) * S_ + s] = NEGV;
        return;
    }
    int j0 = lane * 8;
    uint4 ev = *(const uint4*)(EOr + (size_t)row * H_ + j0);
    const unsigned short* ep = (const unsigned short*)&ev;
    float4 a0 = *(const float4*)(b_ra + j0);
    float4 a1 = *(const float4*)(b_ra + j0 + 4);
    float4 w0 = *(const float4*)(w_rs + j0);
    float4 w1 = *(const float4*)(w_rs + j0 + 4);
    float ba[8] = {a0.x, a0.y, a0.z, a0.w, a1.x, a1.y, a1.z, a1.w};
    float w2[8], ed[8];
    float wsum = 0.f;
    {
        float w[8] = {w0.x, w0.y, w0.z, w0.w, w1.x, w1.y, w1.z, w1.w};
        #pragma unroll
        for (int k = 0; k < 8; ++k) {
            wsum += w[k];
            w2[k] = 2.0f * w[k];
            ed[k] = C2_ * (bf2f(ep[k]) + ba[k]);
        }
    }
    float bias = b_rs[0];
    #pragma unroll
    for (int r = 0; r < R_; ++r) {
        float4 r0 = *(const float4*)(RP + r * H_ + j0);
        float4 r1 = *(const float4*)(RP + r * H_ + j0 + 4);
        float rp[8] = {r0.x, r0.y, r0.z, r0.w, r1.x, r1.y, r1.z, r1.w};
        float acc = -wsum;
        #pragma unroll
        for (int k = 0; k < 8; ++k) {
            float y = fmaf(C2_, rp[k], ed[k]);
            float rc = rcp_f(1.0f + exp2_f(y));
            acc = fmaf(w2[k], rc, acc);
        }
        #pragma unroll
        for (int o = 32; o > 0; o >>= 1) acc += __shfl_xor(acc, o);
        if (lane == 0) comb[((size_t)b * R_ + r) * S_ + s] = acc + bias;
    }
}

__global__ __launch_bounds__(128) void k_softmax_tree(float* __restrict__ data) {
    __shared__ float red[2], red2[2];
    int t = threadIdx.x;
    float* row = data + (size_t)blockIdx.x * 128;
    float v = row[t];
    float m = v;
    for (int o = 32; o > 0; o >>= 1) m = fmaxf(m, __shfl_down(m, o));
    if ((t & 63) == 0) red[t >> 6] = m;
    __syncthreads();
    m = fmaxf(red[0], red[1]);
    float e = __expf(v - m);
    float ssum = e;
    for (int o = 32; o > 0; o >>= 1) ssum += __shfl_down(ssum, o);
    if ((t & 63) == 0) red2[t >> 6] = ssum;
    __syncthreads();
    row[t] = e * rcp_f(red2[0] + red2[1]);
}

__global__ __launch_bounds__(128) void k_softmax_rules(float* __restrict__ comb,
                                                       const float* __restrict__ attn) {
    __shared__ float red[2], red2[2];
    int br = blockIdx.x;
    int b = br >> 4;
    int t = threadIdx.x;
    float* row = comb + (size_t)br * 128;
    float v = row[t];
    float m = v;
    for (int o = 32; o > 0; o >>= 1) m = fmaxf(m, __shfl_down(m, o));
    if ((t & 63) == 0) red[t >> 6] = m;
    __syncthreads();
    m = fmaxf(red[0], red[1]);
    float e = __expf(v - m);
    float ssum = e;
    for (int o = 32; o > 0; o >>= 1) ssum += __shfl_down(ssum, o);
    if ((t & 63) == 0) red2[t >> 6] = ssum;
    __syncthreads();
    row[t] = e * rcp_f(red2[0] + red2[1]) + 0.2f * attn[b * 128 + t];
}

// contexts; masked s skipped (their weights are exactly 0 post-softmax)
__global__ __launch_bounds__(256) void k_context(const float* __restrict__ EO,
                                                 const float* __restrict__ attn,
                                                 const float* __restrict__ comb,
                                                 const int* __restrict__ sm,
                                                 float* __restrict__ ctx_out,
                                                 float* __restrict__ leaf,
                                                 unsigned short* __restrict__ rctx) {
    __shared__ float at[S_];
    __shared__ float cb[R_ * S_];
    __shared__ int smr[S_];
    int b = blockIdx.x;
    int j = blockIdx.y * 256 + threadIdx.x;
    if (threadIdx.x < S_) {
        at[threadIdx.x] = attn[b * S_ + threadIdx.x];
        smr[threadIdx.x] = sm[b * S_ + threadIdx.x];
    }
    for (int i = threadIdx.x; i < R_ * S_; i += 256) cb[i] = comb[(size_t)b * R_ * S_ + i];
    __syncthreads();
    float ctx = 0.f;
    float rc[R_] = {};
    for (int s = 0; s < S_; ++s) {
        if (smr[s]) continue;
        float eo = EO[((size_t)s * B_ + b) * H_ + j];
        ctx += at[s] * eo;
        #pragma unroll
        for (int r = 0; r < R_; ++r) rc[r] += cb[r * S_ + s] * eo;
    }
    ctx_out[b * H_ + j] = ctx;
    leaf[b * 1024 + 512 + j] = ctx;
    #pragma unroll
    for (int r = 0; r < R_; ++r) rctx[((size_t)b * R_ + r) * H_ + j] = f2bf(rc[r]);
}

// rule_prob: block per b; 4 waves x 4 r; then 16-wide softmax
__global__ __launch_bounds__(256) void k_rp2(const float* __restrict__ rclin,
                                             const float* __restrict__ b_rp1,
                                             const float* __restrict__ w_rp2,
                                             const float* __restrict__ b_rp2,
                                             float* __restrict__ prob) {
    __shared__ float sc[R_];
    int b = blockIdx.x;
    int wid = threadIdx.x >> 6, lane = threadIdx.x & 63;
    int j0 = lane * 8;
    float4 p0 = *(const float4*)(b_rp1 + j0);
    float4 p1 = *(const float4*)(b_rp1 + j0 + 4);
    float4 w0 = *(const float4*)(w_rp2 + j0);
    float4 w1 = *(const float4*)(w_rp2 + j0 + 4);
    float brc[8] = {C2_*p0.x, C2_*p0.y, C2_*p0.z, C2_*p0.w, C2_*p1.x, C2_*p1.y, C2_*p1.z, C2_*p1.w};
    float w[8] = {w0.x, w0.y, w0.z, w0.w, w1.x, w1.y, w1.z, w1.w};
    float wsum = 0.f;
    #pragma unroll
    for (int k = 0; k < 8; ++k) wsum += w[k];
    #pragma unroll
    for (int rr = 0; rr < 4; ++rr) {
        int r = wid * 4 + rr;
        const float* rl = rclin + ((size_t)b * R_ + r) * H_ + j0;
        float4 r0 = *(const float4*)(rl);
        float4 r1 = *(const float4*)(rl + 4);
        float rv[8] = {r0.x, r0.y, r0.z, r0.w, r1.x, r1.y, r1.z, r1.w};
        float acc = -wsum;
        #pragma unroll
        for (int k = 0; k < 8; ++k) {
            float y = fmaf(C2_, rv[k], brc[k]);
            float rc = rcp_f(1.0f + exp2_f(y));
            acc = fmaf(2.0f * w[k], rc, acc);
        }
        #pragma unroll
        for (int o = 32; o > 0; o >>= 1) acc += __shfl_xor(acc, o);
        if (lane == 0) sc[r] = acc + b_rp2[0];
    }
    __syncthreads();
    if (threadIdx.x < R_) {
        float m = -1e30f;
        for (int r = 0; r < R_; ++r) m = fmaxf(m, sc[r]);
        float sum = 0.f;
        for (int r = 0; r < R_; ++r) sum += __expf(sc[r] - m);
        prob[b * R_ + threadIdx.x] = __expf(sc[threadIdx.x] - m) * rcp_f(sum);
    }
}

// num_score: rows = B*L; x = lsb[b] + ewp[row] + b_sc ; masked -> NEG
__global__ __launch_bounds__(256) void k_numscore2(const float* __restrict__ lsb,
                                                   const unsigned short* __restrict__ ewp,
                                                   const float* __restrict__ b_sc,
                                                   const float* __restrict__ w_scs,
                                                   const int* __restrict__ mask_nums,
                                                   float* __restrict__ outp) {
    int wid = threadIdx.x >> 6, lane = threadIdx.x & 63;
    int row = blockIdx.x * 4 + wid;       // b*L + l
    if (row >= B_ * L_) return;
    int b = row / L_, l = row - b * L_;
    bool masked = mask_nums[b * L_ + l] != 0;
    if (masked) {
        if (lane == 0) outp[b * L_ + l] = NEGV;
        return;
    }
    int j0 = lane * 8;
    uint4 ev = *(const uint4*)(ewp + (size_t)row * H_ + j0);
    const unsigned short* ep = (const unsigned short*)&ev;
    float4 l0 = *(const float4*)(lsb + b * H_ + j0);
    float4 l1 = *(const float4*)(lsb + b * H_ + j0 + 4);
    float4 s0 = *(const float4*)(b_sc + j0);
    float4 s1 = *(const float4*)(b_sc + j0 + 4);
    float4 w0 = *(const float4*)(w_scs + j0);
    float4 w1 = *(const float4*)(w_scs + j0 + 4);
    float lc[8] = {C2_*(l0.x+s0.x), C2_*(l0.y+s0.y), C2_*(l0.z+s0.z), C2_*(l0.w+s0.w),
                   C2_*(l1.x+s1.x), C2_*(l1.y+s1.y), C2_*(l1.z+s1.z), C2_*(l1.w+s1.w)};
    float w[8] = {w0.x, w0.y, w0.z, w0.w, w1.x, w1.y, w1.z, w1.w};
    float wsum = 0.f;
    #pragma unroll
    for (int k = 0; k < 8; ++k) wsum += w[k];
    float acc = -wsum;
    #pragma unroll
    for (int k = 0; k < 8; ++k) {
        float y = fmaf(C2_, bf2f(ep[k]), lc[k]);
        float rc = rcp_f(1.0f + exp2_f(y));
        acc = fmaf(2.0f * w[k], rc, acc);
    }
    #pragma unroll
    for (int o = 32; o > 0; o >>= 1) acc += __shfl_xor(acc, o);
    if (lane == 0) outp[b * L_ + l] = acc;
}

__global__ __launch_bounds__(320) void k_op(const float* __restrict__ leaf,
                                            const float* __restrict__ Wops,
                                            const float* __restrict__ bops,
                                            float* __restrict__ out) {
    int b = blockIdx.x;
    int wid = threadIdx.x / 64, lane = threadIdx.x % 64;
    float acc = 0.f;
    #pragma unroll
    for (int it = 0; it < 16; ++it) {
        int k = lane + it * 64;
        acc += leaf[b * 1024 + k] * Wops[k * OPS_ + wid];
    }
    for (int o = 32; o > 0; o >>= 1) acc += __shfl_down(acc, o);
    if (lane == 0) out[b * OPS_ + wid] = acc + bops[wid];
}

// ---------------------------------------------------------------------------
static inline void gemm(const float* A, const float* W, float* C, int M, int N, int K,
                        hipStream_t s) {
    dim3 grid(N / BN, (M + BM - 1) / BM);
    gemm_f32<<<grid, 256, 0, s>>>(A, W, C, M, N, K);
}
template <bool BF16_OUT>
static inline void gemm_bf(const unsigned short* A, const unsigned short* Bt, void* C,
                           int M, int N, int K, hipStream_t s) {
    dim3 grid(N / 128, M / 128);
    gemm_bf16_bt<BF16_OUT><<<grid, 256, 0, s>>>(A, Bt, C, M, N, K);
}

extern "C" void kernel_launch(void* const* d_in, const int* in_sizes, int n_in,
                              void* d_out, int out_size, void* d_ws, size_t ws_size,
                              hipStream_t stream) {
    const float* EO   = (const float*)d_in[0];
    const float* cur  = (const float*)d_in[1];
    const float* left = (const float*)d_in[2];
    const float* padh = (const float*)d_in[3];
    const float* npad = (const float*)d_in[4];
    const float* rsc  = (const float*)d_in[5];
    const float* embw = (const float*)d_in[6];
    const float* Wl   = (const float*)d_in[7];  const float* bl   = (const float*)d_in[8];
    const float* Wlg  = (const float*)d_in[9];  const float* blg  = (const float*)d_in[10];
    const float* Wr   = (const float*)d_in[11]; const float* br   = (const float*)d_in[12];
    const float* Wrg  = (const float*)d_in[13]; const float* brg  = (const float*)d_in[14];
    const float* Wta  = (const float*)d_in[15]; const float* bta  = (const float*)d_in[16];
    const float* Wts  = (const float*)d_in[17]; const float* bts  = (const float*)d_in[18];
    const float* Wra  = (const float*)d_in[19]; const float* bra  = (const float*)d_in[20];
    const float* Wrs  = (const float*)d_in[21]; const float* brs  = (const float*)d_in[22];
    const float* Wrp1 = (const float*)d_in[23]; const float* brp1 = (const float*)d_in[24];
    const float* Wrp2 = (const float*)d_in[25]; const float* brp2 = (const float*)d_in[26];
    const float* Wsa  = (const float*)d_in[27]; const float* bsa  = (const float*)d_in[28];
    const float* Wss  = (const float*)d_in[29];
    const float* Wops = (const float*)d_in[30]; const float* bops = (const float*)d_in[31];
    const int* smk = (const int*)d_in[32];
    const int* nmk = (const int*)d_in[33];
    const int* hlk = (const int*)d_in[34];
    const int* sek = (const int*)d_in[35];

    float* out = (float*)d_out;
    float* ws  = (float*)d_ws;

    const size_t O_NS    = 0;
    const size_t O_OP    = O_NS + (size_t)B_ * L_;
    const size_t O_NODE  = O_OP + (size_t)B_ * OPS_;
    const size_t O_CTX   = O_NODE + (size_t)B_ * H_;
    const size_t O_EW    = O_CTX + (size_t)B_ * H_;
    const size_t O_RPROB = O_EW + (size_t)B_ * L_ * H_;

    // ---- workspace layout (float units) ----
    float* c_     = ws;
    float* acat   = c_ + 65536;
    float* gl     = acat + 131072;
    float* glg    = gl + 65536;
    float* gr     = glg + 65536;
    float* grg    = gr + 65536;
    float* q      = grg + 65536;
    float* qT     = q + 65536;
    float* rp_buf = qT + 65536;
    float* attn   = rp_buf + 8192;
    float* comb   = attn + 16384;
    float* leaf   = comb + 262144;
    float* lsb    = leaf + 131072;
    unsigned short* EO_bf   = (unsigned short*)(lsb + 65536);
    unsigned short* ew_bf   = (unsigned short*)(EO_bf + 8388608);
    unsigned short* Wt_tree = (unsigned short*)(ew_bf + 2359296);
    unsigned short* Wt_rule = Wt_tree + 262144;
    unsigned short* Wrp1t   = Wt_rule + 262144;
    unsigned short* Wsa2t   = Wrp1t + 262144;
    unsigned short* rctx_bf = Wsa2t + 262144;
    float* bigreg = (float*)(rctx_bf + 1048576);
    unsigned short* eobuf = (unsigned short*)bigreg;           // tree then rule proj
    float* rclin = bigreg;                                     // aliases (eobuf dead)
    unsigned short* ewp_bf = (unsigned short*)(bigreg + 1048576); // aliases (eobuf dead)

    // 1. prep + casts
    k_prep<<<256, 256, 0, stream>>>(cur, padh, left, sek, c_, acat);
    k_ew<<<4608, 256, 0, stream>>>(embw, npad, out + O_EW, ew_bf);
    k_cast_eo<<<8192, 256, 0, stream>>>(EO, EO_bf);
    k_wtrans<<<dim3(16, 16, 4), 256, 0, stream>>>(
        Wta + (size_t)H_ * H_, Wra, Wrp1, Wsa + (size_t)2 * H_ * H_,
        Wt_tree, Wt_rule, Wrp1t, Wsa2t);

    // 2. small GEMM batch + node gates
    GB5 g;
    g.A[0] = c_;   g.W[0] = Wl;                    g.C[0] = gl;     g.M[0] = B_;  g.K[0] = H_;
    g.A[1] = c_;   g.W[1] = Wlg;                   g.C[1] = glg;    g.M[1] = B_;  g.K[1] = H_;
    g.A[2] = acat; g.W[2] = Wr;                    g.C[2] = gr;     g.M[2] = B_;  g.K[2] = 2 * H_;
    g.A[3] = acat; g.W[3] = Wrg;                   g.C[3] = grg;    g.M[3] = B_;  g.K[3] = 2 * H_;
    g.A[4] = rsc;  g.W[4] = Wra + (size_t)H_ * H_; g.C[4] = rp_buf; g.M[4] = R_;  g.K[4] = H_;
    gemm_f32_b5<<<dim3(8, 2, 5), 256, 0, stream>>>(g);
    k_node<<<256, 256, 0, stream>>>(gl, glg, gr, grg, bl, blg, br, brg, hlk,
                                    q, out + O_NODE, leaf);

    // 3. tree attention
    gemm(q, Wta, qT, B_, H_, H_, stream);
    gemm_bf<true>(EO_bf, Wt_tree, eobuf, S_ * B_, H_, H_, stream);
    k_tree_score2<<<S_ * B_ / 4, 256, 0, stream>>>(qT, eobuf, bta, Wts, bts, smk, attn);
    k_softmax_tree<<<B_, 128, 0, stream>>>(attn);

    // 4. rule attention
    gemm_bf<true>(EO_bf, Wt_rule, eobuf, S_ * B_, H_, H_, stream);
    k_rule_score2<<<S_ * B_ / 4, 256, 0, stream>>>(eobuf, rp_buf, bra, Wrs, brs, smk, comb);
    k_softmax_rules<<<B_ * R_, 128, 0, stream>>>(comb, attn);

    // 5. contexts
    k_context<<<dim3(B_, 2), 256, 0, stream>>>(EO, attn, comb, smk, out + O_CTX, leaf, rctx_bf);

    // 6. rule_prob
    gemm_bf<false>(rctx_bf, Wrp1t, rclin, B_ * R_, H_, H_, stream);
    k_rp2<<<B_, 256, 0, stream>>>(rclin, brp1, Wrp2, brp2, out + O_RPROB);

    // 7. num_score + op
    gemm(leaf, Wsa, lsb, B_, H_, 2 * H_, stream);
    gemm_bf<true>(ew_bf, Wsa2t, ewp_bf, B_ * L_, H_, H_, stream);
    k_numscore2<<<(B_ * L_ + 3) / 4, 256, 0, stream>>>(lsb, ewp_bf, bsa, Wss, nmk, out + O_NS);
    k_op<<<B_, 320, 0, stream>>>(leaf, Wops, bops, out + O_OP);
}

// Round 4
// 379.807 us; speedup vs baseline: 2.2476x; 1.1656x over previous
//
#include <hip/hip_runtime.h>
#include <hip/hip_bf16.h>

// Problem constants
#define B_ 128
#define S_ 128
#define H_ 512
#define R_ 16
#define IN_ 2
#define OPS_ 5
#define NPAD_ 16
#define L_ 18          // IN_ + NPAD_
#define NEGV (-1000000000000.0f)
#define C2_ (-2.885390081777927f)   // -2*log2(e):  tanh(x) = 2*rcp(1+exp2(C2*x)) - 1

typedef __bf16 bf16_t;
typedef bf16_t bf16x8 __attribute__((ext_vector_type(8)));
typedef float floatx4 __attribute__((ext_vector_type(4)));

__device__ __forceinline__ float rcp_f(float x) { return __builtin_amdgcn_rcpf(x); }
__device__ __forceinline__ float exp2_f(float x) { return __builtin_amdgcn_exp2f(x); }

__device__ __forceinline__ float fast_tanh(float x) {
    return 2.0f * rcp_f(1.0f + exp2_f(C2_ * x)) - 1.0f;
}
__device__ __forceinline__ float fast_sigmoid(float x) {
    return rcp_f(1.0f + exp2_f(-1.4426950408889634f * x));
}
__device__ __forceinline__ unsigned short f2bf(float f) {   // RNE
    unsigned int u = __builtin_bit_cast(unsigned int, f);
    u += 0x7fff + ((u >> 16) & 1);
    return (unsigned short)(u >> 16);
}
__device__ __forceinline__ float bf2f(unsigned short u) {
    return __builtin_bit_cast(float, (unsigned int)u << 16);
}

// ---------------------------------------------------------------------------
// bf16 MFMA GEMM:  C[M,N] = A[M,K](bf16,row-major) . B  where Bt[N,K] = B^T
// 128x128 block tile, 4 waves, BK=32, 16x16x32 MFMA. M%128==0, N%128==0.
// ---------------------------------------------------------------------------
#define LSTR 40

template <bool BF16_OUT>
__global__ __launch_bounds__(256) void gemm_bf16_bt(const unsigned short* __restrict__ A,
                                                    const unsigned short* __restrict__ Bt,
                                                    void* __restrict__ Cv,
                                                    int M, int N, int K) {
    __shared__ unsigned short As[128 * LSTR];
    __shared__ unsigned short Bs[128 * LSTR];

    const int tid  = threadIdx.x;
    const int wid  = tid >> 6, lane = tid & 63;
    const int quad = lane >> 4, mn = lane & 15;
    const int wm = (wid & 1) * 64, wn = (wid >> 1) * 64;
    const int m0 = blockIdx.y * 128, n0 = blockIdx.x * 128;

    const int sr = tid >> 2;
    const int sc = (tid & 3) * 8;

    floatx4 acc[4][4] = {};

    for (int k0 = 0; k0 < K; k0 += 32) {
        uint4 a0 = *(const uint4*)(A  + (size_t)(m0 + sr)      * K + k0 + sc);
        uint4 a1 = *(const uint4*)(A  + (size_t)(m0 + sr + 64) * K + k0 + sc);
        uint4 b0 = *(const uint4*)(Bt + (size_t)(n0 + sr)      * K + k0 + sc);
        uint4 b1 = *(const uint4*)(Bt + (size_t)(n0 + sr + 64) * K + k0 + sc);
        __syncthreads();
        *(uint4*)&As[sr * LSTR + sc]        = a0;
        *(uint4*)&As[(sr + 64) * LSTR + sc] = a1;
        *(uint4*)&Bs[sr * LSTR + sc]        = b0;
        *(uint4*)&Bs[(sr + 64) * LSTR + sc] = b1;
        __syncthreads();

        bf16x8 af[4], bfr[4];
        #pragma unroll
        for (int i = 0; i < 4; ++i)
            af[i] = *(const bf16x8*)&As[(wm + i * 16 + mn) * LSTR + quad * 8];
        #pragma unroll
        for (int j = 0; j < 4; ++j)
            bfr[j] = *(const bf16x8*)&Bs[(wn + j * 16 + mn) * LSTR + quad * 8];

        #pragma unroll
        for (int i = 0; i < 4; ++i)
            #pragma unroll
            for (int j = 0; j < 4; ++j)
                acc[i][j] = __builtin_amdgcn_mfma_f32_16x16x32_bf16(af[i], bfr[j], acc[i][j], 0, 0, 0);
    }

    // C/D layout: col = lane&15, row = quad*4 + reg   [verified m89/m91]
    #pragma unroll
    for (int i = 0; i < 4; ++i) {
        #pragma unroll
        for (int j = 0; j < 4; ++j) {
            #pragma unroll
            for (int r = 0; r < 4; ++r) {
                int row = m0 + wm + i * 16 + quad * 4 + r;
                int col = n0 + wn + j * 16 + mn;
                if (BF16_OUT)
                    ((unsigned short*)Cv)[(size_t)row * N + col] = f2bf(acc[i][j][r]);
                else
                    ((float*)Cv)[(size_t)row * N + col] = acc[i][j][r];
            }
        }
    }
}

// z-batched 5-job variant, N=512 fixed, M<=128 (row-clamped loads, guarded stores)
struct MJ5 {
    const unsigned short* A[5]; const unsigned short* Bt[5]; float* C[5];
    int M[5]; int K[5];
};
__global__ __launch_bounds__(256) void gemm_bf16_j5(MJ5 g) {
    __shared__ unsigned short As[128 * LSTR];
    __shared__ unsigned short Bs[128 * LSTR];

    const int z = blockIdx.z;
    const unsigned short* A  = g.A[z];
    const unsigned short* Bt = g.Bt[z];
    float* C = g.C[z];
    const int M = g.M[z], K = g.K[z];

    const int tid  = threadIdx.x;
    const int wid  = tid >> 6, lane = tid & 63;
    const int quad = lane >> 4, mn = lane & 15;
    const int wm = (wid & 1) * 64, wn = (wid >> 1) * 64;
    const int n0 = blockIdx.x * 128;

    const int sr = tid >> 2;
    const int sc = (tid & 3) * 8;
    const int ra0 = min(sr, M - 1);
    const int ra1 = min(sr + 64, M - 1);

    floatx4 acc[4][4] = {};

    for (int k0 = 0; k0 < K; k0 += 32) {
        uint4 a0 = *(const uint4*)(A  + (size_t)ra0 * K + k0 + sc);
        uint4 a1 = *(const uint4*)(A  + (size_t)ra1 * K + k0 + sc);
        uint4 b0 = *(const uint4*)(Bt + (size_t)(n0 + sr)      * K + k0 + sc);
        uint4 b1 = *(const uint4*)(Bt + (size_t)(n0 + sr + 64) * K + k0 + sc);
        __syncthreads();
        *(uint4*)&As[sr * LSTR + sc]        = a0;
        *(uint4*)&As[(sr + 64) * LSTR + sc] = a1;
        *(uint4*)&Bs[sr * LSTR + sc]        = b0;
        *(uint4*)&Bs[(sr + 64) * LSTR + sc] = b1;
        __syncthreads();

        bf16x8 af[4], bfr[4];
        #pragma unroll
        for (int i = 0; i < 4; ++i)
            af[i] = *(const bf16x8*)&As[(wm + i * 16 + mn) * LSTR + quad * 8];
        #pragma unroll
        for (int j = 0; j < 4; ++j)
            bfr[j] = *(const bf16x8*)&Bs[(wn + j * 16 + mn) * LSTR + quad * 8];

        #pragma unroll
        for (int i = 0; i < 4; ++i)
            #pragma unroll
            for (int j = 0; j < 4; ++j)
                acc[i][j] = __builtin_amdgcn_mfma_f32_16x16x32_bf16(af[i], bfr[j], acc[i][j], 0, 0, 0);
    }

    #pragma unroll
    for (int i = 0; i < 4; ++i) {
        #pragma unroll
        for (int j = 0; j < 4; ++j) {
            #pragma unroll
            for (int r = 0; r < 4; ++r) {
                int row = wm + i * 16 + quad * 4 + r;
                int col = n0 + wn + j * 16 + mn;
                if (row < M)
                    C[(size_t)row * 512 + col] = acc[i][j][r];
            }
        }
    }
}

// ---------------------------------------------------------------------------
// prep kernels
// ---------------------------------------------------------------------------
__global__ void k_cast_eo(const float* __restrict__ src, unsigned short* __restrict__ dst) {
    int i = (blockIdx.x * 256 + threadIdx.x) * 4;
    float4 v = *(const float4*)(src + i);
    ushort4 o;
    o.x = f2bf(v.x); o.y = f2bf(v.y); o.z = f2bf(v.z); o.w = f2bf(v.w);
    *(ushort4*)(dst + i) = o;
}

// 11-job batched transpose+cast: dst[n][k] = f2bf(src[k][n]), n<512, k<K
struct TJ11 { const float* src[11]; unsigned short* dst[11]; int K[11]; };
__global__ __launch_bounds__(256) void k_wtrans_all(TJ11 j) {
    int z = blockIdx.z;
    int K = j.K[z];
    int by = blockIdx.y * 32;          // k-tile
    if (by >= K) return;
    const float* src = j.src[z];
    unsigned short* dst = j.dst[z];
    __shared__ float t[32][33];
    int bx = blockIdx.x * 32;          // n-tile
    int tx = threadIdx.x & 31, ty = threadIdx.x >> 5;
    #pragma unroll
    for (int i = 0; i < 32; i += 8)
        t[ty + i][tx] = src[(size_t)(by + ty + i) * 512 + bx + tx];
    __syncthreads();
    #pragma unroll
    for (int i = 0; i < 32; i += 8)
        dst[(size_t)(bx + ty + i) * K + by + tx] = f2bf(t[tx][ty + i]);
}

// c/acat/rsc -> bf16
__global__ void k_prep(const float* __restrict__ cur, const float* __restrict__ padh,
                       const float* __restrict__ left, const float* __restrict__ rsc,
                       const int* __restrict__ se,
                       unsigned short* __restrict__ c_bf,
                       unsigned short* __restrict__ acat_bf,
                       unsigned short* __restrict__ rsc_bf) {
    int i = blockIdx.x * blockDim.x + threadIdx.x;
    if (i < B_ * H_) {
        int b = i >> 9, j = i & 511;
        float cv = se[b] ? padh[j] : cur[i];
        c_bf[i] = f2bf(cv);
        acat_bf[b * 1024 + j] = f2bf(left[i]);
        acat_bf[b * 1024 + 512 + j] = f2bf(cv);
    } else {
        int k = i - B_ * H_;
        if (k < R_ * H_) rsc_bf[k] = f2bf(rsc[k]);
    }
}

__global__ void k_ew(const float* __restrict__ embw, const float* __restrict__ npade,
                     float* __restrict__ ew, unsigned short* __restrict__ ewb) {
    int i = blockIdx.x * blockDim.x + threadIdx.x;
    int j = i & 511;
    int bl = i >> 9;
    int l = bl % L_;
    int b = bl / L_;
    float v = (l < IN_) ? embw[l * H_ + j] : npade[((size_t)b * NPAD_ + (l - IN_)) * H_ + j];
    ew[i] = v;
    ewb[i] = f2bf(v);
}

// gates -> q (bf16 for GEMM), node_out (fp32 output), leaf_bf[:, :H]
__global__ void k_node(const float* __restrict__ gl, const float* __restrict__ glg,
                       const float* __restrict__ gr, const float* __restrict__ grg,
                       const float* __restrict__ bl, const float* __restrict__ blg,
                       const float* __restrict__ br, const float* __restrict__ brg,
                       const int* __restrict__ hl,
                       unsigned short* __restrict__ q_bf, float* __restrict__ node_out,
                       unsigned short* __restrict__ leaf_bf) {
    int i = blockIdx.x * blockDim.x + threadIdx.x;
    int b = i >> 9, j = i & 511;
    float nl = fast_tanh(gl[i] + bl[j]) * fast_sigmoid(glg[i] + blg[j]);
    float nr = fast_tanh(gr[i] + br[j]) * fast_sigmoid(grg[i] + brg[j]);
    float v = hl[b] ? nr : nl;
    node_out[i] = v;
    q_bf[i] = f2bf(v);
    leaf_bf[b * 1024 + j] = f2bf(v);
}

// ---------------------------------------------------------------------------
// fused tree score + softmax: one block per b
// ---------------------------------------------------------------------------
__global__ __launch_bounds__(256) void k_tree_attn(const float* __restrict__ qT,
                                                   const unsigned short* __restrict__ EOt,
                                                   const float* __restrict__ b_ta,
                                                   const float* __restrict__ w_ts,
                                                   const float* __restrict__ b_ts,
                                                   const int* __restrict__ sm,
                                                   float* __restrict__ attn) {
    __shared__ float sc[S_];
    int b = blockIdx.x;
    int tid = threadIdx.x;
    int wid = tid >> 6, lane = tid & 63;
    int j0 = lane * 8;
    float4 q0 = *(const float4*)(qT + b * H_ + j0);
    float4 q1 = *(const float4*)(qT + b * H_ + j0 + 4);
    float4 t0 = *(const float4*)(b_ta + j0);
    float4 t1 = *(const float4*)(b_ta + j0 + 4);
    float4 w0 = *(const float4*)(w_ts + j0);
    float4 w1 = *(const float4*)(w_ts + j0 + 4);
    float qc[8] = {C2_*(q0.x+t0.x), C2_*(q0.y+t0.y), C2_*(q0.z+t0.z), C2_*(q0.w+t0.w),
                   C2_*(q1.x+t1.x), C2_*(q1.y+t1.y), C2_*(q1.z+t1.z), C2_*(q1.w+t1.w)};
    float w2[8] = {2*w0.x, 2*w0.y, 2*w0.z, 2*w0.w, 2*w1.x, 2*w1.y, 2*w1.z, 2*w1.w};
    float wsum = 0.5f * (w2[0]+w2[1]+w2[2]+w2[3]+w2[4]+w2[5]+w2[6]+w2[7]);
    float bias = b_ts[0];

    for (int s = wid; s < S_; s += 4) {
        if (sm[b * S_ + s]) {
            if (lane == 0) sc[s] = NEGV;
            continue;
        }
        uint4 ev = *(const uint4*)(EOt + ((size_t)s * B_ + b) * H_ + j0);
        const unsigned short* ep = (const unsigned short*)&ev;
        float acc = -wsum;
        #pragma unroll
        for (int k = 0; k < 8; ++k) {
            float y = fmaf(C2_, bf2f(ep[k]), qc[k]);
            acc = fmaf(w2[k], rcp_f(1.0f + exp2_f(y)), acc);
        }
        #pragma unroll
        for (int o = 32; o > 0; o >>= 1) acc += __shfl_xor(acc, o);
        if (lane == 0) sc[s] = acc + bias;
    }
    __syncthreads();
    if (tid < 64) {
        float v0 = sc[tid], v1 = sc[tid + 64];
        float m = fmaxf(v0, v1);
        #pragma unroll
        for (int o = 32; o > 0; o >>= 1) m = fmaxf(m, __shfl_xor(m, o));
        float e0 = __expf(v0 - m), e1 = __expf(v1 - m);
        float ss = e0 + e1;
        #pragma unroll
        for (int o = 32; o > 0; o >>= 1) ss += __shfl_xor(ss, o);
        float r = rcp_f(ss);
        attn[b * S_ + tid] = e0 * r;
        attn[b * S_ + tid + 64] = e1 * r;
    }
}

// rule scores: wave per (s,b)-row, 16 rules each
__global__ __launch_bounds__(256) void k_rule_score2(const unsigned short* __restrict__ EOr,
                                                     const float* __restrict__ RP,
                                                     const float* __restrict__ b_ra,
                                                     const float* __restrict__ w_rs,
                                                     const float* __restrict__ b_rs,
                                                     const int* __restrict__ sm,
                                                     float* __restrict__ comb) {
    int wid = threadIdx.x >> 6, lane = threadIdx.x & 63;
    int row = blockIdx.x * 4 + wid;   // s*B + b
    int s = row >> 7, b = row & 127;
    bool masked = sm[b * S_ + s] != 0;
    if (masked) {
        if (lane < R_) comb[((size_t)b * R_ + lane) * S_ + s] = NEGV;
        return;
    }
    int j0 = lane * 8;
    uint4 ev = *(const uint4*)(EOr + (size_t)row * H_ + j0);
    const unsigned short* ep = (const unsigned short*)&ev;
    float4 a0 = *(const float4*)(b_ra + j0);
    float4 a1 = *(const float4*)(b_ra + j0 + 4);
    float4 w0 = *(const float4*)(w_rs + j0);
    float4 w1 = *(const float4*)(w_rs + j0 + 4);
    float ba[8] = {a0.x, a0.y, a0.z, a0.w, a1.x, a1.y, a1.z, a1.w};
    float w2[8], ed[8];
    float wsum = 0.f;
    {
        float w[8] = {w0.x, w0.y, w0.z, w0.w, w1.x, w1.y, w1.z, w1.w};
        #pragma unroll
        for (int k = 0; k < 8; ++k) {
            wsum += w[k];
            w2[k] = 2.0f * w[k];
            ed[k] = C2_ * (bf2f(ep[k]) + ba[k]);
        }
    }
    float bias = b_rs[0];
    #pragma unroll
    for (int r = 0; r < R_; ++r) {
        float4 r0 = *(const float4*)(RP + r * H_ + j0);
        float4 r1 = *(const float4*)(RP + r * H_ + j0 + 4);
        float rp[8] = {r0.x, r0.y, r0.z, r0.w, r1.x, r1.y, r1.z, r1.w};
        float acc = -wsum;
        #pragma unroll
        for (int k = 0; k < 8; ++k) {
            float y = fmaf(C2_, rp[k], ed[k]);
            acc = fmaf(w2[k], rcp_f(1.0f + exp2_f(y)), acc);
        }
        #pragma unroll
        for (int o = 32; o > 0; o >>= 1) acc += __shfl_xor(acc, o);
        if (lane == 0) comb[((size_t)b * R_ + r) * S_ + s] = acc + bias;
    }
}

__global__ __launch_bounds__(128) void k_softmax_rules(float* __restrict__ comb,
                                                       const float* __restrict__ attn) {
    __shared__ float red[2], red2[2];
    int br = blockIdx.x;
    int b = br >> 4;
    int t = threadIdx.x;
    float* row = comb + (size_t)br * 128;
    float v = row[t];
    float m = v;
    for (int o = 32; o > 0; o >>= 1) m = fmaxf(m, __shfl_down(m, o));
    if ((t & 63) == 0) red[t >> 6] = m;
    __syncthreads();
    m = fmaxf(red[0], red[1]);
    float e = __expf(v - m);
    float ssum = e;
    for (int o = 32; o > 0; o >>= 1) ssum += __shfl_down(ssum, o);
    if ((t & 63) == 0) red2[t >> 6] = ssum;
    __syncthreads();
    row[t] = e * rcp_f(red2[0] + red2[1]) + 0.2f * attn[b * 128 + t];
}

// contexts; masked s skipped; emits leaf_bf[:, H:] and rctx_bf
__global__ __launch_bounds__(256) void k_context(const float* __restrict__ EO,
                                                 const float* __restrict__ attn,
                                                 const float* __restrict__ comb,
                                                 const int* __restrict__ sm,
                                                 float* __restrict__ ctx_out,
                                                 unsigned short* __restrict__ leaf_bf,
                                                 unsigned short* __restrict__ rctx) {
    __shared__ float at[S_];
    __shared__ float cb[R_ * S_];
    __shared__ int smr[S_];
    int b = blockIdx.x;
    int j = blockIdx.y * 256 + threadIdx.x;
    if (threadIdx.x < S_) {
        at[threadIdx.x] = attn[b * S_ + threadIdx.x];
        smr[threadIdx.x] = sm[b * S_ + threadIdx.x];
    }
    for (int i = threadIdx.x; i < R_ * S_; i += 256) cb[i] = comb[(size_t)b * R_ * S_ + i];
    __syncthreads();
    float ctx = 0.f;
    float rc[R_] = {};
    for (int s = 0; s < S_; ++s) {
        if (smr[s]) continue;
        float eo = EO[((size_t)s * B_ + b) * H_ + j];
        ctx += at[s] * eo;
        #pragma unroll
        for (int r = 0; r < R_; ++r) rc[r] += cb[r * S_ + s] * eo;
    }
    ctx_out[b * H_ + j] = ctx;
    leaf_bf[b * 1024 + 512 + j] = f2bf(ctx);
    #pragma unroll
    for (int r = 0; r < R_; ++r) rctx[((size_t)b * R_ + r) * H_ + j] = f2bf(rc[r]);
}

__global__ __launch_bounds__(256) void k_rp2(const float* __restrict__ rclin,
                                             const float* __restrict__ b_rp1,
                                             const float* __restrict__ w_rp2,
                                             const float* __restrict__ b_rp2,
                                             float* __restrict__ prob) {
    __shared__ float sc[R_];
    int b = blockIdx.x;
    int wid = threadIdx.x >> 6, lane = threadIdx.x & 63;
    int j0 = lane * 8;
    float4 p0 = *(const float4*)(b_rp1 + j0);
    float4 p1 = *(const float4*)(b_rp1 + j0 + 4);
    float4 w0 = *(const float4*)(w_rp2 + j0);
    float4 w1 = *(const float4*)(w_rp2 + j0 + 4);
    float brc[8] = {C2_*p0.x, C2_*p0.y, C2_*p0.z, C2_*p0.w, C2_*p1.x, C2_*p1.y, C2_*p1.z, C2_*p1.w};
    float w[8] = {w0.x, w0.y, w0.z, w0.w, w1.x, w1.y, w1.z, w1.w};
    float wsum = 0.f;
    #pragma unroll
    for (int k = 0; k < 8; ++k) wsum += w[k];
    #pragma unroll
    for (int rr = 0; rr < 4; ++rr) {
        int r = wid * 4 + rr;
        const float* rl = rclin + ((size_t)b * R_ + r) * H_ + j0;
        float4 r0 = *(const float4*)(rl);
        float4 r1 = *(const float4*)(rl + 4);
        float rv[8] = {r0.x, r0.y, r0.z, r0.w, r1.x, r1.y, r1.z, r1.w};
        float acc = -wsum;
        #pragma unroll
        for (int k = 0; k < 8; ++k) {
            float y = fmaf(C2_, rv[k], brc[k]);
            acc = fmaf(2.0f * w[k], rcp_f(1.0f + exp2_f(y)), acc);
        }
        #pragma unroll
        for (int o = 32; o > 0; o >>= 1) acc += __shfl_xor(acc, o);
        if (lane == 0) sc[r] = acc + b_rp2[0];
    }
    __syncthreads();
    if (threadIdx.x < R_) {
        float m = -1e30f;
        for (int r = 0; r < R_; ++r) m = fmaxf(m, sc[r]);
        float sum = 0.f;
        for (int r = 0; r < R_; ++r) sum += __expf(sc[r] - m);
        prob[b * R_ + threadIdx.x] = __expf(sc[threadIdx.x] - m) * rcp_f(sum);
    }
}

__global__ __launch_bounds__(256) void k_numscore2(const float* __restrict__ lsb,
                                                   const unsigned short* __restrict__ ewp,
                                                   const float* __restrict__ b_sc,
                                                   const float* __restrict__ w_scs,
                                                   const int* __restrict__ mask_nums,
                                                   float* __restrict__ outp) {
    int wid = threadIdx.x >> 6, lane = threadIdx.x & 63;
    int row = blockIdx.x * 4 + wid;       // b*L + l
    if (row >= B_ * L_) return;
    int b = row / L_, l = row - b * L_;
    bool masked = mask_nums[b * L_ + l] != 0;
    if (masked) {
        if (lane == 0) outp[b * L_ + l] = NEGV;
        return;
    }
    int j0 = lane * 8;
    uint4 ev = *(const uint4*)(ewp + (size_t)row * H_ + j0);
    const unsigned short* ep = (const unsigned short*)&ev;
    float4 l0 = *(const float4*)(lsb + b * H_ + j0);
    float4 l1 = *(const float4*)(lsb + b * H_ + j0 + 4);
    float4 s0 = *(const float4*)(b_sc + j0);
    float4 s1 = *(const float4*)(b_sc + j0 + 4);
    float4 w0 = *(const float4*)(w_scs + j0);
    float4 w1 = *(const float4*)(w_scs + j0 + 4);
    float lc[8] = {C2_*(l0.x+s0.x), C2_*(l0.y+s0.y), C2_*(l0.z+s0.z), C2_*(l0.w+s0.w),
                   C2_*(l1.x+s1.x), C2_*(l1.y+s1.y), C2_*(l1.z+s1.z), C2_*(l1.w+s1.w)};
    float w[8] = {w0.x, w0.y, w0.z, w0.w, w1.x, w1.y, w1.z, w1.w};
    float wsum = 0.f;
    #pragma unroll
    for (int k = 0; k < 8; ++k) wsum += w[k];
    float acc = -wsum;
    #pragma unroll
    for (int k = 0; k < 8; ++k) {
        float y = fmaf(C2_, bf2f(ep[k]), lc[k]);
        acc = fmaf(2.0f * w[k], rcp_f(1.0f + exp2_f(y)), acc);
    }
    #pragma unroll
    for (int o = 32; o > 0; o >>= 1) acc += __shfl_xor(acc, o);
    if (lane == 0) outp[b * L_ + l] = acc;
}

__global__ __launch_bounds__(320) void k_op(const unsigned short* __restrict__ leaf_bf,
                                            const float* __restrict__ Wops,
                                            const float* __restrict__ bops,
                                            float* __restrict__ out) {
    int b = blockIdx.x;
    int wid = threadIdx.x / 64, lane = threadIdx.x % 64;
    float acc = 0.f;
    #pragma unroll
    for (int it = 0; it < 16; ++it) {
        int k = lane + it * 64;
        acc += bf2f(leaf_bf[b * 1024 + k]) * Wops[k * OPS_ + wid];
    }
    for (int o = 32; o > 0; o >>= 1) acc += __shfl_down(acc, o);
    if (lane == 0) out[b * OPS_ + wid] = acc + bops[wid];
}

// ---------------------------------------------------------------------------
template <bool BF16_OUT>
static inline void gemm_bf(const unsigned short* A, const unsigned short* Bt, void* C,
                           int M, int N, int K, hipStream_t s) {
    dim3 grid(N / 128, M / 128);
    gemm_bf16_bt<BF16_OUT><<<grid, 256, 0, s>>>(A, Bt, C, M, N, K);
}

extern "C" void kernel_launch(void* const* d_in, const int* in_sizes, int n_in,
                              void* d_out, int out_size, void* d_ws, size_t ws_size,
                              hipStream_t stream) {
    const float* EO   = (const float*)d_in[0];
    const float* cur  = (const float*)d_in[1];
    const float* left = (const float*)d_in[2];
    const float* padh = (const float*)d_in[3];
    const float* npad = (const float*)d_in[4];
    const float* rsc  = (const float*)d_in[5];
    const float* embw = (const float*)d_in[6];
    const float* Wl   = (const float*)d_in[7];  const float* bl   = (const float*)d_in[8];
    const float* Wlg  = (const float*)d_in[9];  const float* blg  = (const float*)d_in[10];
    const float* Wr   = (const float*)d_in[11]; const float* br   = (const float*)d_in[12];
    const float* Wrg  = (const float*)d_in[13]; const float* brg  = (const float*)d_in[14];
    const float* Wta  = (const float*)d_in[15]; const float* bta  = (const float*)d_in[16];
    const float* Wts  = (const float*)d_in[17]; const float* bts  = (const float*)d_in[18];
    const float* Wra  = (const float*)d_in[19]; const float* bra  = (const float*)d_in[20];
    const float* Wrs  = (const float*)d_in[21]; const float* brs  = (const float*)d_in[22];
    const float* Wrp1 = (const float*)d_in[23]; const float* brp1 = (const float*)d_in[24];
    const float* Wrp2 = (const float*)d_in[25]; const float* brp2 = (const float*)d_in[26];
    const float* Wsa  = (const float*)d_in[27]; const float* bsa  = (const float*)d_in[28];
    const float* Wss  = (const float*)d_in[29];
    const float* Wops = (const float*)d_in[30]; const float* bops = (const float*)d_in[31];
    const int* smk = (const int*)d_in[32];
    const int* nmk = (const int*)d_in[33];
    const int* hlk = (const int*)d_in[34];
    const int* sek = (const int*)d_in[35];

    float* out = (float*)d_out;
    float* ws  = (float*)d_ws;

    const size_t O_NS    = 0;
    const size_t O_OP    = O_NS + (size_t)B_ * L_;
    const size_t O_NODE  = O_OP + (size_t)B_ * OPS_;
    const size_t O_CTX   = O_NODE + (size_t)B_ * H_;
    const size_t O_EW    = O_CTX + (size_t)B_ * H_;
    const size_t O_RPROB = O_EW + (size_t)B_ * L_ * H_;

    // ---- workspace layout ----
    // fp32 head (live across eobuf writes):
    float* rp_buf = ws;                    // 8192   (R x H rule projection)
    float* qT     = rp_buf + 8192;         // 65536
    float* attn   = qT + 65536;            // 16384
    float* comb   = attn + 16384;          // 262144
    unsigned short* us = (unsigned short*)(comb + 262144);
    unsigned short* EO_bf   = us;                   // 8388608
    unsigned short* ew_bf   = EO_bf + 8388608;      // 1179648
    unsigned short* leaf_bf = ew_bf + 1179648;      // 131072
    unsigned short* rctx_bf = leaf_bf + 131072;     // 1048576
    unsigned short* WT      = rctx_bf + 1048576;    // 3670016 total, offsets below
    unsigned short* T0  = WT;                 // Wl^T       K=512
    unsigned short* T1  = WT + 262144;        // Wlg^T      K=512
    unsigned short* T2  = WT + 524288;        // Wr^T       K=1024
    unsigned short* T3  = WT + 1048576;       // Wrg^T      K=1024
    unsigned short* T4  = WT + 1572864;       // Wra[h:]^T  K=512
    unsigned short* T5  = WT + 1835008;       // Wta[:h]^T  K=512
    unsigned short* T6  = WT + 2097152;       // Wta[h:]^T  K=512
    unsigned short* T7  = WT + 2359296;       // Wra[:h]^T  K=512
    unsigned short* T8  = WT + 2621440;       // Wrp1^T     K=512
    unsigned short* T9  = WT + 2883584;       // Wsa[:2h]^T K=1024
    unsigned short* T10 = WT + 3407872;       // Wsa[2h:]^T K=512
    unsigned short* eobuf = WT + 3670016;     // 8388608 us — EO projections (tree, rule)
    // aliases inside eobuf (each live only when eobuf is dead, order-checked):
    float* rclin = (float*)eobuf;                       // [d14..d15]
    unsigned short* ewp_bf  = eobuf + 2097152;          // [d17..d18]
    float* gl  = (float*)(eobuf + 3276800);             // [d5..d6]
    float* glg = gl + 65536;
    float* gr  = glg + 65536;
    float* grg = gr + 65536;
    float* lsb = (float*)(eobuf + 3801088);             // [d16..d18]
    unsigned short* c_bf    = eobuf + 3932160;          // [d1..d5]
    unsigned short* acat_bf = c_bf + 65536;             // [d1..d5]
    unsigned short* rsc_bf  = acat_bf + 131072;         // [d1..d5]
    unsigned short* q_bf    = rsc_bf + 8192;            // [d6..d7]

    // d1-d4: prep + casts (inputs only)
    k_prep<<<288, 256, 0, stream>>>(cur, padh, left, rsc, sek, c_bf, acat_bf, rsc_bf);
    k_ew<<<4608, 256, 0, stream>>>(embw, npad, out + O_EW, ew_bf);
    k_cast_eo<<<8192, 256, 0, stream>>>(EO, EO_bf);
    TJ11 tj;
    const float* tsrc[11] = {Wl, Wlg, Wr, Wrg, Wra + (size_t)H_ * H_, Wta,
                             Wta + (size_t)H_ * H_, Wra, Wrp1, Wsa, Wsa + (size_t)2 * H_ * H_};
    unsigned short* tdst[11] = {T0, T1, T2, T3, T4, T5, T6, T7, T8, T9, T10};
    int tk[11] = {512, 512, 1024, 1024, 512, 512, 512, 512, 512, 1024, 512};
    for (int i = 0; i < 11; ++i) { tj.src[i] = tsrc[i]; tj.dst[i] = tdst[i]; tj.K[i] = tk[i]; }
    k_wtrans_all<<<dim3(16, 32, 11), 256, 0, stream>>>(tj);

    // d5: 5-way batched MFMA (node gates + rule projection)
    MJ5 g;
    g.A[0] = c_bf;    g.Bt[0] = T0; g.C[0] = gl;     g.M[0] = B_;  g.K[0] = 512;
    g.A[1] = c_bf;    g.Bt[1] = T1; g.C[1] = glg;    g.M[1] = B_;  g.K[1] = 512;
    g.A[2] = acat_bf; g.Bt[2] = T2; g.C[2] = gr;     g.M[2] = B_;  g.K[2] = 1024;
    g.A[3] = acat_bf; g.Bt[3] = T3; g.C[3] = grg;    g.M[3] = B_;  g.K[3] = 1024;
    g.A[4] = rsc_bf;  g.Bt[4] = T4; g.C[4] = rp_buf; g.M[4] = R_;  g.K[4] = 512;
    gemm_bf16_j5<<<dim3(4, 1, 5), 256, 0, stream>>>(g);

    // d6: node gates
    k_node<<<256, 256, 0, stream>>>(gl, glg, gr, grg, bl, blg, br, brg, hlk,
                                    q_bf, out + O_NODE, leaf_bf);

    // d7-d9: tree attention
    gemm_bf<false>(q_bf, T5, qT, B_, H_, H_, stream);
    gemm_bf<true>(EO_bf, T6, eobuf, S_ * B_, H_, H_, stream);
    k_tree_attn<<<B_, 256, 0, stream>>>(qT, eobuf, bta, Wts, bts, smk, attn);

    // d10-d12: rule attention
    gemm_bf<true>(EO_bf, T7, eobuf, S_ * B_, H_, H_, stream);
    k_rule_score2<<<S_ * B_ / 4, 256, 0, stream>>>(eobuf, rp_buf, bra, Wrs, brs, smk, comb);
    k_softmax_rules<<<B_ * R_, 128, 0, stream>>>(comb, attn);

    // d13: contexts
    k_context<<<dim3(B_, 2), 256, 0, stream>>>(EO, attn, comb, smk, out + O_CTX,
                                               leaf_bf, rctx_bf);

    // d14-d15: rule_prob
    gemm_bf<false>(rctx_bf, T8, rclin, B_ * R_, H_, H_, stream);
    k_rp2<<<B_, 256, 0, stream>>>(rclin, brp1, Wrp2, brp2, out + O_RPROB);

    // d16-d19: num_score + op
    gemm_bf<false>(leaf_bf, T9, lsb, B_, H_, 2 * H_, stream);
    gemm_bf<true>(ew_bf, T10, ewp_bf, B_ * L_, H_, H_, stream);
    k_numscore2<<<(B_ * L_ + 3) / 4, 256, 0, stream>>>(lsb, ewp_bf, bsa, Wss, nmk, out + O_NS);
    k_op<<<B_, 320, 0, stream>>>(leaf_bf, Wops, bops, out + O_OP);
}

// Round 5
// 333.357 us; speedup vs baseline: 2.5608x; 1.1393x over previous
//
#include <hip/hip_runtime.h>
#include <hip/hip_bf16.h>

// Problem constants
#define B_ 128
#define S_ 128
#define H_ 512
#define R_ 16
#define IN_ 2
#define OPS_ 5
#define NPAD_ 16
#define L_ 18          // IN_ + NPAD_
#define NEGV (-1000000000000.0f)
#define C2_ (-2.885390081777927f)   // -2*log2(e):  tanh(x) = 2*rcp(1+exp2(C2*x)) - 1

typedef __bf16 bf16_t;
typedef bf16_t bf16x8 __attribute__((ext_vector_type(8)));
typedef float floatx4 __attribute__((ext_vector_type(4)));

__device__ __forceinline__ float rcp_f(float x) { return __builtin_amdgcn_rcpf(x); }
__device__ __forceinline__ float exp2_f(float x) { return __builtin_amdgcn_exp2f(x); }

__device__ __forceinline__ float fast_tanh(float x) {
    return 2.0f * rcp_f(1.0f + exp2_f(C2_ * x)) - 1.0f;
}
__device__ __forceinline__ float fast_sigmoid(float x) {
    return rcp_f(1.0f + exp2_f(-1.4426950408889634f * x));
}
__device__ __forceinline__ unsigned short f2bf(float f) {   // RNE
    unsigned int u = __builtin_bit_cast(unsigned int, f);
    u += 0x7fff + ((u >> 16) & 1);
    return (unsigned short)(u >> 16);
}
__device__ __forceinline__ float bf2f(unsigned short u) {
    return __builtin_bit_cast(float, (unsigned int)u << 16);
}

// ---------------------------------------------------------------------------
// bf16 MFMA tile body: one 128x128 C-tile at (m0,n0). A row-major [.,K],
// Bt row-major [N,K] (= B^T). Full tiles only (no M/N guards). ldc = C row
// stride. 4 waves, BK=32, 16x16x32 MFMA.
// ---------------------------------------------------------------------------
#define LSTR 40

__device__ __forceinline__ void mfma_tile(const unsigned short* __restrict__ A,
                                          const unsigned short* __restrict__ Bt,
                                          void* __restrict__ Cv, bool bf16_out,
                                          int m0, int n0, int K, int ldc,
                                          unsigned short* As, unsigned short* Bs) {
    const int tid  = threadIdx.x;
    const int wid  = tid >> 6, lane = tid & 63;
    const int quad = lane >> 4, mn = lane & 15;
    const int wm = (wid & 1) * 64, wn = (wid >> 1) * 64;
    const int sr = tid >> 2;
    const int sc = (tid & 3) * 8;

    floatx4 acc[4][4] = {};

    for (int k0 = 0; k0 < K; k0 += 32) {
        uint4 a0 = *(const uint4*)(A  + (size_t)(m0 + sr)      * K + k0 + sc);
        uint4 a1 = *(const uint4*)(A  + (size_t)(m0 + sr + 64) * K + k0 + sc);
        uint4 b0 = *(const uint4*)(Bt + (size_t)(n0 + sr)      * K + k0 + sc);
        uint4 b1 = *(const uint4*)(Bt + (size_t)(n0 + sr + 64) * K + k0 + sc);
        __syncthreads();
        *(uint4*)&As[sr * LSTR + sc]        = a0;
        *(uint4*)&As[(sr + 64) * LSTR + sc] = a1;
        *(uint4*)&Bs[sr * LSTR + sc]        = b0;
        *(uint4*)&Bs[(sr + 64) * LSTR + sc] = b1;
        __syncthreads();

        bf16x8 af[4], bfr[4];
        #pragma unroll
        for (int i = 0; i < 4; ++i)
            af[i] = *(const bf16x8*)&As[(wm + i * 16 + mn) * LSTR + quad * 8];
        #pragma unroll
        for (int j = 0; j < 4; ++j)
            bfr[j] = *(const bf16x8*)&Bs[(wn + j * 16 + mn) * LSTR + quad * 8];

        #pragma unroll
        for (int i = 0; i < 4; ++i)
            #pragma unroll
            for (int j = 0; j < 4; ++j)
                acc[i][j] = __builtin_amdgcn_mfma_f32_16x16x32_bf16(af[i], bfr[j], acc[i][j], 0, 0, 0);
    }

    // C/D layout: col = lane&15, row = quad*4 + reg   [verified m89/m91]
    #pragma unroll
    for (int i = 0; i < 4; ++i) {
        #pragma unroll
        for (int j = 0; j < 4; ++j) {
            #pragma unroll
            for (int r = 0; r < 4; ++r) {
                int row = m0 + wm + i * 16 + quad * 4 + r;
                int col = n0 + wn + j * 16 + mn;
                if (bf16_out)
                    ((unsigned short*)Cv)[(size_t)row * ldc + col] = f2bf(acc[i][j][r]);
                else
                    ((float*)Cv)[(size_t)row * ldc + col] = acc[i][j][r];
            }
        }
    }
}

// mega-GEMM 1: blocks 0..1023 = EO_bf @ Wcat (N=1024 -> eobuf bf16, ld 1024);
//              blocks 1024..1027 = q_bf @ T5 (-> qT fp32, ld 512)
__global__ __launch_bounds__(256) void k_gemm_mega1(const unsigned short* __restrict__ EO_bf,
                                                    const unsigned short* __restrict__ Wcat,
                                                    unsigned short* __restrict__ eobuf,
                                                    const unsigned short* __restrict__ q_bf,
                                                    const unsigned short* __restrict__ T5,
                                                    float* __restrict__ qT) {
    __shared__ unsigned short As[128 * LSTR];
    __shared__ unsigned short Bs[128 * LSTR];
    int blk = blockIdx.x;
    if (blk < 1024)
        mfma_tile(EO_bf, Wcat, eobuf, true, (blk >> 3) * 128, (blk & 7) * 128, 512, 1024, As, Bs);
    else
        mfma_tile(q_bf, T5, qT, false, 0, (blk - 1024) * 128, 512, 512, As, Bs);
}

// mega-GEMM 2: rctx@T8 (64 blk), leaf@T9 (4 blk), ew@T10 (72 blk)
__global__ __launch_bounds__(256) void k_gemm_mega2(const unsigned short* __restrict__ rctx_bf,
                                                    const unsigned short* __restrict__ T8,
                                                    float* __restrict__ rclin,
                                                    const unsigned short* __restrict__ leaf_bf,
                                                    const unsigned short* __restrict__ T9,
                                                    float* __restrict__ lsb,
                                                    const unsigned short* __restrict__ ew_bf,
                                                    const unsigned short* __restrict__ T10,
                                                    unsigned short* __restrict__ ewp_bf) {
    __shared__ unsigned short As[128 * LSTR];
    __shared__ unsigned short Bs[128 * LSTR];
    int blk = blockIdx.x;
    if (blk < 64)
        mfma_tile(rctx_bf, T8, rclin, false, (blk >> 2) * 128, (blk & 3) * 128, 512, 512, As, Bs);
    else if (blk < 68)
        mfma_tile(leaf_bf, T9, lsb, false, 0, (blk - 64) * 128, 1024, 512, As, Bs);
    else {
        int r = blk - 68;
        mfma_tile(ew_bf, T10, ewp_bf, true, (r >> 2) * 128, (r & 3) * 128, 512, 512, As, Bs);
    }
}

// z-batched 5-job GEMM, N=512 fixed, M<=128 (row-clamped loads, guarded stores)
struct MJ5 {
    const unsigned short* A[5]; const unsigned short* Bt[5]; float* C[5];
    int M[5]; int K[5];
};
__global__ __launch_bounds__(256) void gemm_bf16_j5(MJ5 g) {
    __shared__ unsigned short As[128 * LSTR];
    __shared__ unsigned short Bs[128 * LSTR];

    const int z = blockIdx.z;
    const unsigned short* A  = g.A[z];
    const unsigned short* Bt = g.Bt[z];
    float* C = g.C[z];
    const int M = g.M[z], K = g.K[z];

    const int tid  = threadIdx.x;
    const int wid  = tid >> 6, lane = tid & 63;
    const int quad = lane >> 4, mn = lane & 15;
    const int wm = (wid & 1) * 64, wn = (wid >> 1) * 64;
    const int n0 = blockIdx.x * 128;

    const int sr = tid >> 2;
    const int sc = (tid & 3) * 8;
    const int ra0 = min(sr, M - 1);
    const int ra1 = min(sr + 64, M - 1);

    floatx4 acc[4][4] = {};

    for (int k0 = 0; k0 < K; k0 += 32) {
        uint4 a0 = *(const uint4*)(A  + (size_t)ra0 * K + k0 + sc);
        uint4 a1 = *(const uint4*)(A  + (size_t)ra1 * K + k0 + sc);
        uint4 b0 = *(const uint4*)(Bt + (size_t)(n0 + sr)      * K + k0 + sc);
        uint4 b1 = *(const uint4*)(Bt + (size_t)(n0 + sr + 64) * K + k0 + sc);
        __syncthreads();
        *(uint4*)&As[sr * LSTR + sc]        = a0;
        *(uint4*)&As[(sr + 64) * LSTR + sc] = a1;
        *(uint4*)&Bs[sr * LSTR + sc]        = b0;
        *(uint4*)&Bs[(sr + 64) * LSTR + sc] = b1;
        __syncthreads();

        bf16x8 af[4], bfr[4];
        #pragma unroll
        for (int i = 0; i < 4; ++i)
            af[i] = *(const bf16x8*)&As[(wm + i * 16 + mn) * LSTR + quad * 8];
        #pragma unroll
        for (int j = 0; j < 4; ++j)
            bfr[j] = *(const bf16x8*)&Bs[(wn + j * 16 + mn) * LSTR + quad * 8];

        #pragma unroll
        for (int i = 0; i < 4; ++i)
            #pragma unroll
            for (int j = 0; j < 4; ++j)
                acc[i][j] = __builtin_amdgcn_mfma_f32_16x16x32_bf16(af[i], bfr[j], acc[i][j], 0, 0, 0);
    }

    #pragma unroll
    for (int i = 0; i < 4; ++i) {
        #pragma unroll
        for (int j = 0; j < 4; ++j) {
            #pragma unroll
            for (int r = 0; r < 4; ++r) {
                int row = wm + i * 16 + quad * 4 + r;
                int col = n0 + wn + j * 16 + mn;
                if (row < M)
                    C[(size_t)row * 512 + col] = acc[i][j][r];
            }
        }
    }
}

// ---------------------------------------------------------------------------
// fused prep: EO cast | ew build | c/acat/rsc cast | 11 weight transposes
// ---------------------------------------------------------------------------
struct PrepArgs {
    const float *EO, *cur, *padh, *left, *rsc, *embw, *npad;
    const int* se;
    unsigned short *EO_bf, *c_bf, *acat_bf, *rsc_bf, *ew_bf;
    float* ew_out;
    const float* tsrc[11];
    unsigned short* tdst[11];
    int tK[11];
    int tbase[12];
};
#define PG_CAST 8192
#define PG_EW   1152
#define PG_PREP 288
#define PG_WT   3584
#define PG_TOTAL (PG_CAST + PG_EW + PG_PREP + PG_WT)   // 13216

__global__ __launch_bounds__(256) void k_prep_mega(PrepArgs a) {
    __shared__ float t[32][33];
    int blk = blockIdx.x, tid = threadIdx.x;
    if (blk < PG_CAST) {
        int i = (blk * 256 + tid) * 4;
        float4 v = *(const float4*)(a.EO + i);
        ushort4 o;
        o.x = f2bf(v.x); o.y = f2bf(v.y); o.z = f2bf(v.z); o.w = f2bf(v.w);
        *(ushort4*)(a.EO_bf + i) = o;
    } else if (blk < PG_CAST + PG_EW) {
        int i = ((blk - PG_CAST) * 256 + tid) * 4;
        int j = i & 511;
        int bl = i >> 9;
        int l = bl % L_;
        int b = bl / L_;
        const float* src = (l < IN_) ? (a.embw + l * H_ + j)
                                     : (a.npad + ((size_t)b * NPAD_ + (l - IN_)) * H_ + j);
        float4 v = *(const float4*)src;
        *(float4*)(a.ew_out + i) = v;
        ushort4 o;
        o.x = f2bf(v.x); o.y = f2bf(v.y); o.z = f2bf(v.z); o.w = f2bf(v.w);
        *(ushort4*)(a.ew_bf + i) = o;
    } else if (blk < PG_CAST + PG_EW + PG_PREP) {
        int i = (blk - PG_CAST - PG_EW) * 256 + tid;
        if (i < B_ * H_) {
            int b = i >> 9, j = i & 511;
            float cv = a.se[b] ? a.padh[j] : a.cur[i];
            a.c_bf[i] = f2bf(cv);
            a.acat_bf[b * 1024 + j] = f2bf(a.left[i]);
            a.acat_bf[b * 1024 + 512 + j] = f2bf(cv);
        } else {
            int k = i - B_ * H_;
            a.rsc_bf[k] = f2bf(a.rsc[k]);
        }
    } else {
        int rel = blk - (PG_CAST + PG_EW + PG_PREP);
        int j = 0;
        while (rel >= a.tbase[j + 1]) ++j;
        int r = rel - a.tbase[j];
        int K = a.tK[j];
        const float* src = a.tsrc[j];
        unsigned short* dst = a.tdst[j];
        int bx = (r & 15) * 32;   // n tile
        int by = (r >> 4) * 32;   // k tile
        int tx = tid & 31, ty = tid >> 5;
        #pragma unroll
        for (int i = 0; i < 32; i += 8)
            t[ty + i][tx] = src[(size_t)(by + ty + i) * 512 + bx + tx];
        __syncthreads();
        #pragma unroll
        for (int i = 0; i < 32; i += 8)
            dst[(size_t)(bx + ty + i) * K + by + tx] = f2bf(t[tx][ty + i]);
    }
}

// gates -> q_bf, node_out (fp32 output), leaf_bf[:, :H]
__global__ void k_node(const float* __restrict__ gl, const float* __restrict__ glg,
                       const float* __restrict__ gr, const float* __restrict__ grg,
                       const float* __restrict__ bl, const float* __restrict__ blg,
                       const float* __restrict__ br, const float* __restrict__ brg,
                       const int* __restrict__ hl,
                       unsigned short* __restrict__ q_bf, float* __restrict__ node_out,
                       unsigned short* __restrict__ leaf_bf) {
    int i = blockIdx.x * blockDim.x + threadIdx.x;
    int b = i >> 9, j = i & 511;
    float nl = fast_tanh(gl[i] + bl[j]) * fast_sigmoid(glg[i] + blg[j]);
    float nr = fast_tanh(gr[i] + br[j]) * fast_sigmoid(grg[i] + brg[j]);
    float v = hl[b] ? nr : nl;
    node_out[i] = v;
    q_bf[i] = f2bf(v);
    leaf_bf[b * 1024 + j] = f2bf(v);
}

// fused tree score + softmax: one block per b (eobuf stride 1024, cols 0..511)
__global__ __launch_bounds__(256) void k_tree_attn(const float* __restrict__ qT,
                                                   const unsigned short* __restrict__ eobuf,
                                                   const float* __restrict__ b_ta,
                                                   const float* __restrict__ w_ts,
                                                   const float* __restrict__ b_ts,
                                                   const int* __restrict__ sm,
                                                   float* __restrict__ attn) {
    __shared__ float sc[S_];
    int b = blockIdx.x;
    int tid = threadIdx.x;
    int wid = tid >> 6, lane = tid & 63;
    int j0 = lane * 8;
    float4 q0 = *(const float4*)(qT + b * H_ + j0);
    float4 q1 = *(const float4*)(qT + b * H_ + j0 + 4);
    float4 t0 = *(const float4*)(b_ta + j0);
    float4 t1 = *(const float4*)(b_ta + j0 + 4);
    float4 w0 = *(const float4*)(w_ts + j0);
    float4 w1 = *(const float4*)(w_ts + j0 + 4);
    float qc[8] = {C2_*(q0.x+t0.x), C2_*(q0.y+t0.y), C2_*(q0.z+t0.z), C2_*(q0.w+t0.w),
                   C2_*(q1.x+t1.x), C2_*(q1.y+t1.y), C2_*(q1.z+t1.z), C2_*(q1.w+t1.w)};
    float w2[8] = {2*w0.x, 2*w0.y, 2*w0.z, 2*w0.w, 2*w1.x, 2*w1.y, 2*w1.z, 2*w1.w};
    float wsum = 0.5f * (w2[0]+w2[1]+w2[2]+w2[3]+w2[4]+w2[5]+w2[6]+w2[7]);
    float bias = b_ts[0];

    for (int s = wid; s < S_; s += 4) {
        if (sm[b * S_ + s]) {
            if (lane == 0) sc[s] = NEGV;
            continue;
        }
        uint4 ev = *(const uint4*)(eobuf + ((size_t)s * B_ + b) * 1024 + j0);
        const unsigned short* ep = (const unsigned short*)&ev;
        float acc = -wsum;
        #pragma unroll
        for (int k = 0; k < 8; ++k) {
            float y = fmaf(C2_, bf2f(ep[k]), qc[k]);
            acc = fmaf(w2[k], rcp_f(1.0f + exp2_f(y)), acc);
        }
        #pragma unroll
        for (int o = 32; o > 0; o >>= 1) acc += __shfl_xor(acc, o);
        if (lane == 0) sc[s] = acc + bias;
    }
    __syncthreads();
    if (tid < 64) {
        float v0 = sc[tid], v1 = sc[tid + 64];
        float m = fmaxf(v0, v1);
        #pragma unroll
        for (int o = 32; o > 0; o >>= 1) m = fmaxf(m, __shfl_xor(m, o));
        float e0 = __expf(v0 - m), e1 = __expf(v1 - m);
        float ss = e0 + e1;
        #pragma unroll
        for (int o = 32; o > 0; o >>= 1) ss += __shfl_xor(ss, o);
        float r = rcp_f(ss);
        attn[b * S_ + tid] = e0 * r;
        attn[b * S_ + tid + 64] = e1 * r;
    }
}

// rule scores: wave per (s,b)-row (eobuf stride 1024, cols 512..1023)
__global__ __launch_bounds__(256) void k_rule_score2(const unsigned short* __restrict__ eobuf,
                                                     const float* __restrict__ RP,
                                                     const float* __restrict__ b_ra,
                                                     const float* __restrict__ w_rs,
                                                     const float* __restrict__ b_rs,
                                                     const int* __restrict__ sm,
                                                     float* __restrict__ comb) {
    int wid = threadIdx.x >> 6, lane = threadIdx.x & 63;
    int row = blockIdx.x * 4 + wid;   // s*B + b
    int s = row >> 7, b = row & 127;
    bool masked = sm[b * S_ + s] != 0;
    if (masked) {
        if (lane < R_) comb[((size_t)b * R_ + lane) * S_ + s] = NEGV;
        return;
    }
    int j0 = lane * 8;
    uint4 ev = *(const uint4*)(eobuf + (size_t)row * 1024 + 512 + j0);
    const unsigned short* ep = (const unsigned short*)&ev;
    float4 a0 = *(const float4*)(b_ra + j0);
    float4 a1 = *(const float4*)(b_ra + j0 + 4);
    float4 w0 = *(const float4*)(w_rs + j0);
    float4 w1 = *(const float4*)(w_rs + j0 + 4);
    float ba[8] = {a0.x, a0.y, a0.z, a0.w, a1.x, a1.y, a1.z, a1.w};
    float w2[8], ed[8];
    float wsum = 0.f;
    {
        float w[8] = {w0.x, w0.y, w0.z, w0.w, w1.x, w1.y, w1.z, w1.w};
        #pragma unroll
        for (int k = 0; k < 8; ++k) {
            wsum += w[k];
            w2[k] = 2.0f * w[k];
            ed[k] = C2_ * (bf2f(ep[k]) + ba[k]);
        }
    }
    float bias = b_rs[0];
    #pragma unroll
    for (int r = 0; r < R_; ++r) {
        float4 r0 = *(const float4*)(RP + r * H_ + j0);
        float4 r1 = *(const float4*)(RP + r * H_ + j0 + 4);
        float rp[8] = {r0.x, r0.y, r0.z, r0.w, r1.x, r1.y, r1.z, r1.w};
        float acc = -wsum;
        #pragma unroll
        for (int k = 0; k < 8; ++k) {
            float y = fmaf(C2_, rp[k], ed[k]);
            acc = fmaf(w2[k], rcp_f(1.0f + exp2_f(y)), acc);
        }
        #pragma unroll
        for (int o = 32; o > 0; o >>= 1) acc += __shfl_xor(acc, o);
        if (lane == 0) comb[((size_t)b * R_ + r) * S_ + s] = acc + bias;
    }
}

__global__ __launch_bounds__(128) void k_softmax_rules(float* __restrict__ comb,
                                                       const float* __restrict__ attn) {
    __shared__ float red[2], red2[2];
    int br = blockIdx.x;
    int b = br >> 4;
    int t = threadIdx.x;
    float* row = comb + (size_t)br * 128;
    float v = row[t];
    float m = v;
    for (int o = 32; o > 0; o >>= 1) m = fmaxf(m, __shfl_down(m, o));
    if ((t & 63) == 0) red[t >> 6] = m;
    __syncthreads();
    m = fmaxf(red[0], red[1]);
    float e = __expf(v - m);
    float ssum = e;
    for (int o = 32; o > 0; o >>= 1) ssum += __shfl_down(ssum, o);
    if ((t & 63) == 0) red2[t >> 6] = ssum;
    __syncthreads();
    row[t] = e * rcp_f(red2[0] + red2[1]) + 0.2f * attn[b * 128 + t];
}

// contexts; masked s skipped; emits ctx (fp32 out), leaf_bf[:, H:], rctx_bf
__global__ __launch_bounds__(256) void k_context(const float* __restrict__ EO,
                                                 const float* __restrict__ attn,
                                                 const float* __restrict__ comb,
                                                 const int* __restrict__ sm,
                                                 float* __restrict__ ctx_out,
                                                 unsigned short* __restrict__ leaf_bf,
                                                 unsigned short* __restrict__ rctx) {
    __shared__ float at[S_];
    __shared__ float cb[R_ * S_];
    __shared__ int smr[S_];
    int b = blockIdx.x;
    int j = blockIdx.y * 256 + threadIdx.x;
    if (threadIdx.x < S_) {
        at[threadIdx.x] = attn[b * S_ + threadIdx.x];
        smr[threadIdx.x] = sm[b * S_ + threadIdx.x];
    }
    for (int i = threadIdx.x; i < R_ * S_; i += 256) cb[i] = comb[(size_t)b * R_ * S_ + i];
    __syncthreads();
    float ctx = 0.f;
    float rc[R_] = {};
    for (int s = 0; s < S_; ++s) {
        if (smr[s]) continue;
        float eo = EO[((size_t)s * B_ + b) * H_ + j];
        ctx += at[s] * eo;
        #pragma unroll
        for (int r = 0; r < R_; ++r) rc[r] += cb[r * S_ + s] * eo;
    }
    ctx_out[b * H_ + j] = ctx;
    leaf_bf[b * 1024 + 512 + j] = f2bf(ctx);
    #pragma unroll
    for (int r = 0; r < R_; ++r) rctx[((size_t)b * R_ + r) * H_ + j] = f2bf(rc[r]);
}

// ---------------------------------------------------------------------------
// fused epilogue: rp2 (blocks 0..127) | numscore (128..703) | op (704..735)
// ---------------------------------------------------------------------------
__global__ __launch_bounds__(256) void k_epilogue(const float* __restrict__ rclin,
                                                  const float* __restrict__ b_rp1,
                                                  const float* __restrict__ w_rp2,
                                                  const float* __restrict__ b_rp2,
                                                  float* __restrict__ prob,
                                                  const float* __restrict__ lsb,
                                                  const unsigned short* __restrict__ ewp,
                                                  const float* __restrict__ b_sc,
                                                  const float* __restrict__ w_scs,
                                                  const int* __restrict__ mask_nums,
                                                  float* __restrict__ ns_out,
                                                  const unsigned short* __restrict__ leaf_bf,
                                                  const float* __restrict__ Wops,
                                                  const float* __restrict__ bops,
                                                  float* __restrict__ op_out) {
    __shared__ float sc[R_];
    int blk = blockIdx.x;
    int wid = threadIdx.x >> 6, lane = threadIdx.x & 63;
    if (blk < 128) {
        // ---- rule_prob ----
        int b = blk;
        int j0 = lane * 8;
        float4 p0 = *(const float4*)(b_rp1 + j0);
        float4 p1 = *(const float4*)(b_rp1 + j0 + 4);
        float4 w0 = *(const float4*)(w_rp2 + j0);
        float4 w1 = *(const float4*)(w_rp2 + j0 + 4);
        float brc[8] = {C2_*p0.x, C2_*p0.y, C2_*p0.z, C2_*p0.w,
                        C2_*p1.x, C2_*p1.y, C2_*p1.z, C2_*p1.w};
        float w[8] = {w0.x, w0.y, w0.z, w0.w, w1.x, w1.y, w1.z, w1.w};
        float wsum = 0.f;
        #pragma unroll
        for (int k = 0; k < 8; ++k) wsum += w[k];
        #pragma unroll
        for (int rr = 0; rr < 4; ++rr) {
            int r = wid * 4 + rr;
            const float* rl = rclin + ((size_t)b * R_ + r) * H_ + j0;
            float4 r0 = *(const float4*)(rl);
            float4 r1 = *(const float4*)(rl + 4);
            float rv[8] = {r0.x, r0.y, r0.z, r0.w, r1.x, r1.y, r1.z, r1.w};
            float acc = -wsum;
            #pragma unroll
            for (int k = 0; k < 8; ++k) {
                float y = fmaf(C2_, rv[k], brc[k]);
                acc = fmaf(2.0f * w[k], rcp_f(1.0f + exp2_f(y)), acc);
            }
            #pragma unroll
            for (int o = 32; o > 0; o >>= 1) acc += __shfl_xor(acc, o);
            if (lane == 0) sc[r] = acc + b_rp2[0];
        }
        __syncthreads();
        if (threadIdx.x < R_) {
            float m = -1e30f;
            for (int r = 0; r < R_; ++r) m = fmaxf(m, sc[r]);
            float sum = 0.f;
            for (int r = 0; r < R_; ++r) sum += __expf(sc[r] - m);
            prob[b * R_ + threadIdx.x] = __expf(sc[threadIdx.x] - m) * rcp_f(sum);
        }
    } else if (blk < 704) {
        // ---- num_score ----
        int row = (blk - 128) * 4 + wid;   // b*L + l, < 2304
        int b = row / L_, l = row - b * L_;
        bool masked = mask_nums[b * L_ + l] != 0;
        if (masked) {
            if (lane == 0) ns_out[b * L_ + l] = NEGV;
            return;
        }
        int j0 = lane * 8;
        uint4 ev = *(const uint4*)(ewp + (size_t)row * H_ + j0);
        const unsigned short* ep = (const unsigned short*)&ev;
        float4 l0 = *(const float4*)(lsb + b * H_ + j0);
        float4 l1 = *(const float4*)(lsb + b * H_ + j0 + 4);
        float4 s0 = *(const float4*)(b_sc + j0);
        float4 s1 = *(const float4*)(b_sc + j0 + 4);
        float4 w0 = *(const float4*)(w_scs + j0);
        float4 w1 = *(const float4*)(w_scs + j0 + 4);
        float lc[8] = {C2_*(l0.x+s0.x), C2_*(l0.y+s0.y), C2_*(l0.z+s0.z), C2_*(l0.w+s0.w),
                       C2_*(l1.x+s1.x), C2_*(l1.y+s1.y), C2_*(l1.z+s1.z), C2_*(l1.w+s1.w)};
        float w[8] = {w0.x, w0.y, w0.z, w0.w, w1.x, w1.y, w1.z, w1.w};
        float wsum = 0.f;
        #pragma unroll
        for (int k = 0; k < 8; ++k) wsum += w[k];
        float acc = -wsum;
        #pragma unroll
        for (int k = 0; k < 8; ++k) {
            float y = fmaf(C2_, bf2f(ep[k]), lc[k]);
            acc = fmaf(2.0f * w[k], rcp_f(1.0f + exp2_f(y)), acc);
        }
        #pragma unroll
        for (int o = 32; o > 0; o >>= 1) acc += __shfl_xor(acc, o);
        if (lane == 0) ns_out[b * L_ + l] = acc;
    } else {
        // ---- op ----  wave per b, 5 dots of K=1024
        int b = (blk - 704) * 4 + wid;
        int base = b * 1024 + lane * 16;
        uint4 v0 = *(const uint4*)(leaf_bf + base);
        uint4 v1 = *(const uint4*)(leaf_bf + base + 8);
        const unsigned short* lp0 = (const unsigned short*)&v0;
        const unsigned short* lp1 = (const unsigned short*)&v1;
        float lv[16];
        #pragma unroll
        for (int k = 0; k < 8; ++k) { lv[k] = bf2f(lp0[k]); lv[8 + k] = bf2f(lp1[k]); }
        #pragma unroll
        for (int o = 0; o < OPS_; ++o) {
            float acc = 0.f;
            #pragma unroll
            for (int k = 0; k < 16; ++k)
                acc = fmaf(lv[k], Wops[(size_t)(lane * 16 + k) * OPS_ + o], acc);
            #pragma unroll
            for (int of = 32; of > 0; of >>= 1) acc += __shfl_xor(acc, of);
            if (lane == 0) op_out[b * OPS_ + o] = acc + bops[o];
        }
    }
}

// ---------------------------------------------------------------------------
extern "C" void kernel_launch(void* const* d_in, const int* in_sizes, int n_in,
                              void* d_out, int out_size, void* d_ws, size_t ws_size,
                              hipStream_t stream) {
    const float* EO   = (const float*)d_in[0];
    const float* cur  = (const float*)d_in[1];
    const float* left = (const float*)d_in[2];
    const float* padh = (const float*)d_in[3];
    const float* npad = (const float*)d_in[4];
    const float* rsc  = (const float*)d_in[5];
    const float* embw = (const float*)d_in[6];
    const float* Wl   = (const float*)d_in[7];  const float* bl   = (const float*)d_in[8];
    const float* Wlg  = (const float*)d_in[9];  const float* blg  = (const float*)d_in[10];
    const float* Wr   = (const float*)d_in[11]; const float* br   = (const float*)d_in[12];
    const float* Wrg  = (const float*)d_in[13]; const float* brg  = (const float*)d_in[14];
    const float* Wta  = (const float*)d_in[15]; const float* bta  = (const float*)d_in[16];
    const float* Wts  = (const float*)d_in[17]; const float* bts  = (const float*)d_in[18];
    const float* Wra  = (const float*)d_in[19]; const float* bra  = (const float*)d_in[20];
    const float* Wrs  = (const float*)d_in[21]; const float* brs  = (const float*)d_in[22];
    const float* Wrp1 = (const float*)d_in[23]; const float* brp1 = (const float*)d_in[24];
    const float* Wrp2 = (const float*)d_in[25]; const float* brp2 = (const float*)d_in[26];
    const float* Wsa  = (const float*)d_in[27]; const float* bsa  = (const float*)d_in[28];
    const float* Wss  = (const float*)d_in[29];
    const float* Wops = (const float*)d_in[30]; const float* bops = (const float*)d_in[31];
    const int* smk = (const int*)d_in[32];
    const int* nmk = (const int*)d_in[33];
    const int* hlk = (const int*)d_in[34];
    const int* sek = (const int*)d_in[35];

    float* out = (float*)d_out;

    const size_t O_NS    = 0;
    const size_t O_OP    = O_NS + (size_t)B_ * L_;
    const size_t O_NODE  = O_OP + (size_t)B_ * OPS_;
    const size_t O_CTX   = O_NODE + (size_t)B_ * H_;
    const size_t O_EW    = O_CTX + (size_t)B_ * H_;
    const size_t O_RPROB = O_EW + (size_t)B_ * L_ * H_;

    // ---- workspace layout (no aliasing; ws is ~256 MB) ----
    float* f = (float*)d_ws;
    float* rp_buf = f;               f += 8192;      // R x H rule projection
    float* qT     = f;               f += 65536;
    float* attn   = f;               f += 16384;
    float* comb   = f;               f += 262144;
    float* gl     = f;               f += 65536;
    float* glg    = f;               f += 65536;
    float* gr     = f;               f += 65536;
    float* grg    = f;               f += 65536;
    float* lsb    = f;               f += 65536;
    float* rclin  = f;               f += 1048576;
    unsigned short* u = (unsigned short*)f;
    unsigned short* EO_bf   = u;     u += 8388608;
    unsigned short* ew_bf   = u;     u += 1179648;
    unsigned short* leaf_bf = u;     u += 131072;
    unsigned short* rctx_bf = u;     u += 1048576;
    unsigned short* Wcat    = u;     u += 524288;    // [Wta[h:]^T ; Wra[:h]^T]  1024x512
    unsigned short* T0      = u;     u += 262144;    // Wl^T
    unsigned short* T1      = u;     u += 262144;    // Wlg^T
    unsigned short* T2      = u;     u += 524288;    // Wr^T      K=1024
    unsigned short* T3      = u;     u += 524288;    // Wrg^T     K=1024
    unsigned short* T4      = u;     u += 262144;    // Wra[h:]^T
    unsigned short* T5      = u;     u += 262144;    // Wta[:h]^T
    unsigned short* T8      = u;     u += 262144;    // Wrp1^T
    unsigned short* T9      = u;     u += 524288;    // Wsa[:2h]^T K=1024
    unsigned short* T10     = u;     u += 262144;    // Wsa[2h:]^T
    unsigned short* q_bf    = u;     u += 65536;
    unsigned short* c_bf    = u;     u += 65536;
    unsigned short* acat_bf = u;     u += 131072;
    unsigned short* rsc_bf  = u;     u += 8192;
    unsigned short* ewp_bf  = u;     u += 1179648;
    unsigned short* eobuf   = u;     u += 16777216;  // 16384 x 1024

    // d1: fused prep
    PrepArgs a;
    a.EO = EO; a.cur = cur; a.padh = padh; a.left = left; a.rsc = rsc;
    a.embw = embw; a.npad = npad; a.se = sek;
    a.EO_bf = EO_bf; a.c_bf = c_bf; a.acat_bf = acat_bf; a.rsc_bf = rsc_bf;
    a.ew_bf = ew_bf; a.ew_out = out + O_EW;
    const float* tsrc[11] = {Wl, Wlg, Wr, Wrg, Wra + (size_t)H_ * H_, Wta,
                             Wta + (size_t)H_ * H_, Wra, Wrp1, Wsa, Wsa + (size_t)2 * H_ * H_};
    unsigned short* tdst[11] = {T0, T1, T2, T3, T4, T5, Wcat, Wcat + 512 * 512, T8, T9, T10};
    int tk[11] = {512, 512, 1024, 1024, 512, 512, 512, 512, 512, 1024, 512};
    int base = 0;
    for (int i = 0; i < 11; ++i) {
        a.tsrc[i] = tsrc[i]; a.tdst[i] = tdst[i]; a.tK[i] = tk[i];
        a.tbase[i] = base;
        base += 16 * (tk[i] / 32);
    }
    a.tbase[11] = base;   // 3584
    k_prep_mega<<<PG_TOTAL, 256, 0, stream>>>(a);

    // d2: 5-way batched MFMA (node gates + rule projection)
    MJ5 g;
    g.A[0] = c_bf;    g.Bt[0] = T0; g.C[0] = gl;     g.M[0] = B_;  g.K[0] = 512;
    g.A[1] = c_bf;    g.Bt[1] = T1; g.C[1] = glg;    g.M[1] = B_;  g.K[1] = 512;
    g.A[2] = acat_bf; g.Bt[2] = T2; g.C[2] = gr;     g.M[2] = B_;  g.K[2] = 1024;
    g.A[3] = acat_bf; g.Bt[3] = T3; g.C[3] = grg;    g.M[3] = B_;  g.K[3] = 1024;
    g.A[4] = rsc_bf;  g.Bt[4] = T4; g.C[4] = rp_buf; g.M[4] = R_;  g.K[4] = 512;
    gemm_bf16_j5<<<dim3(4, 1, 5), 256, 0, stream>>>(g);

    // d3: node gates
    k_node<<<256, 256, 0, stream>>>(gl, glg, gr, grg, bl, blg, br, brg, hlk,
                                    q_bf, out + O_NODE, leaf_bf);

    // d4: mega-GEMM 1 (EO projections fused N=1024, + qT)
    k_gemm_mega1<<<1028, 256, 0, stream>>>(EO_bf, Wcat, eobuf, q_bf, T5, qT);

    // d5: tree attention (score + softmax)
    k_tree_attn<<<B_, 256, 0, stream>>>(qT, eobuf, bta, Wts, bts, smk, attn);

    // d6-d7: rule attention
    k_rule_score2<<<S_ * B_ / 4, 256, 0, stream>>>(eobuf, rp_buf, bra, Wrs, brs, smk, comb);
    k_softmax_rules<<<B_ * R_, 128, 0, stream>>>(comb, attn);

    // d8: contexts
    k_context<<<dim3(B_, 2), 256, 0, stream>>>(EO, attn, comb, smk, out + O_CTX,
                                               leaf_bf, rctx_bf);

    // d9: mega-GEMM 2 (rclin, lsb, ewp)
    k_gemm_mega2<<<140, 256, 0, stream>>>(rctx_bf, T8, rclin, leaf_bf, T9, lsb,
                                          ew_bf, T10, ewp_bf);

    // d10: fused epilogue (rule_prob, num_score, op)
    k_epilogue<<<736, 256, 0, stream>>>(rclin, brp1, Wrp2, brp2, out + O_RPROB,
                                        lsb, ewp_bf, bsa, Wss, nmk, out + O_NS,
                                        leaf_bf, Wops, bops, out + O_OP);
}

// Round 6
// 298.186 us; speedup vs baseline: 2.8628x; 1.1180x over previous
//
#include <hip/hip_runtime.h>
#include <hip/hip_bf16.h>

// Problem constants
#define B_ 128
#define S_ 128
#define H_ 512
#define R_ 16
#define IN_ 2
#define OPS_ 5
#define NPAD_ 16
#define L_ 18          // IN_ + NPAD_
#define NEGV (-1000000000000.0f)
#define C2_ (-2.885390081777927f)   // -2*log2(e):  tanh(x) = 2*rcp(1+exp2(C2*x)) - 1

typedef __bf16 bf16_t;
typedef bf16_t bf16x8 __attribute__((ext_vector_type(8)));
typedef float floatx4 __attribute__((ext_vector_type(4)));

__device__ __forceinline__ float rcp_f(float x) { return __builtin_amdgcn_rcpf(x); }
__device__ __forceinline__ float exp2_f(float x) { return __builtin_amdgcn_exp2f(x); }

__device__ __forceinline__ float fast_tanh(float x) {
    return 2.0f * rcp_f(1.0f + exp2_f(C2_ * x)) - 1.0f;
}
__device__ __forceinline__ float fast_sigmoid(float x) {
    return rcp_f(1.0f + exp2_f(-1.4426950408889634f * x));
}
__device__ __forceinline__ unsigned short f2bf(float f) {   // RNE
    unsigned int u = __builtin_bit_cast(unsigned int, f);
    u += 0x7fff + ((u >> 16) & 1);
    return (unsigned short)(u >> 16);
}
__device__ __forceinline__ float bf2f(unsigned short u) {
    return __builtin_bit_cast(float, (unsigned int)u << 16);
}

// ---------------------------------------------------------------------------
// bf16 MFMA tile body with cross-iteration register prefetch.
// One 128x128 C-tile at (m0,n0). A row-major [.,K], Bt row-major [N,K] (=B^T).
// Full tiles only. 4 waves, BK=32, 16x16x32 MFMA.
// ---------------------------------------------------------------------------
#define LSTR 40

__device__ __forceinline__ void mfma_tile(const unsigned short* __restrict__ A,
                                          const unsigned short* __restrict__ Bt,
                                          void* __restrict__ Cv, bool bf16_out,
                                          int m0, int n0, int K, int ldc,
                                          unsigned short* As, unsigned short* Bs) {
    const int tid  = threadIdx.x;
    const int wid  = tid >> 6, lane = tid & 63;
    const int quad = lane >> 4, mn = lane & 15;
    const int wm = (wid & 1) * 64, wn = (wid >> 1) * 64;
    const int sr = tid >> 2;
    const int sc = (tid & 3) * 8;

    const unsigned short* pa0 = A  + (size_t)(m0 + sr)      * K + sc;
    const unsigned short* pa1 = A  + (size_t)(m0 + sr + 64) * K + sc;
    const unsigned short* pb0 = Bt + (size_t)(n0 + sr)      * K + sc;
    const unsigned short* pb1 = Bt + (size_t)(n0 + sr + 64) * K + sc;

    uint4 a0 = *(const uint4*)pa0;
    uint4 a1 = *(const uint4*)pa1;
    uint4 b0 = *(const uint4*)pb0;
    uint4 b1 = *(const uint4*)pb1;

    floatx4 acc[4][4] = {};

    for (int k0 = 0; k0 < K; k0 += 32) {
        __syncthreads();
        *(uint4*)&As[sr * LSTR + sc]        = a0;
        *(uint4*)&As[(sr + 64) * LSTR + sc] = a1;
        *(uint4*)&Bs[sr * LSTR + sc]        = b0;
        *(uint4*)&Bs[(sr + 64) * LSTR + sc] = b1;
        __syncthreads();

        // prefetch next K-tile while this tile computes
        if (k0 + 32 < K) {
            a0 = *(const uint4*)(pa0 + k0 + 32);
            a1 = *(const uint4*)(pa1 + k0 + 32);
            b0 = *(const uint4*)(pb0 + k0 + 32);
            b1 = *(const uint4*)(pb1 + k0 + 32);
        }

        bf16x8 af[4], bfr[4];
        #pragma unroll
        for (int i = 0; i < 4; ++i)
            af[i] = *(const bf16x8*)&As[(wm + i * 16 + mn) * LSTR + quad * 8];
        #pragma unroll
        for (int j = 0; j < 4; ++j)
            bfr[j] = *(const bf16x8*)&Bs[(wn + j * 16 + mn) * LSTR + quad * 8];

        #pragma unroll
        for (int i = 0; i < 4; ++i)
            #pragma unroll
            for (int j = 0; j < 4; ++j)
                acc[i][j] = __builtin_amdgcn_mfma_f32_16x16x32_bf16(af[i], bfr[j], acc[i][j], 0, 0, 0);
    }

    // C/D layout: col = lane&15, row = quad*4 + reg   [verified m89/m91]
    #pragma unroll
    for (int i = 0; i < 4; ++i) {
        #pragma unroll
        for (int j = 0; j < 4; ++j) {
            #pragma unroll
            for (int r = 0; r < 4; ++r) {
                int row = m0 + wm + i * 16 + quad * 4 + r;
                int col = n0 + wn + j * 16 + mn;
                if (bf16_out)
                    ((unsigned short*)Cv)[(size_t)row * ldc + col] = f2bf(acc[i][j][r]);
                else
                    ((float*)Cv)[(size_t)row * ldc + col] = acc[i][j][r];
            }
        }
    }
}

// mega-GEMM 1: blocks 0..1023 = EO_bf @ Wcat (N=1024 -> eobuf bf16, ld 1024),
//   XCD-friendly mapping m=blk&127, n=blk>>7 (same-m blocks share an XCD L2);
//   blocks 1024..1027 = q_bf @ T5 (-> qT fp32, ld 512)
__global__ __launch_bounds__(256) void k_gemm_mega1(const unsigned short* __restrict__ EO_bf,
                                                    const unsigned short* __restrict__ Wcat,
                                                    unsigned short* __restrict__ eobuf,
                                                    const unsigned short* __restrict__ q_bf,
                                                    const unsigned short* __restrict__ T5,
                                                    float* __restrict__ qT) {
    __shared__ unsigned short As[128 * LSTR];
    __shared__ unsigned short Bs[128 * LSTR];
    int blk = blockIdx.x;
    if (blk < 1024)
        mfma_tile(EO_bf, Wcat, eobuf, true, (blk & 127) * 128, (blk >> 7) * 128, 512, 1024, As, Bs);
    else
        mfma_tile(q_bf, T5, qT, false, 0, (blk - 1024) * 128, 512, 512, As, Bs);
}

// mega-GEMM 2: rctx@T8 (64 blk), leaf@T9 (4 blk), ew@T10 (72 blk)
__global__ __launch_bounds__(256) void k_gemm_mega2(const unsigned short* __restrict__ rctx_bf,
                                                    const unsigned short* __restrict__ T8,
                                                    float* __restrict__ rclin,
                                                    const unsigned short* __restrict__ leaf_bf,
                                                    const unsigned short* __restrict__ T9,
                                                    float* __restrict__ lsb,
                                                    const unsigned short* __restrict__ ew_bf,
                                                    const unsigned short* __restrict__ T10,
                                                    unsigned short* __restrict__ ewp_bf) {
    __shared__ unsigned short As[128 * LSTR];
    __shared__ unsigned short Bs[128 * LSTR];
    int blk = blockIdx.x;
    if (blk < 64)
        mfma_tile(rctx_bf, T8, rclin, false, (blk >> 2) * 128, (blk & 3) * 128, 512, 512, As, Bs);
    else if (blk < 68)
        mfma_tile(leaf_bf, T9, lsb, false, 0, (blk - 64) * 128, 1024, 512, As, Bs);
    else {
        int r = blk - 68;
        mfma_tile(ew_bf, T10, ewp_bf, true, (r >> 2) * 128, (r & 3) * 128, 512, 512, As, Bs);
    }
}

// z-batched 5-job GEMM, N=512 fixed, M<=128 (row-clamped loads, guarded stores)
struct MJ5 {
    const unsigned short* A[5]; const unsigned short* Bt[5]; float* C[5];
    int M[5]; int K[5];
};
__global__ __launch_bounds__(256) void gemm_bf16_j5(MJ5 g) {
    __shared__ unsigned short As[128 * LSTR];
    __shared__ unsigned short Bs[128 * LSTR];

    const int z = blockIdx.z;
    const unsigned short* A  = g.A[z];
    const unsigned short* Bt = g.Bt[z];
    float* C = g.C[z];
    const int M = g.M[z], K = g.K[z];

    const int tid  = threadIdx.x;
    const int wid  = tid >> 6, lane = tid & 63;
    const int quad = lane >> 4, mn = lane & 15;
    const int wm = (wid & 1) * 64, wn = (wid >> 1) * 64;
    const int n0 = blockIdx.x * 128;

    const int sr = tid >> 2;
    const int sc = (tid & 3) * 8;
    const int ra0 = min(sr, M - 1);
    const int ra1 = min(sr + 64, M - 1);

    const unsigned short* pa0 = A  + (size_t)ra0 * K + sc;
    const unsigned short* pa1 = A  + (size_t)ra1 * K + sc;
    const unsigned short* pb0 = Bt + (size_t)(n0 + sr)      * K + sc;
    const unsigned short* pb1 = Bt + (size_t)(n0 + sr + 64) * K + sc;

    uint4 a0 = *(const uint4*)pa0;
    uint4 a1 = *(const uint4*)pa1;
    uint4 b0 = *(const uint4*)pb0;
    uint4 b1 = *(const uint4*)pb1;

    floatx4 acc[4][4] = {};

    for (int k0 = 0; k0 < K; k0 += 32) {
        __syncthreads();
        *(uint4*)&As[sr * LSTR + sc]        = a0;
        *(uint4*)&As[(sr + 64) * LSTR + sc] = a1;
        *(uint4*)&Bs[sr * LSTR + sc]        = b0;
        *(uint4*)&Bs[(sr + 64) * LSTR + sc] = b1;
        __syncthreads();

        if (k0 + 32 < K) {
            a0 = *(const uint4*)(pa0 + k0 + 32);
            a1 = *(const uint4*)(pa1 + k0 + 32);
            b0 = *(const uint4*)(pb0 + k0 + 32);
            b1 = *(const uint4*)(pb1 + k0 + 32);
        }

        bf16x8 af[4], bfr[4];
        #pragma unroll
        for (int i = 0; i < 4; ++i)
            af[i] = *(const bf16x8*)&As[(wm + i * 16 + mn) * LSTR + quad * 8];
        #pragma unroll
        for (int j = 0; j < 4; ++j)
            bfr[j] = *(const bf16x8*)&Bs[(wn + j * 16 + mn) * LSTR + quad * 8];

        #pragma unroll
        for (int i = 0; i < 4; ++i)
            #pragma unroll
            for (int j = 0; j < 4; ++j)
                acc[i][j] = __builtin_amdgcn_mfma_f32_16x16x32_bf16(af[i], bfr[j], acc[i][j], 0, 0, 0);
    }

    #pragma unroll
    for (int i = 0; i < 4; ++i) {
        #pragma unroll
        for (int j = 0; j < 4; ++j) {
            #pragma unroll
            for (int r = 0; r < 4; ++r) {
                int row = wm + i * 16 + quad * 4 + r;
                int col = n0 + wn + j * 16 + mn;
                if (row < M)
                    C[(size_t)row * 512 + col] = acc[i][j][r];
            }
        }
    }
}

// ---------------------------------------------------------------------------
// fused prep: EO cast | ew build | c/acat/rsc cast | 11 weight transposes
// ---------------------------------------------------------------------------
struct PrepArgs {
    const float *EO, *cur, *padh, *left, *rsc, *embw, *npad;
    const int* se;
    unsigned short *EO_bf, *c_bf, *acat_bf, *rsc_bf, *ew_bf;
    float* ew_out;
    const float* tsrc[11];
    unsigned short* tdst[11];
    int tK[11];
    int tbase[12];
};
#define PG_CAST 8192
#define PG_EW   1152
#define PG_PREP 288
#define PG_WT   3584
#define PG_TOTAL (PG_CAST + PG_EW + PG_PREP + PG_WT)   // 13216

__global__ __launch_bounds__(256) void k_prep_mega(PrepArgs a) {
    __shared__ float t[32][33];
    int blk = blockIdx.x, tid = threadIdx.x;
    if (blk < PG_CAST) {
        int i = (blk * 256 + tid) * 4;
        float4 v = *(const float4*)(a.EO + i);
        ushort4 o;
        o.x = f2bf(v.x); o.y = f2bf(v.y); o.z = f2bf(v.z); o.w = f2bf(v.w);
        *(ushort4*)(a.EO_bf + i) = o;
    } else if (blk < PG_CAST + PG_EW) {
        int i = ((blk - PG_CAST) * 256 + tid) * 4;
        int j = i & 511;
        int bl = i >> 9;
        int l = bl % L_;
        int b = bl / L_;
        const float* src = (l < IN_) ? (a.embw + l * H_ + j)
                                     : (a.npad + ((size_t)b * NPAD_ + (l - IN_)) * H_ + j);
        float4 v = *(const float4*)src;
        *(float4*)(a.ew_out + i) = v;
        ushort4 o;
        o.x = f2bf(v.x); o.y = f2bf(v.y); o.z = f2bf(v.z); o.w = f2bf(v.w);
        *(ushort4*)(a.ew_bf + i) = o;
    } else if (blk < PG_CAST + PG_EW + PG_PREP) {
        int i = (blk - PG_CAST - PG_EW) * 256 + tid;
        if (i < B_ * H_) {
            int b = i >> 9, j = i & 511;
            float cv = a.se[b] ? a.padh[j] : a.cur[i];
            a.c_bf[i] = f2bf(cv);
            a.acat_bf[b * 1024 + j] = f2bf(a.left[i]);
            a.acat_bf[b * 1024 + 512 + j] = f2bf(cv);
        } else {
            int k = i - B_ * H_;
            a.rsc_bf[k] = f2bf(a.rsc[k]);
        }
    } else {
        int rel = blk - (PG_CAST + PG_EW + PG_PREP);
        int j = 0;
        while (rel >= a.tbase[j + 1]) ++j;
        int r = rel - a.tbase[j];
        int K = a.tK[j];
        const float* src = a.tsrc[j];
        unsigned short* dst = a.tdst[j];
        int bx = (r & 15) * 32;   // n tile
        int by = (r >> 4) * 32;   // k tile
        int tx = tid & 31, ty = tid >> 5;
        #pragma unroll
        for (int i = 0; i < 32; i += 8)
            t[ty + i][tx] = src[(size_t)(by + ty + i) * 512 + bx + tx];
        __syncthreads();
        #pragma unroll
        for (int i = 0; i < 32; i += 8)
            dst[(size_t)(bx + ty + i) * K + by + tx] = f2bf(t[tx][ty + i]);
    }
}

// gates -> q_bf, node_out (fp32 output), leaf_bf[:, :H]
__global__ void k_node(const float* __restrict__ gl, const float* __restrict__ glg,
                       const float* __restrict__ gr, const float* __restrict__ grg,
                       const float* __restrict__ bl, const float* __restrict__ blg,
                       const float* __restrict__ br, const float* __restrict__ brg,
                       const int* __restrict__ hl,
                       unsigned short* __restrict__ q_bf, float* __restrict__ node_out,
                       unsigned short* __restrict__ leaf_bf) {
    int i = blockIdx.x * blockDim.x + threadIdx.x;
    int b = i >> 9, j = i & 511;
    float nl = fast_tanh(gl[i] + bl[j]) * fast_sigmoid(glg[i] + blg[j]);
    float nr = fast_tanh(gr[i] + br[j]) * fast_sigmoid(grg[i] + brg[j]);
    float v = hl[b] ? nr : nl;
    node_out[i] = v;
    q_bf[i] = f2bf(v);
    leaf_bf[b * 1024 + j] = f2bf(v);
}

// ---------------------------------------------------------------------------
// fused scores: blocks 0..127 = tree score+softmax (block per b);
//               blocks 128..4223 = rule scores (wave per (s,b)-row)
// eobuf stride 1024: cols 0..511 tree proj, 512..1023 rule proj
// ---------------------------------------------------------------------------
__global__ __launch_bounds__(256) void k_score_fused(const float* __restrict__ qT,
                                                     const unsigned short* __restrict__ eobuf,
                                                     const float* __restrict__ b_ta,
                                                     const float* __restrict__ w_ts,
                                                     const float* __restrict__ b_ts,
                                                     const float* __restrict__ RP,
                                                     const float* __restrict__ b_ra,
                                                     const float* __restrict__ w_rs,
                                                     const float* __restrict__ b_rs,
                                                     const int* __restrict__ sm,
                                                     float* __restrict__ attn,
                                                     float* __restrict__ comb) {
    __shared__ float sc[S_];
    int blk = blockIdx.x;
    int tid = threadIdx.x;
    int wid = tid >> 6, lane = tid & 63;
    int j0 = lane * 8;

    if (blk < 128) {
        // ---- tree score + softmax ----
        int b = blk;
        float4 q0 = *(const float4*)(qT + b * H_ + j0);
        float4 q1 = *(const float4*)(qT + b * H_ + j0 + 4);
        float4 t0 = *(const float4*)(b_ta + j0);
        float4 t1 = *(const float4*)(b_ta + j0 + 4);
        float4 w0 = *(const float4*)(w_ts + j0);
        float4 w1 = *(const float4*)(w_ts + j0 + 4);
        float qc[8] = {C2_*(q0.x+t0.x), C2_*(q0.y+t0.y), C2_*(q0.z+t0.z), C2_*(q0.w+t0.w),
                       C2_*(q1.x+t1.x), C2_*(q1.y+t1.y), C2_*(q1.z+t1.z), C2_*(q1.w+t1.w)};
        float w2[8] = {2*w0.x, 2*w0.y, 2*w0.z, 2*w0.w, 2*w1.x, 2*w1.y, 2*w1.z, 2*w1.w};
        float wsum = 0.5f * (w2[0]+w2[1]+w2[2]+w2[3]+w2[4]+w2[5]+w2[6]+w2[7]);
        float bias = b_ts[0];

        for (int s = wid; s < S_; s += 4) {
            if (sm[b * S_ + s]) {
                if (lane == 0) sc[s] = NEGV;
                continue;
            }
            uint4 ev = *(const uint4*)(eobuf + ((size_t)s * B_ + b) * 1024 + j0);
            const unsigned short* ep = (const unsigned short*)&ev;
            float acc = -wsum;
            #pragma unroll
            for (int k = 0; k < 8; ++k) {
                float y = fmaf(C2_, bf2f(ep[k]), qc[k]);
                acc = fmaf(w2[k], rcp_f(1.0f + exp2_f(y)), acc);
            }
            #pragma unroll
            for (int o = 32; o > 0; o >>= 1) acc += __shfl_xor(acc, o);
            if (lane == 0) sc[s] = acc + bias;
        }
        __syncthreads();
        if (tid < 64) {
            float v0 = sc[tid], v1 = sc[tid + 64];
            float m = fmaxf(v0, v1);
            #pragma unroll
            for (int o = 32; o > 0; o >>= 1) m = fmaxf(m, __shfl_xor(m, o));
            float e0 = __expf(v0 - m), e1 = __expf(v1 - m);
            float ss = e0 + e1;
            #pragma unroll
            for (int o = 32; o > 0; o >>= 1) ss += __shfl_xor(ss, o);
            float r = rcp_f(ss);
            attn[b * S_ + tid] = e0 * r;
            attn[b * S_ + tid + 64] = e1 * r;
        }
        return;
    }

    // ---- rule scores ----
    int row = (blk - 128) * 4 + wid;   // s*B + b
    int s = row >> 7, b = row & 127;
    bool masked = sm[b * S_ + s] != 0;
    if (masked) {
        if (lane < R_) comb[((size_t)b * R_ + lane) * S_ + s] = NEGV;
        return;
    }
    uint4 ev = *(const uint4*)(eobuf + (size_t)row * 1024 + 512 + j0);
    const unsigned short* ep = (const unsigned short*)&ev;
    float4 a0 = *(const float4*)(b_ra + j0);
    float4 a1 = *(const float4*)(b_ra + j0 + 4);
    float4 w0 = *(const float4*)(w_rs + j0);
    float4 w1 = *(const float4*)(w_rs + j0 + 4);
    float ba[8] = {a0.x, a0.y, a0.z, a0.w, a1.x, a1.y, a1.z, a1.w};
    float w2[8], ed[8];
    float wsum = 0.f;
    {
        float w[8] = {w0.x, w0.y, w0.z, w0.w, w1.x, w1.y, w1.z, w1.w};
        #pragma unroll
        for (int k = 0; k < 8; ++k) {
            wsum += w[k];
            w2[k] = 2.0f * w[k];
            ed[k] = C2_ * (bf2f(ep[k]) + ba[k]);
        }
    }
    float bias = b_rs[0];
    #pragma unroll
    for (int r = 0; r < R_; ++r) {
        float4 r0 = *(const float4*)(RP + r * H_ + j0);
        float4 r1 = *(const float4*)(RP + r * H_ + j0 + 4);
        float rp[8] = {r0.x, r0.y, r0.z, r0.w, r1.x, r1.y, r1.z, r1.w};
        float acc = -wsum;
        #pragma unroll
        for (int k = 0; k < 8; ++k) {
            float y = fmaf(C2_, rp[k], ed[k]);
            acc = fmaf(w2[k], rcp_f(1.0f + exp2_f(y)), acc);
        }
        #pragma unroll
        for (int o = 32; o > 0; o >>= 1) acc += __shfl_xor(acc, o);
        if (lane == 0) comb[((size_t)b * R_ + r) * S_ + s] = acc + bias;
    }
}

// ---------------------------------------------------------------------------
// fused rules-softmax + contexts: one 512-thread block per b.
// comb holds RAW rule scores; this kernel softmaxes them (+0.2*attn) in LDS,
// then computes current_context and rules_context from EO_bf.
// ---------------------------------------------------------------------------
__global__ __launch_bounds__(512) void k_ctxsm(const unsigned short* __restrict__ EO_bf,
                                               const float* __restrict__ attn,
                                               const float* __restrict__ comb,
                                               const int* __restrict__ sm,
                                               float* __restrict__ ctx_out,
                                               unsigned short* __restrict__ leaf_bf,
                                               unsigned short* __restrict__ rctx) {
    __shared__ float cb[R_ * S_];
    __shared__ float at[S_];
    __shared__ int smr[S_];
    int b = blockIdx.x;
    int tid = threadIdx.x;
    int w = tid >> 6, lane = tid & 63;

    if (tid < S_) {
        at[tid] = attn[b * S_ + tid];
        smr[tid] = sm[b * S_ + tid];
    }
    for (int i = tid; i < R_ * S_; i += 512) cb[i] = comb[(size_t)b * R_ * S_ + i];
    __syncthreads();

    // softmax over s for rows 2w, 2w+1  (8 waves x 2 rows = 16)
    #pragma unroll
    for (int rr = 0; rr < 2; ++rr) {
        int r = w * 2 + rr;
        float v0 = cb[r * S_ + lane], v1 = cb[r * S_ + lane + 64];
        float m = fmaxf(v0, v1);
        #pragma unroll
        for (int o = 32; o > 0; o >>= 1) m = fmaxf(m, __shfl_xor(m, o));
        float e0 = __expf(v0 - m), e1 = __expf(v1 - m);
        float ss = e0 + e1;
        #pragma unroll
        for (int o = 32; o > 0; o >>= 1) ss += __shfl_xor(ss, o);
        float rc_ = rcp_f(ss);
        cb[r * S_ + lane]      = e0 * rc_ + 0.2f * at[lane];
        cb[r * S_ + lane + 64] = e1 * rc_ + 0.2f * at[lane + 64];
    }
    __syncthreads();

    // contexts: thread tid handles j = tid (H=512)
    int j = tid;
    float ctx = 0.f;
    float rc[R_] = {};
    for (int s = 0; s < S_; ++s) {
        if (smr[s]) continue;
        float eo = bf2f(EO_bf[((size_t)s * B_ + b) * H_ + j]);
        ctx += at[s] * eo;
        #pragma unroll
        for (int r = 0; r < R_; ++r) rc[r] += cb[r * S_ + s] * eo;
    }
    ctx_out[b * H_ + j] = ctx;
    leaf_bf[b * 1024 + 512 + j] = f2bf(ctx);
    #pragma unroll
    for (int r = 0; r < R_; ++r) rctx[((size_t)b * R_ + r) * H_ + j] = f2bf(rc[r]);
}

// ---------------------------------------------------------------------------
// fused epilogue: rp2 (blocks 0..127) | numscore (128..703) | op (704..735)
// ---------------------------------------------------------------------------
__global__ __launch_bounds__(256) void k_epilogue(const float* __restrict__ rclin,
                                                  const float* __restrict__ b_rp1,
                                                  const float* __restrict__ w_rp2,
                                                  const float* __restrict__ b_rp2,
                                                  float* __restrict__ prob,
                                                  const float* __restrict__ lsb,
                                                  const unsigned short* __restrict__ ewp,
                                                  const float* __restrict__ b_sc,
                                                  const float* __restrict__ w_scs,
                                                  const int* __restrict__ mask_nums,
                                                  float* __restrict__ ns_out,
                                                  const unsigned short* __restrict__ leaf_bf,
                                                  const float* __restrict__ Wops,
                                                  const float* __restrict__ bops,
                                                  float* __restrict__ op_out) {
    __shared__ float sc[R_];
    int blk = blockIdx.x;
    int wid = threadIdx.x >> 6, lane = threadIdx.x & 63;
    if (blk < 128) {
        // ---- rule_prob ----
        int b = blk;
        int j0 = lane * 8;
        float4 p0 = *(const float4*)(b_rp1 + j0);
        float4 p1 = *(const float4*)(b_rp1 + j0 + 4);
        float4 w0 = *(const float4*)(w_rp2 + j0);
        float4 w1 = *(const float4*)(w_rp2 + j0 + 4);
        float brc[8] = {C2_*p0.x, C2_*p0.y, C2_*p0.z, C2_*p0.w,
                        C2_*p1.x, C2_*p1.y, C2_*p1.z, C2_*p1.w};
        float w[8] = {w0.x, w0.y, w0.z, w0.w, w1.x, w1.y, w1.z, w1.w};
        float wsum = 0.f;
        #pragma unroll
        for (int k = 0; k < 8; ++k) wsum += w[k];
        #pragma unroll
        for (int rr = 0; rr < 4; ++rr) {
            int r = wid * 4 + rr;
            const float* rl = rclin + ((size_t)b * R_ + r) * H_ + j0;
            float4 r0 = *(const float4*)(rl);
            float4 r1 = *(const float4*)(rl + 4);
            float rv[8] = {r0.x, r0.y, r0.z, r0.w, r1.x, r1.y, r1.z, r1.w};
            float acc = -wsum;
            #pragma unroll
            for (int k = 0; k < 8; ++k) {
                float y = fmaf(C2_, rv[k], brc[k]);
                acc = fmaf(2.0f * w[k], rcp_f(1.0f + exp2_f(y)), acc);
            }
            #pragma unroll
            for (int o = 32; o > 0; o >>= 1) acc += __shfl_xor(acc, o);
            if (lane == 0) sc[r] = acc + b_rp2[0];
        }
        __syncthreads();
        if (threadIdx.x < R_) {
            float m = -1e30f;
            for (int r = 0; r < R_; ++r) m = fmaxf(m, sc[r]);
            float sum = 0.f;
            for (int r = 0; r < R_; ++r) sum += __expf(sc[r] - m);
            prob[b * R_ + threadIdx.x] = __expf(sc[threadIdx.x] - m) * rcp_f(sum);
        }
    } else if (blk < 704) {
        // ---- num_score ----
        int row = (blk - 128) * 4 + wid;   // b*L + l, < 2304
        int b = row / L_, l = row - b * L_;
        bool masked = mask_nums[b * L_ + l] != 0;
        if (masked) {
            if (lane == 0) ns_out[b * L_ + l] = NEGV;
            return;
        }
        int j0 = lane * 8;
        uint4 ev = *(const uint4*)(ewp + (size_t)row * H_ + j0);
        const unsigned short* ep = (const unsigned short*)&ev;
        float4 l0 = *(const float4*)(lsb + b * H_ + j0);
        float4 l1 = *(const float4*)(lsb + b * H_ + j0 + 4);
        float4 s0 = *(const float4*)(b_sc + j0);
        float4 s1 = *(const float4*)(b_sc + j0 + 4);
        float4 w0 = *(const float4*)(w_scs + j0);
        float4 w1 = *(const float4*)(w_scs + j0 + 4);
        float lc[8] = {C2_*(l0.x+s0.x), C2_*(l0.y+s0.y), C2_*(l0.z+s0.z), C2_*(l0.w+s0.w),
                       C2_*(l1.x+s1.x), C2_*(l1.y+s1.y), C2_*(l1.z+s1.z), C2_*(l1.w+s1.w)};
        float w[8] = {w0.x, w0.y, w0.z, w0.w, w1.x, w1.y, w1.z, w1.w};
        float wsum = 0.f;
        #pragma unroll
        for (int k = 0; k < 8; ++k) wsum += w[k];
        float acc = -wsum;
        #pragma unroll
        for (int k = 0; k < 8; ++k) {
            float y = fmaf(C2_, bf2f(ep[k]), lc[k]);
            acc = fmaf(2.0f * w[k], rcp_f(1.0f + exp2_f(y)), acc);
        }
        #pragma unroll
        for (int o = 32; o > 0; o >>= 1) acc += __shfl_xor(acc, o);
        if (lane == 0) ns_out[b * L_ + l] = acc;
    } else {
        // ---- op ----  wave per b, 5 dots of K=1024
        int b = (blk - 704) * 4 + wid;
        int base = b * 1024 + lane * 16;
        uint4 v0 = *(const uint4*)(leaf_bf + base);
        uint4 v1 = *(const uint4*)(leaf_bf + base + 8);
        const unsigned short* lp0 = (const unsigned short*)&v0;
        const unsigned short* lp1 = (const unsigned short*)&v1;
        float lv[16];
        #pragma unroll
        for (int k = 0; k < 8; ++k) { lv[k] = bf2f(lp0[k]); lv[8 + k] = bf2f(lp1[k]); }
        #pragma unroll
        for (int o = 0; o < OPS_; ++o) {
            float acc = 0.f;
            #pragma unroll
            for (int k = 0; k < 16; ++k)
                acc = fmaf(lv[k], Wops[(size_t)(lane * 16 + k) * OPS_ + o], acc);
            #pragma unroll
            for (int of = 32; of > 0; of >>= 1) acc += __shfl_xor(acc, of);
            if (lane == 0) op_out[b * OPS_ + o] = acc + bops[o];
        }
    }
}

// ---------------------------------------------------------------------------
extern "C" void kernel_launch(void* const* d_in, const int* in_sizes, int n_in,
                              void* d_out, int out_size, void* d_ws, size_t ws_size,
                              hipStream_t stream) {
    const float* EO   = (const float*)d_in[0];
    const float* cur  = (const float*)d_in[1];
    const float* left = (const float*)d_in[2];
    const float* padh = (const float*)d_in[3];
    const float* npad = (const float*)d_in[4];
    const float* rsc  = (const float*)d_in[5];
    const float* embw = (const float*)d_in[6];
    const float* Wl   = (const float*)d_in[7];  const float* bl   = (const float*)d_in[8];
    const float* Wlg  = (const float*)d_in[9];  const float* blg  = (const float*)d_in[10];
    const float* Wr   = (const float*)d_in[11]; const float* br   = (const float*)d_in[12];
    const float* Wrg  = (const float*)d_in[13]; const float* brg  = (const float*)d_in[14];
    const float* Wta  = (const float*)d_in[15]; const float* bta  = (const float*)d_in[16];
    const float* Wts  = (const float*)d_in[17]; const float* bts  = (const float*)d_in[18];
    const float* Wra  = (const float*)d_in[19]; const float* bra  = (const float*)d_in[20];
    const float* Wrs  = (const float*)d_in[21]; const float* brs  = (const float*)d_in[22];
    const float* Wrp1 = (const float*)d_in[23]; const float* brp1 = (const float*)d_in[24];
    const float* Wrp2 = (const float*)d_in[25]; const float* brp2 = (const float*)d_in[26];
    const float* Wsa  = (const float*)d_in[27]; const float* bsa  = (const float*)d_in[28];
    const float* Wss  = (const float*)d_in[29];
    const float* Wops = (const float*)d_in[30]; const float* bops = (const float*)d_in[31];
    const int* smk = (const int*)d_in[32];
    const int* nmk = (const int*)d_in[33];
    const int* hlk = (const int*)d_in[34];
    const int* sek = (const int*)d_in[35];

    float* out = (float*)d_out;

    const size_t O_NS    = 0;
    const size_t O_OP    = O_NS + (size_t)B_ * L_;
    const size_t O_NODE  = O_OP + (size_t)B_ * OPS_;
    const size_t O_CTX   = O_NODE + (size_t)B_ * H_;
    const size_t O_EW    = O_CTX + (size_t)B_ * H_;
    const size_t O_RPROB = O_EW + (size_t)B_ * L_ * H_;

    // ---- workspace layout (no aliasing; ws is ~256 MB) ----
    float* f = (float*)d_ws;
    float* rp_buf = f;               f += 8192;      // R x H rule projection
    float* qT     = f;               f += 65536;
    float* attn   = f;               f += 16384;
    float* comb   = f;               f += 262144;
    float* gl     = f;               f += 65536;
    float* glg    = f;               f += 65536;
    float* gr     = f;               f += 65536;
    float* grg    = f;               f += 65536;
    float* lsb    = f;               f += 65536;
    float* rclin  = f;               f += 1048576;
    unsigned short* u = (unsigned short*)f;
    unsigned short* EO_bf   = u;     u += 8388608;
    unsigned short* ew_bf   = u;     u += 1179648;
    unsigned short* leaf_bf = u;     u += 131072;
    unsigned short* rctx_bf = u;     u += 1048576;
    unsigned short* Wcat    = u;     u += 524288;    // [Wta[h:]^T ; Wra[:h]^T]  1024x512
    unsigned short* T0      = u;     u += 262144;    // Wl^T
    unsigned short* T1      = u;     u += 262144;    // Wlg^T
    unsigned short* T2      = u;     u += 524288;    // Wr^T      K=1024
    unsigned short* T3      = u;     u += 524288;    // Wrg^T     K=1024
    unsigned short* T4      = u;     u += 262144;    // Wra[h:]^T
    unsigned short* T5      = u;     u += 262144;    // Wta[:h]^T
    unsigned short* T8      = u;     u += 262144;    // Wrp1^T
    unsigned short* T9      = u;     u += 524288;    // Wsa[:2h]^T K=1024
    unsigned short* T10     = u;     u += 262144;    // Wsa[2h:]^T
    unsigned short* q_bf    = u;     u += 65536;
    unsigned short* c_bf    = u;     u += 65536;
    unsigned short* acat_bf = u;     u += 131072;
    unsigned short* rsc_bf  = u;     u += 8192;
    unsigned short* ewp_bf  = u;     u += 1179648;
    unsigned short* eobuf   = u;     u += 16777216;  // 16384 x 1024

    // d1: fused prep
    PrepArgs a;
    a.EO = EO; a.cur = cur; a.padh = padh; a.left = left; a.rsc = rsc;
    a.embw = embw; a.npad = npad; a.se = sek;
    a.EO_bf = EO_bf; a.c_bf = c_bf; a.acat_bf = acat_bf; a.rsc_bf = rsc_bf;
    a.ew_bf = ew_bf; a.ew_out = out + O_EW;
    const float* tsrc[11] = {Wl, Wlg, Wr, Wrg, Wra + (size_t)H_ * H_, Wta,
                             Wta + (size_t)H_ * H_, Wra, Wrp1, Wsa, Wsa + (size_t)2 * H_ * H_};
    unsigned short* tdst[11] = {T0, T1, T2, T3, T4, T5, Wcat, Wcat + 512 * 512, T8, T9, T10};
    int tk[11] = {512, 512, 1024, 1024, 512, 512, 512, 512, 512, 1024, 512};
    int base = 0;
    for (int i = 0; i < 11; ++i) {
        a.tsrc[i] = tsrc[i]; a.tdst[i] = tdst[i]; a.tK[i] = tk[i];
        a.tbase[i] = base;
        base += 16 * (tk[i] / 32);
    }
    a.tbase[11] = base;   // 3584
    k_prep_mega<<<PG_TOTAL, 256, 0, stream>>>(a);

    // d2: 5-way batched MFMA (node gates + rule projection)
    MJ5 g;
    g.A[0] = c_bf;    g.Bt[0] = T0; g.C[0] = gl;     g.M[0] = B_;  g.K[0] = 512;
    g.A[1] = c_bf;    g.Bt[1] = T1; g.C[1] = glg;    g.M[1] = B_;  g.K[1] = 512;
    g.A[2] = acat_bf; g.Bt[2] = T2; g.C[2] = gr;     g.M[2] = B_;  g.K[2] = 1024;
    g.A[3] = acat_bf; g.Bt[3] = T3; g.C[3] = grg;    g.M[3] = B_;  g.K[3] = 1024;
    g.A[4] = rsc_bf;  g.Bt[4] = T4; g.C[4] = rp_buf; g.M[4] = R_;  g.K[4] = 512;
    gemm_bf16_j5<<<dim3(4, 1, 5), 256, 0, stream>>>(g);

    // d3: node gates
    k_node<<<256, 256, 0, stream>>>(gl, glg, gr, grg, bl, blg, br, brg, hlk,
                                    q_bf, out + O_NODE, leaf_bf);

    // d4: mega-GEMM 1 (EO projections fused N=1024, XCD-swizzled, + qT)
    k_gemm_mega1<<<1028, 256, 0, stream>>>(EO_bf, Wcat, eobuf, q_bf, T5, qT);

    // d5: fused scores (tree attn+softmax | rule scores)
    k_score_fused<<<128 + S_ * B_ / 4, 256, 0, stream>>>(
        qT, eobuf, bta, Wts, bts, rp_buf, bra, Wrs, brs, smk, attn, comb);

    // d6: fused rules-softmax + contexts
    k_ctxsm<<<B_, 512, 0, stream>>>(EO_bf, attn, comb, smk, out + O_CTX,
                                    leaf_bf, rctx_bf);

    // d7: mega-GEMM 2 (rclin, lsb, ewp)
    k_gemm_mega2<<<140, 256, 0, stream>>>(rctx_bf, T8, rclin, leaf_bf, T9, lsb,
                                          ew_bf, T10, ewp_bf);

    // d8: fused epilogue (rule_prob, num_score, op)
    k_epilogue<<<736, 256, 0, stream>>>(rclin, brp1, Wrp2, brp2, out + O_RPROB,
                                        lsb, ewp_bf, bsa, Wss, nmk, out + O_NS,
                                        leaf_bf, Wops, bops, out + O_OP);
}

// Round 7
// 284.701 us; speedup vs baseline: 2.9984x; 1.0474x over previous
//
#include <hip/hip_runtime.h>
#include <hip/hip_bf16.h>

// Problem constants
#define B_ 128
#define S_ 128
#define H_ 512
#define R_ 16
#define IN_ 2
#define OPS_ 5
#define NPAD_ 16
#define L_ 18          // IN_ + NPAD_
#define NEGV (-1000000000000.0f)
#define C2_ (-2.885390081777927f)   // -2*log2(e):  tanh(x) = 2*rcp(1+exp2(C2*x)) - 1

typedef __bf16 bf16_t;
typedef bf16_t bf16x8 __attribute__((ext_vector_type(8)));
typedef float floatx4 __attribute__((ext_vector_type(4)));

__device__ __forceinline__ float rcp_f(float x) { return __builtin_amdgcn_rcpf(x); }
__device__ __forceinline__ float exp2_f(float x) { return __builtin_amdgcn_exp2f(x); }

__device__ __forceinline__ float fast_tanh(float x) {
    return 2.0f * rcp_f(1.0f + exp2_f(C2_ * x)) - 1.0f;
}
__device__ __forceinline__ float fast_sigmoid(float x) {
    return rcp_f(1.0f + exp2_f(-1.4426950408889634f * x));
}
__device__ __forceinline__ unsigned short f2bf(float f) {   // RNE
    unsigned int u = __builtin_bit_cast(unsigned int, f);
    u += 0x7fff + ((u >> 16) & 1);
    return (unsigned short)(u >> 16);
}
__device__ __forceinline__ float bf2f(unsigned short u) {
    return __builtin_bit_cast(float, (unsigned int)u << 16);
}

// ---------------------------------------------------------------------------
// bf16 MFMA tile body: one 128x128 C-tile at (m0,n0). A row-major [.,K],
// Bt row-major [N,K] (=B^T). LDS double-buffered (1 barrier/iter), operand-
// SWAPPED mfma so each lane's 4 acc regs are 4 consecutive COLUMNS of C
// (row = lane&15, cols = quad*4+reg) -> vectorized 8B/16B stores.
// ---------------------------------------------------------------------------
#define LSTR 40
#define LBUF (128 * LSTR)   // shorts per operand per buffer

__device__ __forceinline__ void mfma_tile(const unsigned short* __restrict__ A,
                                          const unsigned short* __restrict__ Bt,
                                          void* __restrict__ Cv, bool bf16_out,
                                          int m0, int n0, int K, int ldc,
                                          unsigned short* As, unsigned short* Bs) {
    const int tid  = threadIdx.x;
    const int wid  = tid >> 6, lane = tid & 63;
    const int quad = lane >> 4, mn = lane & 15;
    const int wm = (wid & 1) * 64, wn = (wid >> 1) * 64;
    const int sr = tid >> 2;
    const int sc = (tid & 3) * 8;

    const unsigned short* pa0 = A  + (size_t)(m0 + sr)      * K + sc;
    const unsigned short* pa1 = A  + (size_t)(m0 + sr + 64) * K + sc;
    const unsigned short* pb0 = Bt + (size_t)(n0 + sr)      * K + sc;
    const unsigned short* pb1 = Bt + (size_t)(n0 + sr + 64) * K + sc;

    // tile 0 -> buf0
    uint4 a0 = *(const uint4*)pa0;
    uint4 a1 = *(const uint4*)pa1;
    uint4 b0 = *(const uint4*)pb0;
    uint4 b1 = *(const uint4*)pb1;
    *(uint4*)&As[sr * LSTR + sc]        = a0;
    *(uint4*)&As[(sr + 64) * LSTR + sc] = a1;
    *(uint4*)&Bs[sr * LSTR + sc]        = b0;
    *(uint4*)&Bs[(sr + 64) * LSTR + sc] = b1;
    // prefetch tile 1 into regs
    if (K > 32) {
        a0 = *(const uint4*)(pa0 + 32);
        a1 = *(const uint4*)(pa1 + 32);
        b0 = *(const uint4*)(pb0 + 32);
        b1 = *(const uint4*)(pb1 + 32);
    }
    __syncthreads();

    floatx4 acc[4][4] = {};

    for (int k0 = 0; k0 < K; k0 += 32) {
        const int cur = (k0 >> 5) & 1;
        unsigned short* Asb = As + cur * LBUF;
        unsigned short* Bsb = Bs + cur * LBUF;

        bf16x8 af[4], bfr[4];
        #pragma unroll
        for (int i = 0; i < 4; ++i)
            af[i] = *(const bf16x8*)&Asb[(wm + i * 16 + mn) * LSTR + quad * 8];
        #pragma unroll
        for (int j = 0; j < 4; ++j)
            bfr[j] = *(const bf16x8*)&Bsb[(wn + j * 16 + mn) * LSTR + quad * 8];

        // SWAPPED operands: D[x=colsub][y=rowsub]; lane holds row=mn, cols=quad*4+r
        #pragma unroll
        for (int i = 0; i < 4; ++i)
            #pragma unroll
            for (int j = 0; j < 4; ++j)
                acc[i][j] = __builtin_amdgcn_mfma_f32_16x16x32_bf16(bfr[j], af[i], acc[i][j], 0, 0, 0);

        if (k0 + 32 < K) {
            unsigned short* Asn = As + (cur ^ 1) * LBUF;
            unsigned short* Bsn = Bs + (cur ^ 1) * LBUF;
            *(uint4*)&Asn[sr * LSTR + sc]        = a0;
            *(uint4*)&Asn[(sr + 64) * LSTR + sc] = a1;
            *(uint4*)&Bsn[sr * LSTR + sc]        = b0;
            *(uint4*)&Bsn[(sr + 64) * LSTR + sc] = b1;
            if (k0 + 64 < K) {
                a0 = *(const uint4*)(pa0 + k0 + 64);
                a1 = *(const uint4*)(pa1 + k0 + 64);
                b0 = *(const uint4*)(pb0 + k0 + 64);
                b1 = *(const uint4*)(pb1 + k0 + 64);
            }
            __syncthreads();
        }
    }

    // C[row = m0+wm+i*16+mn][col = n0+wn+j*16+quad*4 + r], r=0..3 contiguous
    #pragma unroll
    for (int i = 0; i < 4; ++i) {
        int row = m0 + wm + i * 16 + mn;
        #pragma unroll
        for (int j = 0; j < 4; ++j) {
            int col = n0 + wn + j * 16 + quad * 4;
            if (bf16_out) {
                ushort4 v = {f2bf(acc[i][j][0]), f2bf(acc[i][j][1]),
                             f2bf(acc[i][j][2]), f2bf(acc[i][j][3])};
                *(ushort4*)((unsigned short*)Cv + (size_t)row * ldc + col) = v;
            } else {
                float4 v = {acc[i][j][0], acc[i][j][1], acc[i][j][2], acc[i][j][3]};
                *(float4*)((float*)Cv + (size_t)row * ldc + col) = v;
            }
        }
    }
}

// mega-GEMM 1: blocks 0..1023 = EO_bf @ Wcat (N=1024 -> eobuf bf16, ld 1024),
//   XCD-friendly mapping m=blk&127, n=blk>>7; blocks 1024..1027 = q_bf @ T5.
__global__ __launch_bounds__(256) void k_gemm_mega1(const unsigned short* __restrict__ EO_bf,
                                                    const unsigned short* __restrict__ Wcat,
                                                    unsigned short* __restrict__ eobuf,
                                                    const unsigned short* __restrict__ q_bf,
                                                    const unsigned short* __restrict__ T5,
                                                    float* __restrict__ qT) {
    __shared__ unsigned short As[2 * LBUF];
    __shared__ unsigned short Bs[2 * LBUF];
    int blk = blockIdx.x;
    if (blk < 1024)
        mfma_tile(EO_bf, Wcat, eobuf, true, (blk & 127) * 128, (blk >> 7) * 128, 512, 1024, As, Bs);
    else
        mfma_tile(q_bf, T5, qT, false, 0, (blk - 1024) * 128, 512, 512, As, Bs);
}

// mega-GEMM 2: rctx@T8 (64 blk), leaf@T9 (4 blk), ew@T10 (72 blk)
__global__ __launch_bounds__(256) void k_gemm_mega2(const unsigned short* __restrict__ rctx_bf,
                                                    const unsigned short* __restrict__ T8,
                                                    float* __restrict__ rclin,
                                                    const unsigned short* __restrict__ leaf_bf,
                                                    const unsigned short* __restrict__ T9,
                                                    float* __restrict__ lsb,
                                                    const unsigned short* __restrict__ ew_bf,
                                                    const unsigned short* __restrict__ T10,
                                                    unsigned short* __restrict__ ewp_bf) {
    __shared__ unsigned short As[2 * LBUF];
    __shared__ unsigned short Bs[2 * LBUF];
    int blk = blockIdx.x;
    if (blk < 64)
        mfma_tile(rctx_bf, T8, rclin, false, (blk >> 2) * 128, (blk & 3) * 128, 512, 512, As, Bs);
    else if (blk < 68)
        mfma_tile(leaf_bf, T9, lsb, false, 0, (blk - 64) * 128, 1024, 512, As, Bs);
    else {
        int r = blk - 68;
        mfma_tile(ew_bf, T10, ewp_bf, true, (r >> 2) * 128, (r & 3) * 128, 512, 512, As, Bs);
    }
}

// z-batched 5-job GEMM, N=512 fixed, M<=128 (row-clamped loads, guarded stores)
struct MJ5 {
    const unsigned short* A[5]; const unsigned short* Bt[5]; float* C[5];
    int M[5]; int K[5];
};
__global__ __launch_bounds__(256) void gemm_bf16_j5(MJ5 g) {
    __shared__ unsigned short As[2 * LBUF];
    __shared__ unsigned short Bs[2 * LBUF];

    const int z = blockIdx.z;
    const unsigned short* A  = g.A[z];
    const unsigned short* Bt = g.Bt[z];
    float* C = g.C[z];
    const int M = g.M[z], K = g.K[z];

    const int tid  = threadIdx.x;
    const int wid  = tid >> 6, lane = tid & 63;
    const int quad = lane >> 4, mn = lane & 15;
    const int wm = (wid & 1) * 64, wn = (wid >> 1) * 64;
    const int n0 = blockIdx.x * 128;

    const int sr = tid >> 2;
    const int sc = (tid & 3) * 8;
    const int ra0 = min(sr, M - 1);
    const int ra1 = min(sr + 64, M - 1);

    const unsigned short* pa0 = A  + (size_t)ra0 * K + sc;
    const unsigned short* pa1 = A  + (size_t)ra1 * K + sc;
    const unsigned short* pb0 = Bt + (size_t)(n0 + sr)      * K + sc;
    const unsigned short* pb1 = Bt + (size_t)(n0 + sr + 64) * K + sc;

    uint4 a0 = *(const uint4*)pa0;
    uint4 a1 = *(const uint4*)pa1;
    uint4 b0 = *(const uint4*)pb0;
    uint4 b1 = *(const uint4*)pb1;
    *(uint4*)&As[sr * LSTR + sc]        = a0;
    *(uint4*)&As[(sr + 64) * LSTR + sc] = a1;
    *(uint4*)&Bs[sr * LSTR + sc]        = b0;
    *(uint4*)&Bs[(sr + 64) * LSTR + sc] = b1;
    if (K > 32) {
        a0 = *(const uint4*)(pa0 + 32);
        a1 = *(const uint4*)(pa1 + 32);
        b0 = *(const uint4*)(pb0 + 32);
        b1 = *(const uint4*)(pb1 + 32);
    }
    __syncthreads();

    floatx4 acc[4][4] = {};

    for (int k0 = 0; k0 < K; k0 += 32) {
        const int cur = (k0 >> 5) & 1;
        unsigned short* Asb = As + cur * LBUF;
        unsigned short* Bsb = Bs + cur * LBUF;

        bf16x8 af[4], bfr[4];
        #pragma unroll
        for (int i = 0; i < 4; ++i)
            af[i] = *(const bf16x8*)&Asb[(wm + i * 16 + mn) * LSTR + quad * 8];
        #pragma unroll
        for (int j = 0; j < 4; ++j)
            bfr[j] = *(const bf16x8*)&Bsb[(wn + j * 16 + mn) * LSTR + quad * 8];

        #pragma unroll
        for (int i = 0; i < 4; ++i)
            #pragma unroll
            for (int j = 0; j < 4; ++j)
                acc[i][j] = __builtin_amdgcn_mfma_f32_16x16x32_bf16(bfr[j], af[i], acc[i][j], 0, 0, 0);

        if (k0 + 32 < K) {
            unsigned short* Asn = As + (cur ^ 1) * LBUF;
            unsigned short* Bsn = Bs + (cur ^ 1) * LBUF;
            *(uint4*)&Asn[sr * LSTR + sc]        = a0;
            *(uint4*)&Asn[(sr + 64) * LSTR + sc] = a1;
            *(uint4*)&Bsn[sr * LSTR + sc]        = b0;
            *(uint4*)&Bsn[(sr + 64) * LSTR + sc] = b1;
            if (k0 + 64 < K) {
                a0 = *(const uint4*)(pa0 + k0 + 64);
                a1 = *(const uint4*)(pa1 + k0 + 64);
                b0 = *(const uint4*)(pb0 + k0 + 64);
                b1 = *(const uint4*)(pb1 + k0 + 64);
            }
            __syncthreads();
        }
    }

    #pragma unroll
    for (int i = 0; i < 4; ++i) {
        int row = wm + i * 16 + mn;
        if (row < M) {
            #pragma unroll
            for (int j = 0; j < 4; ++j) {
                int col = n0 + wn + j * 16 + quad * 4;
                float4 v = {acc[i][j][0], acc[i][j][1], acc[i][j][2], acc[i][j][3]};
                *(float4*)(C + (size_t)row * 512 + col) = v;
            }
        }
    }
}

// ---------------------------------------------------------------------------
// fused prep: EO cast | ew build | c/acat/rsc cast | 11 weight transposes
// ---------------------------------------------------------------------------
struct PrepArgs {
    const float *EO, *cur, *padh, *left, *rsc, *embw, *npad;
    const int* se;
    unsigned short *EO_bf, *c_bf, *acat_bf, *rsc_bf, *ew_bf;
    float* ew_out;
    const float* tsrc[11];
    unsigned short* tdst[11];
    int tK[11];
    int tbase[12];
};
#define PG_CAST 8192
#define PG_EW   1152
#define PG_PREP 288
#define PG_WT   3584
#define PG_TOTAL (PG_CAST + PG_EW + PG_PREP + PG_WT)   // 13216

__global__ __launch_bounds__(256) void k_prep_mega(PrepArgs a) {
    __shared__ float t[32][33];
    int blk = blockIdx.x, tid = threadIdx.x;
    if (blk < PG_CAST) {
        int i = (blk * 256 + tid) * 4;
        float4 v = *(const float4*)(a.EO + i);
        ushort4 o;
        o.x = f2bf(v.x); o.y = f2bf(v.y); o.z = f2bf(v.z); o.w = f2bf(v.w);
        *(ushort4*)(a.EO_bf + i) = o;
    } else if (blk < PG_CAST + PG_EW) {
        int i = ((blk - PG_CAST) * 256 + tid) * 4;
        int j = i & 511;
        int bl = i >> 9;
        int l = bl % L_;
        int b = bl / L_;
        const float* src = (l < IN_) ? (a.embw + l * H_ + j)
                                     : (a.npad + ((size_t)b * NPAD_ + (l - IN_)) * H_ + j);
        float4 v = *(const float4*)src;
        *(float4*)(a.ew_out + i) = v;
        ushort4 o;
        o.x = f2bf(v.x); o.y = f2bf(v.y); o.z = f2bf(v.z); o.w = f2bf(v.w);
        *(ushort4*)(a.ew_bf + i) = o;
    } else if (blk < PG_CAST + PG_EW + PG_PREP) {
        int i = (blk - PG_CAST - PG_EW) * 256 + tid;
        if (i < B_ * H_) {
            int b = i >> 9, j = i & 511;
            float cv = a.se[b] ? a.padh[j] : a.cur[i];
            a.c_bf[i] = f2bf(cv);
            a.acat_bf[b * 1024 + j] = f2bf(a.left[i]);
            a.acat_bf[b * 1024 + 512 + j] = f2bf(cv);
        } else {
            int k = i - B_ * H_;
            a.rsc_bf[k] = f2bf(a.rsc[k]);
        }
    } else {
        int rel = blk - (PG_CAST + PG_EW + PG_PREP);
        int j = 0;
        while (rel >= a.tbase[j + 1]) ++j;
        int r = rel - a.tbase[j];
        int K = a.tK[j];
        const float* src = a.tsrc[j];
        unsigned short* dst = a.tdst[j];
        int bx = (r & 15) * 32;   // n tile
        int by = (r >> 4) * 32;   // k tile
        int tx = tid & 31, ty = tid >> 5;
        #pragma unroll
        for (int i = 0; i < 32; i += 8)
            t[ty + i][tx] = src[(size_t)(by + ty + i) * 512 + bx + tx];
        __syncthreads();
        #pragma unroll
        for (int i = 0; i < 32; i += 8)
            dst[(size_t)(bx + ty + i) * K + by + tx] = f2bf(t[tx][ty + i]);
    }
}

// gates -> q_bf, node_out (fp32 output), leaf_bf[:, :H]
__global__ void k_node(const float* __restrict__ gl, const float* __restrict__ glg,
                       const float* __restrict__ gr, const float* __restrict__ grg,
                       const float* __restrict__ bl, const float* __restrict__ blg,
                       const float* __restrict__ br, const float* __restrict__ brg,
                       const int* __restrict__ hl,
                       unsigned short* __restrict__ q_bf, float* __restrict__ node_out,
                       unsigned short* __restrict__ leaf_bf) {
    int i = blockIdx.x * blockDim.x + threadIdx.x;
    int b = i >> 9, j = i & 511;
    float nl = fast_tanh(gl[i] + bl[j]) * fast_sigmoid(glg[i] + blg[j]);
    float nr = fast_tanh(gr[i] + br[j]) * fast_sigmoid(grg[i] + brg[j]);
    float v = hl[b] ? nr : nl;
    node_out[i] = v;
    q_bf[i] = f2bf(v);
    leaf_bf[b * 1024 + j] = f2bf(v);
}

// ---------------------------------------------------------------------------
// fused scores: blocks 0..127 = tree score+softmax (block per b);
//               blocks 128..4223 = rule scores (wave per (s,b)-row)
// eobuf stride 1024: cols 0..511 tree proj, 512..1023 rule proj
// ---------------------------------------------------------------------------
__global__ __launch_bounds__(256) void k_score_fused(const float* __restrict__ qT,
                                                     const unsigned short* __restrict__ eobuf,
                                                     const float* __restrict__ b_ta,
                                                     const float* __restrict__ w_ts,
                                                     const float* __restrict__ b_ts,
                                                     const float* __restrict__ RP,
                                                     const float* __restrict__ b_ra,
                                                     const float* __restrict__ w_rs,
                                                     const float* __restrict__ b_rs,
                                                     const int* __restrict__ sm,
                                                     float* __restrict__ attn,
                                                     float* __restrict__ comb) {
    __shared__ float sc[S_];
    int blk = blockIdx.x;
    int tid = threadIdx.x;
    int wid = tid >> 6, lane = tid & 63;
    int j0 = lane * 8;

    if (blk < 128) {
        // ---- tree score + softmax ----
        int b = blk;
        float4 q0 = *(const float4*)(qT + b * H_ + j0);
        float4 q1 = *(const float4*)(qT + b * H_ + j0 + 4);
        float4 t0 = *(const float4*)(b_ta + j0);
        float4 t1 = *(const float4*)(b_ta + j0 + 4);
        float4 w0 = *(const float4*)(w_ts + j0);
        float4 w1 = *(const float4*)(w_ts + j0 + 4);
        float qc[8] = {C2_*(q0.x+t0.x), C2_*(q0.y+t0.y), C2_*(q0.z+t0.z), C2_*(q0.w+t0.w),
                       C2_*(q1.x+t1.x), C2_*(q1.y+t1.y), C2_*(q1.z+t1.z), C2_*(q1.w+t1.w)};
        float w2[8] = {2*w0.x, 2*w0.y, 2*w0.z, 2*w0.w, 2*w1.x, 2*w1.y, 2*w1.z, 2*w1.w};
        float wsum = 0.5f * (w2[0]+w2[1]+w2[2]+w2[3]+w2[4]+w2[5]+w2[6]+w2[7]);
        float bias = b_ts[0];

        for (int s = wid; s < S_; s += 4) {
            if (sm[b * S_ + s]) {
                if (lane == 0) sc[s] = NEGV;
                continue;
            }
            uint4 ev = *(const uint4*)(eobuf + ((size_t)s * B_ + b) * 1024 + j0);
            const unsigned short* ep = (const unsigned short*)&ev;
            float acc = -wsum;
            #pragma unroll
            for (int k = 0; k < 8; ++k) {
                float y = fmaf(C2_, bf2f(ep[k]), qc[k]);
                acc = fmaf(w2[k], rcp_f(1.0f + exp2_f(y)), acc);
            }
            #pragma unroll
            for (int o = 32; o > 0; o >>= 1) acc += __shfl_xor(acc, o);
            if (lane == 0) sc[s] = acc + bias;
        }
        __syncthreads();
        if (tid < 64) {
            float v0 = sc[tid], v1 = sc[tid + 64];
            float m = fmaxf(v0, v1);
            #pragma unroll
            for (int o = 32; o > 0; o >>= 1) m = fmaxf(m, __shfl_xor(m, o));
            float e0 = __expf(v0 - m), e1 = __expf(v1 - m);
            float ss = e0 + e1;
            #pragma unroll
            for (int o = 32; o > 0; o >>= 1) ss += __shfl_xor(ss, o);
            float r = rcp_f(ss);
            attn[b * S_ + tid] = e0 * r;
            attn[b * S_ + tid + 64] = e1 * r;
        }
        return;
    }

    // ---- rule scores ----
    int row = (blk - 128) * 4 + wid;   // s*B + b
    int s = row >> 7, b = row & 127;
    bool masked = sm[b * S_ + s] != 0;
    if (masked) {
        if (lane < R_) comb[((size_t)b * R_ + lane) * S_ + s] = NEGV;
        return;
    }
    uint4 ev = *(const uint4*)(eobuf + (size_t)row * 1024 + 512 + j0);
    const unsigned short* ep = (const unsigned short*)&ev;
    float4 a0 = *(const float4*)(b_ra + j0);
    float4 a1 = *(const float4*)(b_ra + j0 + 4);
    float4 w0 = *(const float4*)(w_rs + j0);
    float4 w1 = *(const float4*)(w_rs + j0 + 4);
    float ba[8] = {a0.x, a0.y, a0.z, a0.w, a1.x, a1.y, a1.z, a1.w};
    float w2[8], ed[8];
    float wsum = 0.f;
    {
        float w[8] = {w0.x, w0.y, w0.z, w0.w, w1.x, w1.y, w1.z, w1.w};
        #pragma unroll
        for (int k = 0; k < 8; ++k) {
            wsum += w[k];
            w2[k] = 2.0f * w[k];
            ed[k] = C2_ * (bf2f(ep[k]) + ba[k]);
        }
    }
    float bias = b_rs[0];
    #pragma unroll
    for (int r = 0; r < R_; ++r) {
        float4 r0 = *(const float4*)(RP + r * H_ + j0);
        float4 r1 = *(const float4*)(RP + r * H_ + j0 + 4);
        float rp[8] = {r0.x, r0.y, r0.z, r0.w, r1.x, r1.y, r1.z, r1.w};
        float acc = -wsum;
        #pragma unroll
        for (int k = 0; k < 8; ++k) {
            float y = fmaf(C2_, rp[k], ed[k]);
            acc = fmaf(w2[k], rcp_f(1.0f + exp2_f(y)), acc);
        }
        #pragma unroll
        for (int o = 32; o > 0; o >>= 1) acc += __shfl_xor(acc, o);
        if (lane == 0) comb[((size_t)b * R_ + r) * S_ + s] = acc + bias;
    }
}

// ---------------------------------------------------------------------------
// fused rules-softmax + contexts: grid (b, jhalf), 256 threads.
// comb holds RAW rule scores; softmax (+0.2*attn) computed in LDS (redundantly
// per j-half), then contexts via compacted unmasked-s list.
// ---------------------------------------------------------------------------
__global__ __launch_bounds__(256) void k_ctxsm(const unsigned short* __restrict__ EO_bf,
                                               const float* __restrict__ attn,
                                               const float* __restrict__ comb,
                                               const int* __restrict__ sm,
                                               float* __restrict__ ctx_out,
                                               unsigned short* __restrict__ leaf_bf,
                                               unsigned short* __restrict__ rctx) {
    __shared__ float cb[R_ * S_];
    __shared__ float at[S_];
    __shared__ short usl[S_];
    __shared__ int ucount;
    int b = blockIdx.x;
    int tid = threadIdx.x;
    int w = tid >> 6, lane = tid & 63;

    if (tid < S_) at[tid] = attn[b * S_ + tid];
    for (int i = tid; i < R_ * S_; i += 256) cb[i] = comb[(size_t)b * R_ * S_ + i];
    if (tid == 0) {
        int c = 0;
        for (int s = 0; s < S_; ++s)
            if (!sm[b * S_ + s]) usl[c++] = (short)s;
        ucount = c;
    }
    __syncthreads();

    // softmax over s: 4 waves x 4 rows = 16
    #pragma unroll
    for (int rr = 0; rr < 4; ++rr) {
        int r = w * 4 + rr;
        float v0 = cb[r * S_ + lane], v1 = cb[r * S_ + lane + 64];
        float m = fmaxf(v0, v1);
        #pragma unroll
        for (int o = 32; o > 0; o >>= 1) m = fmaxf(m, __shfl_xor(m, o));
        float e0 = __expf(v0 - m), e1 = __expf(v1 - m);
        float ss = e0 + e1;
        #pragma unroll
        for (int o = 32; o > 0; o >>= 1) ss += __shfl_xor(ss, o);
        float rc_ = rcp_f(ss);
        cb[r * S_ + lane]      = e0 * rc_ + 0.2f * at[lane];
        cb[r * S_ + lane + 64] = e1 * rc_ + 0.2f * at[lane + 64];
    }
    __syncthreads();

    int j = blockIdx.y * 256 + tid;
    int nu = ucount;
    float ctx = 0.f;
    float rc[R_] = {};
    #pragma unroll 2
    for (int ii = 0; ii < nu; ++ii) {
        int s = usl[ii];
        float eo = bf2f(EO_bf[((size_t)s * B_ + b) * H_ + j]);
        ctx += at[s] * eo;
        #pragma unroll
        for (int r = 0; r < R_; ++r) rc[r] += cb[r * S_ + s] * eo;
    }
    ctx_out[b * H_ + j] = ctx;
    leaf_bf[b * 1024 + 512 + j] = f2bf(ctx);
    #pragma unroll
    for (int r = 0; r < R_; ++r) rctx[((size_t)b * R_ + r) * H_ + j] = f2bf(rc[r]);
}

// ---------------------------------------------------------------------------
// fused epilogue: rp2 (blocks 0..127) | numscore (128..703) | op (704..735)
// ---------------------------------------------------------------------------
__global__ __launch_bounds__(256) void k_epilogue(const float* __restrict__ rclin,
                                                  const float* __restrict__ b_rp1,
                                                  const float* __restrict__ w_rp2,
                                                  const float* __restrict__ b_rp2,
                                                  float* __restrict__ prob,
                                                  const float* __restrict__ lsb,
                                                  const unsigned short* __restrict__ ewp,
                                                  const float* __restrict__ b_sc,
                                                  const float* __restrict__ w_scs,
                                                  const int* __restrict__ mask_nums,
                                                  float* __restrict__ ns_out,
                                                  const unsigned short* __restrict__ leaf_bf,
                                                  const float* __restrict__ Wops,
                                                  const float* __restrict__ bops,
                                                  float* __restrict__ op_out) {
    __shared__ float sc[R_];
    int blk = blockIdx.x;
    int wid = threadIdx.x >> 6, lane = threadIdx.x & 63;
    if (blk < 128) {
        // ---- rule_prob ----
        int b = blk;
        int j0 = lane * 8;
        float4 p0 = *(const float4*)(b_rp1 + j0);
        float4 p1 = *(const float4*)(b_rp1 + j0 + 4);
        float4 w0 = *(const float4*)(w_rp2 + j0);
        float4 w1 = *(const float4*)(w_rp2 + j0 + 4);
        float brc[8] = {C2_*p0.x, C2_*p0.y, C2_*p0.z, C2_*p0.w,
                        C2_*p1.x, C2_*p1.y, C2_*p1.z, C2_*p1.w};
        float w[8] = {w0.x, w0.y, w0.z, w0.w, w1.x, w1.y, w1.z, w1.w};
        float wsum = 0.f;
        #pragma unroll
        for (int k = 0; k < 8; ++k) wsum += w[k];
        #pragma unroll
        for (int rr = 0; rr < 4; ++rr) {
            int r = wid * 4 + rr;
            const float* rl = rclin + ((size_t)b * R_ + r) * H_ + j0;
            float4 r0 = *(const float4*)(rl);
            float4 r1 = *(const float4*)(rl + 4);
            float rv[8] = {r0.x, r0.y, r0.z, r0.w, r1.x, r1.y, r1.z, r1.w};
            float acc = -wsum;
            #pragma unroll
            for (int k = 0; k < 8; ++k) {
                float y = fmaf(C2_, rv[k], brc[k]);
                acc = fmaf(2.0f * w[k], rcp_f(1.0f + exp2_f(y)), acc);
            }
            #pragma unroll
            for (int o = 32; o > 0; o >>= 1) acc += __shfl_xor(acc, o);
            if (lane == 0) sc[r] = acc + b_rp2[0];
        }
        __syncthreads();
        if (threadIdx.x < R_) {
            float m = -1e30f;
            for (int r = 0; r < R_; ++r) m = fmaxf(m, sc[r]);
            float sum = 0.f;
            for (int r = 0; r < R_; ++r) sum += __expf(sc[r] - m);
            prob[b * R_ + threadIdx.x] = __expf(sc[threadIdx.x] - m) * rcp_f(sum);
        }
    } else if (blk < 704) {
        // ---- num_score ----
        int row = (blk - 128) * 4 + wid;   // b*L + l, < 2304
        int b = row / L_, l = row - b * L_;
        bool masked = mask_nums[b * L_ + l] != 0;
        if (masked) {
            if (lane == 0) ns_out[b * L_ + l] = NEGV;
            return;
        }
        int j0 = lane * 8;
        uint4 ev = *(const uint4*)(ewp + (size_t)row * H_ + j0);
        const unsigned short* ep = (const unsigned short*)&ev;
        float4 l0 = *(const float4*)(lsb + b * H_ + j0);
        float4 l1 = *(const float4*)(lsb + b * H_ + j0 + 4);
        float4 s0 = *(const float4*)(b_sc + j0);
        float4 s1 = *(const float4*)(b_sc + j0 + 4);
        float4 w0 = *(const float4*)(w_scs + j0);
        float4 w1 = *(const float4*)(w_scs + j0 + 4);
        float lc[8] = {C2_*(l0.x+s0.x), C2_*(l0.y+s0.y), C2_*(l0.z+s0.z), C2_*(l0.w+s0.w),
                       C2_*(l1.x+s1.x), C2_*(l1.y+s1.y), C2_*(l1.z+s1.z), C2_*(l1.w+s1.w)};
        float w[8] = {w0.x, w0.y, w0.z, w0.w, w1.x, w1.y, w1.z, w1.w};
        float wsum = 0.f;
        #pragma unroll
        for (int k = 0; k < 8; ++k) wsum += w[k];
        float acc = -wsum;
        #pragma unroll
        for (int k = 0; k < 8; ++k) {
            float y = fmaf(C2_, bf2f(ep[k]), lc[k]);
            acc = fmaf(2.0f * w[k], rcp_f(1.0f + exp2_f(y)), acc);
        }
        #pragma unroll
        for (int o = 32; o > 0; o >>= 1) acc += __shfl_xor(acc, o);
        if (lane == 0) ns_out[b * L_ + l] = acc;
    } else {
        // ---- op ----  wave per b, 5 dots of K=1024
        int b = (blk - 704) * 4 + wid;
        int base = b * 1024 + lane * 16;
        uint4 v0 = *(const uint4*)(leaf_bf + base);
        uint4 v1 = *(const uint4*)(leaf_bf + base + 8);
        const unsigned short* lp0 = (const unsigned short*)&v0;
        const unsigned short* lp1 = (const unsigned short*)&v1;
        float lv[16];
        #pragma unroll
        for (int k = 0; k < 8; ++k) { lv[k] = bf2f(lp0[k]); lv[8 + k] = bf2f(lp1[k]); }
        #pragma unroll
        for (int o = 0; o < OPS_; ++o) {
            float acc = 0.f;
            #pragma unroll
            for (int k = 0; k < 16; ++k)
                acc = fmaf(lv[k], Wops[(size_t)(lane * 16 + k) * OPS_ + o], acc);
            #pragma unroll
            for (int of = 32; of > 0; of >>= 1) acc += __shfl_xor(acc, of);
            if (lane == 0) op_out[b * OPS_ + o] = acc + bops[o];
        }
    }
}

// ---------------------------------------------------------------------------
extern "C" void kernel_launch(void* const* d_in, const int* in_sizes, int n_in,
                              void* d_out, int out_size, void* d_ws, size_t ws_size,
                              hipStream_t stream) {
    const float* EO   = (const float*)d_in[0];
    const float* cur  = (const float*)d_in[1];
    const float* left = (const float*)d_in[2];
    const float* padh = (const float*)d_in[3];
    const float* npad = (const float*)d_in[4];
    const float* rsc  = (const float*)d_in[5];
    const float* embw = (const float*)d_in[6];
    const float* Wl   = (const float*)d_in[7];  const float* bl   = (const float*)d_in[8];
    const float* Wlg  = (const float*)d_in[9];  const float* blg  = (const float*)d_in[10];
    const float* Wr   = (const float*)d_in[11]; const float* br   = (const float*)d_in[12];
    const float* Wrg  = (const float*)d_in[13]; const float* brg  = (const float*)d_in[14];
    const float* Wta  = (const float*)d_in[15]; const float* bta  = (const float*)d_in[16];
    const float* Wts  = (const float*)d_in[17]; const float* bts  = (const float*)d_in[18];
    const float* Wra  = (const float*)d_in[19]; const float* bra  = (const float*)d_in[20];
    const float* Wrs  = (const float*)d_in[21]; const float* brs  = (const float*)d_in[22];
    const float* Wrp1 = (const float*)d_in[23]; const float* brp1 = (const float*)d_in[24];
    const float* Wrp2 = (const float*)d_in[25]; const float* brp2 = (const float*)d_in[26];
    const float* Wsa  = (const float*)d_in[27]; const float* bsa  = (const float*)d_in[28];
    const float* Wss  = (const float*)d_in[29];
    const float* Wops = (const float*)d_in[30]; const float* bops = (const float*)d_in[31];
    const int* smk = (const int*)d_in[32];
    const int* nmk = (const int*)d_in[33];
    const int* hlk = (const int*)d_in[34];
    const int* sek = (const int*)d_in[35];

    float* out = (float*)d_out;

    const size_t O_NS    = 0;
    const size_t O_OP    = O_NS + (size_t)B_ * L_;
    const size_t O_NODE  = O_OP + (size_t)B_ * OPS_;
    const size_t O_CTX   = O_NODE + (size_t)B_ * H_;
    const size_t O_EW    = O_CTX + (size_t)B_ * H_;
    const size_t O_RPROB = O_EW + (size_t)B_ * L_ * H_;

    // ---- workspace layout (no aliasing) ----
    float* f = (float*)d_ws;
    float* rp_buf = f;               f += 8192;      // R x H rule projection
    float* qT     = f;               f += 65536;
    float* attn   = f;               f += 16384;
    float* comb   = f;               f += 262144;
    float* gl     = f;               f += 65536;
    float* glg    = f;               f += 65536;
    float* gr     = f;               f += 65536;
    float* grg    = f;               f += 65536;
    float* lsb    = f;               f += 65536;
    float* rclin  = f;               f += 1048576;
    unsigned short* u = (unsigned short*)f;
    unsigned short* EO_bf   = u;     u += 8388608;
    unsigned short* ew_bf   = u;     u += 1179648;
    unsigned short* leaf_bf = u;     u += 131072;
    unsigned short* rctx_bf = u;     u += 1048576;
    unsigned short* Wcat    = u;     u += 524288;    // [Wta[h:]^T ; Wra[:h]^T]  1024x512
    unsigned short* T0      = u;     u += 262144;    // Wl^T
    unsigned short* T1      = u;     u += 262144;    // Wlg^T
    unsigned short* T2      = u;     u += 524288;    // Wr^T      K=1024
    unsigned short* T3      = u;     u += 524288;    // Wrg^T     K=1024
    unsigned short* T4      = u;     u += 262144;    // Wra[h:]^T
    unsigned short* T5      = u;     u += 262144;    // Wta[:h]^T
    unsigned short* T8      = u;     u += 262144;    // Wrp1^T
    unsigned short* T9      = u;     u += 524288;    // Wsa[:2h]^T K=1024
    unsigned short* T10     = u;     u += 262144;    // Wsa[2h:]^T
    unsigned short* q_bf    = u;     u += 65536;
    unsigned short* c_bf    = u;     u += 65536;
    unsigned short* acat_bf = u;     u += 131072;
    unsigned short* rsc_bf  = u;     u += 8192;
    unsigned short* ewp_bf  = u;     u += 1179648;
    unsigned short* eobuf   = u;     u += 16777216;  // 16384 x 1024

    // d1: fused prep
    PrepArgs a;
    a.EO = EO; a.cur = cur; a.padh = padh; a.left = left; a.rsc = rsc;
    a.embw = embw; a.npad = npad; a.se = sek;
    a.EO_bf = EO_bf; a.c_bf = c_bf; a.acat_bf = acat_bf; a.rsc_bf = rsc_bf;
    a.ew_bf = ew_bf; a.ew_out = out + O_EW;
    const float* tsrc[11] = {Wl, Wlg, Wr, Wrg, Wra + (size_t)H_ * H_, Wta,
                             Wta + (size_t)H_ * H_, Wra, Wrp1, Wsa, Wsa + (size_t)2 * H_ * H_};
    unsigned short* tdst[11] = {T0, T1, T2, T3, T4, T5, Wcat, Wcat + 512 * 512, T8, T9, T10};
    int tk[11] = {512, 512, 1024, 1024, 512, 512, 512, 512, 512, 1024, 512};
    int base = 0;
    for (int i = 0; i < 11; ++i) {
        a.tsrc[i] = tsrc[i]; a.tdst[i] = tdst[i]; a.tK[i] = tk[i];
        a.tbase[i] = base;
        base += 16 * (tk[i] / 32);
    }
    a.tbase[11] = base;   // 3584
    k_prep_mega<<<PG_TOTAL, 256, 0, stream>>>(a);

    // d2: 5-way batched MFMA (node gates + rule projection)
    MJ5 g;
    g.A[0] = c_bf;    g.Bt[0] = T0; g.C[0] = gl;     g.M[0] = B_;  g.K[0] = 512;
    g.A[1] = c_bf;    g.Bt[1] = T1; g.C[1] = glg;    g.M[1] = B_;  g.K[1] = 512;
    g.A[2] = acat_bf; g.Bt[2] = T2; g.C[2] = gr;     g.M[2] = B_;  g.K[2] = 1024;
    g.A[3] = acat_bf; g.Bt[3] = T3; g.C[3] = grg;    g.M[3] = B_;  g.K[3] = 1024;
    g.A[4] = rsc_bf;  g.Bt[4] = T4; g.C[4] = rp_buf; g.M[4] = R_;  g.K[4] = 512;
    gemm_bf16_j5<<<dim3(4, 1, 5), 256, 0, stream>>>(g);

    // d3: node gates
    k_node<<<256, 256, 0, stream>>>(gl, glg, gr, grg, bl, blg, br, brg, hlk,
                                    q_bf, out + O_NODE, leaf_bf);

    // d4: mega-GEMM 1 (EO projections fused N=1024, XCD-swizzled, + qT)
    k_gemm_mega1<<<1028, 256, 0, stream>>>(EO_bf, Wcat, eobuf, q_bf, T5, qT);

    // d5: fused scores (tree attn+softmax | rule scores)
    k_score_fused<<<128 + S_ * B_ / 4, 256, 0, stream>>>(
        qT, eobuf, bta, Wts, bts, rp_buf, bra, Wrs, brs, smk, attn, comb);

    // d6: fused rules-softmax + contexts
    k_ctxsm<<<dim3(B_, 2), 256, 0, stream>>>(EO_bf, attn, comb, smk, out + O_CTX,
                                             leaf_bf, rctx_bf);

    // d7: mega-GEMM 2 (rclin, lsb, ewp)
    k_gemm_mega2<<<140, 256, 0, stream>>>(rctx_bf, T8, rclin, leaf_bf, T9, lsb,
                                          ew_bf, T10, ewp_bf);

    // d8: fused epilogue (rule_prob, num_score, op)
    k_epilogue<<<736, 256, 0, stream>>>(rclin, brp1, Wrp2, brp2, out + O_RPROB,
                                        lsb, ewp_bf, bsa, Wss, nmk, out + O_NS,
                                        leaf_bf, Wops, bops, out + O_OP);
}